// Round 6
// baseline (3368.757 us; speedup 1.0000x reference)
//
#include <hip/hip_runtime.h>

typedef unsigned short u16;
typedef unsigned int   u32;
typedef __bf16 bf16x8 __attribute__((ext_vector_type(8)));
typedef float  f32x4  __attribute__((ext_vector_type(4)));

#define DEVI __device__ __forceinline__

DEVI u16 f2bf(float f){
  u32 u = __builtin_bit_cast(u32, f);
  u32 r = (u + 0x7fffu + ((u >> 16) & 1u)) >> 16;   // RNE
  return (u16)r;
}

DEVI void gload16(const void* g, void* lds){
  __builtin_amdgcn_global_load_lds(
      (const __attribute__((address_space(1))) void*)g,
      (__attribute__((address_space(3))) void*)lds, 16, 0, 0);
}

DEVI f32x4 MFMA(bf16x8 a, bf16x8 b, f32x4 c){
  return __builtin_amdgcn_mfma_f32_16x16x32_bf16(a, b, c, 0, 0, 0);
}

// ---------------- mask dtype probe: 1 => uint8 bytes, 0 => int32 ----------------
__global__ void k_maskprobe(const unsigned char* __restrict__ m, int* __restrict__ flag){
  __shared__ int s;
  if (threadIdx.x == 0) s = 0;
  __syncthreads();
  int acc = 0;
  for (int i = threadIdx.x; i < 65536; i += 256)
    if ((i & 3) != 0 && m[i] != 0) acc++;
  atomicAdd(&s, acc);
  __syncthreads();
  if (threadIdx.x == 0) *flag = (s > 0) ? 1 : 0;
}

// ---------------- pack attn_mask to bitmask [B*S][16 words] ----------------
__global__ void k_maskbits(const void* __restrict__ mask, const int* __restrict__ flag,
                           u32* __restrict__ mb){
  int row  = blockIdx.x * 4 + (threadIdx.x >> 6);   // b*512+q
  int lane = threadIdx.x & 63;
  bool bytes = (*flag != 0);
  for (int c0 = 0; c0 < 512; c0 += 64){
    int v;
    if (bytes) v = ((const unsigned char*)mask)[(size_t)row * 512 + c0 + lane];
    else       v = ((const int*)mask)[(size_t)row * 512 + c0 + lane];
    unsigned long long bits = __ballot(v != 0);
    if (lane == 0){
      mb[(size_t)row * 16 + (c0 >> 5)]     = (u32)(bits & 0xffffffffull);
      mb[(size_t)row * 16 + (c0 >> 5) + 1] = (u32)(bits >> 32);
    }
  }
}

// ---------------- embedding gather ----------------
__global__ void k_embed(const int* __restrict__ ids, const float* __restrict__ wemb,
                        float* __restrict__ h){
  int row = blockIdx.x;
  const float* s = wemb + (size_t)ids[row] * 768;
  float* d = h + (size_t)row * 768;
  int t = threadIdx.x;
  d[t] = s[t]; d[t + 256] = s[t + 256]; d[t + 512] = s[t + 512];
}

// ---------------- node-average (rows with pos==0) ----------------
__global__ void k_nodeavg(const int* __restrict__ pos, const u32* __restrict__ mb,
                          float* __restrict__ h){
  int row = blockIdx.x;                 // b*512+n
  if (pos[row] != 0) return;
  int b = row >> 9;
  int c = blockIdx.y * 256 + threadIdx.x;
  const u32* mrow = mb + (size_t)row * 16;
  const int* pb = pos + ((size_t)b << 9);
  float a = 0.f, cnt = 0.f;
  #pragma unroll 4
  for (int t = 0; t < 512; t++){
    if (pb[t] >= 2 && ((mrow[t >> 5] >> (t & 31)) & 1)){
      a += h[(((size_t)b << 9) + t) * 768 + c];
      cnt += 1.f;
    }
  }
  h[(size_t)row * 768 + c] = a / (cnt + 1e-10f);
}

// ---------------- LN kernels ----------------
__global__ void k_ln0(const int* __restrict__ pos, const float* __restrict__ pemb,
                      const float* __restrict__ g, const float* __restrict__ be,
                      float* __restrict__ h, u16* __restrict__ hb){
  __shared__ float s1[4], s2[4];
  int row = blockIdx.x, t = threadIdx.x;
  float* hr = h + (size_t)row * 768;
  const float* pr = pemb + (size_t)pos[row] * 768;
  float x0 = hr[t] + pr[t], x1 = hr[t+256] + pr[t+256], x2 = hr[t+512] + pr[t+512];
  float s = x0 + x1 + x2, q = x0*x0 + x1*x1 + x2*x2;
  for (int o = 32; o; o >>= 1){ s += __shfl_down(s, o, 64); q += __shfl_down(q, o, 64); }
  int wv = t >> 6, ln = t & 63;
  if (!ln){ s1[wv] = s; s2[wv] = q; }
  __syncthreads();
  s = s1[0]+s1[1]+s1[2]+s1[3]; q = s2[0]+s2[1]+s2[2]+s2[3];
  float mu = s * (1.f/768.f);
  float rs = rsqrtf(q * (1.f/768.f) - mu*mu + 1e-5f);
  u16* hbr = hb + (size_t)row * 768;
  float y;
  y = (x0-mu)*rs*g[t]     + be[t];     hr[t]     = y; hbr[t]     = f2bf(y);
  y = (x1-mu)*rs*g[t+256] + be[t+256]; hr[t+256] = y; hbr[t+256] = f2bf(y);
  y = (x2-mu)*rs*g[t+512] + be[t+512]; hr[t+512] = y; hbr[t+512] = f2bf(y);
}

__global__ void k_lnres(const float* __restrict__ C, const float* __restrict__ g,
                        const float* __restrict__ be, float* __restrict__ h,
                        u16* __restrict__ hb){
  __shared__ float s1[4], s2[4];
  int row = blockIdx.x, t = threadIdx.x;
  float* hr = h + (size_t)row * 768;
  const float* cr = C + (size_t)row * 768;
  float x0 = hr[t] + cr[t], x1 = hr[t+256] + cr[t+256], x2 = hr[t+512] + cr[t+512];
  float s = x0 + x1 + x2, q = x0*x0 + x1*x1 + x2*x2;
  for (int o = 32; o; o >>= 1){ s += __shfl_down(s, o, 64); q += __shfl_down(q, o, 64); }
  int wv = t >> 6, ln = t & 63;
  if (!ln){ s1[wv] = s; s2[wv] = q; }
  __syncthreads();
  s = s1[0]+s1[1]+s1[2]+s1[3]; q = s2[0]+s2[1]+s2[2]+s2[3];
  float mu = s * (1.f/768.f);
  float rs = rsqrtf(q * (1.f/768.f) - mu*mu + 1e-5f);
  u16* hbr = hb + (size_t)row * 768;
  float y;
  y = (x0-mu)*rs*g[t]     + be[t];     hr[t]     = y; hbr[t]     = f2bf(y);
  y = (x1-mu)*rs*g[t+256] + be[t+256]; hr[t+256] = y; hbr[t+256] = f2bf(y);
  y = (x2-mu)*rs*g[t+512] + be[t+512]; hr[t+512] = y; hbr[t+512] = f2bf(y);
}

// ---------------- weight transpose+cast: src[K][N] f32 -> dst[N][K] bf16 ----------------
__global__ void k_transpose(const float* __restrict__ src, u16* __restrict__ dst,
                            int K, int N){
  __shared__ float tile[32][33];
  int k0 = blockIdx.x * 32, n0 = blockIdx.y * 32;
  int tx = threadIdx.x & 31, ty = threadIdx.x >> 5;   // ty 0..7
  #pragma unroll
  for (int i = 0; i < 32; i += 8)
    tile[ty + i][tx] = src[(size_t)(k0 + ty + i) * N + n0 + tx];
  __syncthreads();
  #pragma unroll
  for (int i = 0; i < 32; i += 8)
    dst[(size_t)(n0 + ty + i) * K + k0 + tx] = f2bf(tile[tx][ty + i]);
}

// ================== 256x256 8-phase GEMM (T1+T2+T3+T4+T5), BT = [N][K] ==================
// EPI 0: bf16 out + bias; 1: f32 out + bias; 2: bf16 + bias + GELU;
// EPI 3: qkv scatter -> head-packed q/k/v buffers [b*12+h][512][64] bf16

DEVI void stage_half(const u16* __restrict__ P, int row0, int K, int kt, int h,
                     int boff, u16* sm, int w, int lane){
  #pragma unroll
  for (int j = 0; j < 2; j++){
    int ob = ((w*2 + j) << 10);          // wave-uniform byte offset within half
    int o  = ob + lane*16;
    int r  = (h << 7) + (o >> 7);
    int c  = ((o >> 4) & 7) ^ (r & 7);   // inverse-swizzled source chunk
    gload16(P + (size_t)(row0 + r)*K + (size_t)kt*64 + c*8,
            &sm[boff + (h << 13) + (ob >> 1)]);
  }
}

#define BAR() do { asm volatile("s_barrier" ::: "memory"); \
                   __builtin_amdgcn_sched_barrier(0); } while(0)

template<int EPI>
__global__ __launch_bounds__(512, 2)
void k_gemm2(const u16* __restrict__ A, const u16* __restrict__ BT,
             const float* __restrict__ bias, void* __restrict__ out,
             int M, int N, int K){
  __shared__ __align__(16) u16 sm[65536];   // 128 KiB
  const int tid = threadIdx.x;
  const int w = tid >> 6, lane = tid & 63;
  const int wm = w >> 2, wn = w & 3;
  const int cr = lane & 15, cg = lane >> 4;

  // bijective XCD-chunked remap (m204)
  const int nbn = gridDim.x;
  const int nwg = nbn * gridDim.y;
  const int d   = blockIdx.y * nbn + blockIdx.x;
  const int xcd = d & 7, qq = nwg >> 3, rr = nwg & 7;
  const int logical = (xcd < rr ? xcd*(qq+1) : rr*(qq+1) + (xcd-rr)*qq) + (d >> 3);
  const int m0 = (logical / nbn) * 256;
  const int n0 = (logical % nbn) * 256;

  const int NT = K >> 6;
  const int rowA = wm*128 + cr;
  const int rowB = wn*64  + cr;
  int slot[2];
  slot[0] = ((cg     ^ (cr & 7)) << 3);
  slot[1] = (((4+cg) ^ (cr & 7)) << 3);

  f32x4 acc[8][4] = {};
  bf16x8 bfr[4][2], afr[2][2];

#define LOADA(mf0) \
  _Pragma("unroll") for (int i = 0; i < 2; i++) \
    _Pragma("unroll") for (int s = 0; s < 2; s++) \
      afr[i][s] = *(const bf16x8*)&sm[ab + (rowA + ((mf0)+i)*16)*64 + slot[s]];

#define FMA2(mf0) \
  __builtin_amdgcn_s_setprio(1); \
  _Pragma("unroll") for (int n = 0; n < 4; n++){ \
    acc[(mf0)][n]   = MFMA(afr[0][0], bfr[n][0], acc[(mf0)][n]); \
    acc[(mf0)][n]   = MFMA(afr[0][1], bfr[n][1], acc[(mf0)][n]); \
    acc[(mf0)+1][n] = MFMA(afr[1][0], bfr[n][0], acc[(mf0)+1][n]); \
    acc[(mf0)+1][n] = MFMA(afr[1][1], bfr[n][1], acc[(mf0)+1][n]); \
  } \
  __builtin_amdgcn_s_setprio(0);

  // ---- prologue: tile0 (A+B) into buf0, B of tile1 into buf1
  stage_half(A,  m0, K, 0, 0, 0,     sm, w, lane);
  stage_half(A,  m0, K, 0, 1, 0,     sm, w, lane);
  stage_half(BT, n0, K, 0, 0, 32768, sm, w, lane);
  stage_half(BT, n0, K, 0, 1, 32768, sm, w, lane);
  if (NT > 1){
    stage_half(BT, n0, K, 1, 0, 32768+16384, sm, w, lane);
    stage_half(BT, n0, K, 1, 1, 32768+16384, sm, w, lane);
    asm volatile("s_waitcnt vmcnt(4)" ::: "memory");
  } else {
    asm volatile("s_waitcnt vmcnt(0)" ::: "memory");
  }
  __builtin_amdgcn_sched_barrier(0);
  BAR();

  for (int t = 0; t < NT; ++t){
    const int ab  = (t & 1) << 14;
    const int bb  = 32768 + ab;
    const int nb1 = ((t + 1) & 1) << 14;

    // ---- phase 0: all B-frags + A mf0-1; stage A0(t+1)
    #pragma unroll
    for (int n = 0; n < 4; n++)
      #pragma unroll
      for (int s = 0; s < 2; s++)
        bfr[n][s] = *(const bf16x8*)&sm[bb + (rowB + n*16)*64 + slot[s]];
    LOADA(0);
    if (t + 1 < NT) stage_half(A, m0, K, t+1, 0, nb1, sm, w, lane);
    BAR();
    FMA2(0);
    BAR();

    // ---- phase 1: A mf2-3; stage A1(t+1)
    LOADA(2);
    if (t + 1 < NT) stage_half(A, m0, K, t+1, 1, nb1, sm, w, lane);
    BAR();
    FMA2(2);
    BAR();

    // ---- phase 2: A mf4-5; stage B0(t+2)
    LOADA(4);
    if (t + 2 < NT) stage_half(BT, n0, K, t+2, 0, bb, sm, w, lane);
    BAR();
    FMA2(4);
    BAR();

    // ---- phase 3: A mf6-7; stage B1(t+2); counted vmcnt once per K-tile
    LOADA(6);
    if (t + 2 < NT) stage_half(BT, n0, K, t+2, 1, bb, sm, w, lane);
    BAR();
    FMA2(6);
    if (t + 2 < NT) { asm volatile("s_waitcnt vmcnt(4)" ::: "memory"); }
    else            { asm volatile("s_waitcnt vmcnt(0)" ::: "memory"); }
    __builtin_amdgcn_sched_barrier(0);
    BAR();
  }

  // ---- epilogue
  #pragma unroll
  for (int n = 0; n < 4; n++){
    int col = n0 + wn*64 + n*16 + cr;
    float bv = bias[col];
    int sec = 0, hd = 0, dcol = 0;
    if (EPI == 3){
      sec = (col >= 1536) ? 2 : (col >= 768 ? 1 : 0);
      hd  = (col - sec*768) >> 6;
      dcol = col & 63;
    }
    #pragma unroll
    for (int mf = 0; mf < 8; mf++){
      #pragma unroll
      for (int j = 0; j < 4; j++){
        int row = m0 + wm*128 + mf*16 + cg*4 + j;
        float v = acc[mf][n][j] + bv;
        if (EPI == 2) v = 0.5f * v * (1.f + erff(v * 0.70710678118654752f));
        if (EPI == 1)      ((float*)out)[(size_t)row * N + col] = v;
        else if (EPI == 3){
          int b = row >> 9, s = row & 511;
          ((u16*)out)[(size_t)sec*25165824 + (((size_t)(b*12 + hd)*512 + s) << 6) + dcol] = f2bf(v);
        }
        else               ((u16*) out)[(size_t)row * N + col] = f2bf(v);
      }
    }
  }
#undef LOADA
#undef FMA2
}

// ---------------- V^T repack: vbuf[bh][512][64] -> vt[bh][64][512] ----------------
__global__ void k_vtrep(const u16* __restrict__ vbuf, u16* __restrict__ vt){
  __shared__ u16 tile[64][72];
  int bh = blockIdx.y;               // b*12+h
  int t0 = blockIdx.x * 64;
  int tid = threadIdx.x;
  #pragma unroll
  for (int i = 0; i < 16; i++){
    int idx = tid + i * 256;
    int tt = idx >> 6, d = idx & 63;
    tile[tt][d] = vbuf[((size_t)bh * 512 + t0 + tt) * 64 + d];
  }
  __syncthreads();
  #pragma unroll
  for (int i = 0; i < 16; i++){
    int idx = tid + i * 256;
    int d = idx >> 6, tt = idx & 63;
    vt[((size_t)bh * 64 + d) * 512 + t0 + tt] = tile[tt][d];
  }
}

// ---------------- attention v2: swapped QK^T, per-wave softmax, no LDS, no barriers ----
// qp/kp: [bh][512][64] bf16; vt: [bh][64][512].
// Block = 4 waves; each wave owns 16 q-rows (q = qw..qw+15), all 512 kv.
// Swapped QK^T: acc = mfma(A=K_tile, B=Q) -> lane (cr,cg) holds P[q=qw+cr][kv=16t+cg*4+j].
// PV uses a per-lane kv permutation so the A-fragment is the lane's own P values:
//   chunk c (32 kv): e=0..3 -> kv 32c+4cg+e (tile 2c), e=4..7 -> kv 32c+16+4cg+e-4 (tile 2c+1)
//   V fragment loaded from vt with the same permutation (two 8B reads per d-block).
__global__ __launch_bounds__(256)
void k_attn2(const u16* __restrict__ qp, const u16* __restrict__ kp,
             const u16* __restrict__ vt, const u32* __restrict__ mb,
             u16* __restrict__ ctx){
  const int tid = threadIdx.x, wv = tid >> 6, lane = tid & 63;
  const int cr = lane & 15, cg = lane >> 4;

  // XCD-chunked remap: 6144 blocks, 768 per XCD => 96 whole heads per XCD
  const int dd = blockIdx.x + (blockIdx.y << 3);
  const int logical = (dd & 7) * 768 + (dd >> 3);
  const int bh = logical >> 3;
  const int qblk = logical & 7;
  const int b = bh / 12, hh = bh % 12;
  const int qw = qblk * 64 + wv * 16;
  const int qrow = qw + cr;
  const size_t base = (size_t)bh * 512 * 64;

  // Q B-operand fragments (d 0-31, 32-63)
  bf16x8 qB[2];
  #pragma unroll
  for (int ks = 0; ks < 2; ks++)
    qB[ks] = *(const bf16x8*)&qp[base + (size_t)qrow * 64 + ks*32 + cg*8];

  // mask words for this lane's q-row
  u32 mw[16];
  {
    const u32* mrow = mb + ((size_t)b * 512 + qrow) * 16;
    #pragma unroll
    for (int i = 0; i < 4; i++){
      uint4 v4 = *(const uint4*)&mrow[i*4];
      mw[i*4+0] = v4.x; mw[i*4+1] = v4.y; mw[i*4+2] = v4.z; mw[i*4+3] = v4.w;
    }
  }

  // ---- QK^T: 32 kv-tiles of 16
  f32x4 pacc[32];
  #pragma unroll
  for (int t = 0; t < 32; t++){
    bf16x8 kA0 = *(const bf16x8*)&kp[base + (size_t)(t*16 + cr) * 64 + cg*8];
    bf16x8 kA1 = *(const bf16x8*)&kp[base + (size_t)(t*16 + cr) * 64 + 32 + cg*8];
    f32x4 z = {0.f, 0.f, 0.f, 0.f};
    z = MFMA(kA0, qB[0], z);
    z = MFMA(kA1, qB[1], z);
    pacc[t] = z;
  }

  // ---- scale + mask bias + row max
  const int cg4 = cg * 4;
  f32x4 vm = {-3e38f, -3e38f, -3e38f, -3e38f};
  #pragma unroll
  for (int t = 0; t < 32; t++){
    u32 nib = (mw[t >> 1] >> ((t & 1) * 16 + cg4)) & 0xFu;
    #pragma unroll
    for (int j = 0; j < 4; j++){
      float bj = ((nib >> j) & 1u) ? 0.f : -10000.f;
      float v = pacc[t][j] * 0.125f + bj;
      pacc[t][j] = v;
      vm[j] = fmaxf(vm[j], v);
    }
  }
  float m = fmaxf(fmaxf(vm[0], vm[1]), fmaxf(vm[2], vm[3]));
  m = fmaxf(m, __shfl_xor(m, 16, 64));
  m = fmaxf(m, __shfl_xor(m, 32, 64));

  // ---- exp + row sum
  f32x4 vs = {0.f, 0.f, 0.f, 0.f};
  #pragma unroll
  for (int t = 0; t < 32; t++){
    #pragma unroll
    for (int j = 0; j < 4; j++){
      float e = __expf(pacc[t][j] - m);
      pacc[t][j] = e;
      vs[j] += e;
    }
  }
  float rs = vs[0] + vs[1] + vs[2] + vs[3];
  rs += __shfl_xor(rs, 16, 64);
  rs += __shfl_xor(rs, 32, 64);

  // ---- PV: 16 chunks of 32 kv, 4 d-blocks of 16
  f32x4 oacc[4] = {};
  const u16* vbase = vt + (size_t)bh * 64 * 512;
  #pragma unroll
  for (int c = 0; c < 16; c++){
    bf16x8 pa;
    #pragma unroll
    for (int e = 0; e < 4; e++){
      pa[e]   = (__bf16)pacc[2*c][e];
      pa[4+e] = (__bf16)pacc[2*c+1][e];
    }
    #pragma unroll
    for (int db = 0; db < 4; db++){
      const u16* vrow = vbase + (size_t)(16*db + cr) * 512 + 32*c + cg4;
      bf16x8 vb;
      ((uint2*)&vb)[0] = *(const uint2*)vrow;          // kv 32c+4cg..+3
      ((uint2*)&vb)[1] = *(const uint2*)(vrow + 16);   // kv 32c+16+4cg..+3
      oacc[db] = MFMA(pa, vb, oacc[db]);
    }
  }

  // ---- epilogue: O[q=qw+cg*4+j][d=16db+cr] / rowsum
  #pragma unroll
  for (int j = 0; j < 4; j++){
    float ds = __shfl(rs, cg4 + j, 64);   // lane (cr=cg4+j, cg=0) holds that q-row's sum
    float inv = 1.0f / ds;
    #pragma unroll
    for (int db = 0; db < 4; db++)
      ctx[((size_t)b * 512 + qw + cg4 + j) * 768 + hh*64 + 16*db + cr] = f2bf(oacc[db][j] * inv);
  }
}

// ---------------- head: dense+tanh then scalar logit ----------------
__global__ void k_dense(const float* __restrict__ h, const float* __restrict__ W,
                        const float* __restrict__ bias, float* __restrict__ xt){
  __shared__ float xs[768];
  int b = blockIdx.x, t = threadIdx.x;
  const float* hr = h + (size_t)b * 512 * 768;
  xs[t] = hr[t]; xs[t+256] = hr[t+256]; xs[t+512] = hr[t+512];
  __syncthreads();
  for (int j = t; j < 768; j += 256){
    float a = bias[j];
    #pragma unroll 4
    for (int k = 0; k < 768; k++) a += xs[k] * W[(size_t)k * 768 + j];
    xt[(size_t)b * 768 + j] = tanhf(a);
  }
}

__global__ void k_logits(const float* __restrict__ xt, const float* __restrict__ ow,
                         const float* __restrict__ ob, float* __restrict__ out){
  __shared__ float sb[4];
  int b = blockIdx.x, t = threadIdx.x;
  const float* x = xt + (size_t)b * 768;
  float s = x[t]*ow[t] + x[t+256]*ow[t+256] + x[t+512]*ow[t+512];
  for (int o = 32; o; o >>= 1) s += __shfl_down(s, o, 64);
  int wv = t >> 6, ln = t & 63;
  if (!ln) sb[wv] = s;
  __syncthreads();
  if (t == 0) out[b] = sb[0] + sb[1] + sb[2] + sb[3] + ob[0];
}

// ---------------- launch ----------------
extern "C" void kernel_launch(void* const* d_in, const int* in_sizes, int n_in,
                              void* d_out, int out_size, void* d_ws, size_t ws_size,
                              hipStream_t stream){
  if (n_in < 23) return;
  if (ws_size < 534000000ull) return;

  const int*   ids  = (const int*)  d_in[0];
  const int*   pos  = (const int*)  d_in[1];
  const void*  amsk =               d_in[2];
  const float* wemb = (const float*)d_in[3];
  const float* pemb = (const float*)d_in[4];
  const float* lng  = (const float*)d_in[5];
  const float* lnb  = (const float*)d_in[6];
  const float* Wqkv = (const float*)d_in[7];
  const float* bqkv = (const float*)d_in[8];
  const float* Wo   = (const float*)d_in[9];
  const float* bo   = (const float*)d_in[10];
  const float* ln1g = (const float*)d_in[11];
  const float* ln1b = (const float*)d_in[12];
  const float* W1   = (const float*)d_in[13];
  const float* b1   = (const float*)d_in[14];
  const float* W2   = (const float*)d_in[15];
  const float* b2   = (const float*)d_in[16];
  const float* ln2g = (const float*)d_in[17];
  const float* ln2b = (const float*)d_in[18];
  const float* dW   = (const float*)d_in[19];
  const float* db   = (const float*)d_in[20];
  const float* oW   = (const float*)d_in[21];
  const float* ob   = (const float*)d_in[22];

  char* ws = (char*)d_ws;
  float* h    = (float*)(ws);
  u16*   hb   = (u16*)  (ws + 100663296);
  float* C    = (float*)(ws + 150994944);
  u16*   qkvp = (u16*)  (ws + 251658240);   // qp | kp | vbuf, each 50331648 B
  u16*   vt   = (u16*)  (ws + 402653184);
  u16*   act  = (u16*)  (ws + 251658240);   // aliases qkvp+vt (disjoint lifetime)
  u16*   ctx  = (u16*)  (ws + 452984832);
  u32*   mbit = (u32*)  (ws + 503316480);
  u16*   wt   = (u16*)  (ws + 505413632);
  float* xt   = (float*)(ws + 533725184);
  int*   flag = (int*)  (ws + 533921792);

  u16* qp   = qkvp;
  u16* kp   = qkvp + (size_t)25165824;
  u16* vbuf = qkvp + (size_t)50331648;

  u16* WqkvT = wt;                                  // [l][2304][768]
  u16* WoT   = WqkvT + (size_t)2*2304*768;          // [l][768][768]
  u16* W1T   = WoT   + (size_t)2*768*768;           // [l][3072][768]
  u16* W2T   = W1T   + (size_t)2*3072*768;          // [l][768][3072]

  k_maskprobe<<<1, 256, 0, stream>>>((const unsigned char*)amsk, flag);
  k_maskbits<<<8192, 256, 0, stream>>>(amsk, flag, mbit);

  for (int l = 0; l < 2; l++){
    k_transpose<<<dim3(24, 72), 256, 0, stream>>>(Wqkv + (size_t)l*768*2304, WqkvT + (size_t)l*2304*768, 768, 2304);
    k_transpose<<<dim3(24, 24), 256, 0, stream>>>(Wo   + (size_t)l*768*768,  WoT   + (size_t)l*768*768,  768, 768);
    k_transpose<<<dim3(24, 96), 256, 0, stream>>>(W1   + (size_t)l*768*3072, W1T   + (size_t)l*3072*768, 768, 3072);
    k_transpose<<<dim3(96, 24), 256, 0, stream>>>(W2   + (size_t)l*3072*768, W2T   + (size_t)l*768*3072, 3072, 768);
  }

  k_embed<<<32768, 256, 0, stream>>>(ids, wemb, h);
  k_nodeavg<<<dim3(32768, 3), 256, 0, stream>>>(pos, mbit, h);
  k_ln0<<<32768, 256, 0, stream>>>(pos, pemb, lng, lnb, h, hb);

  for (int l = 0; l < 2; l++){
    k_gemm2<3><<<dim3(9, 128), 512, 0, stream>>>(hb, WqkvT + (size_t)l*2304*768, bqkv + l*2304, (void*)qkvp, 32768, 2304, 768);
    k_vtrep<<<dim3(8, 768), 256, 0, stream>>>(vbuf, vt);
    k_attn2<<<dim3(8, 768), 256, 0, stream>>>(qp, kp, vt, mbit, ctx);
    k_gemm2<1><<<dim3(3, 128), 512, 0, stream>>>(ctx, WoT + (size_t)l*768*768, bo + l*768, (void*)C, 32768, 768, 768);
    k_lnres<<<32768, 256, 0, stream>>>(C, ln1g + l*768, ln1b + l*768, h, hb);
    k_gemm2<2><<<dim3(12, 128), 512, 0, stream>>>(hb, W1T + (size_t)l*3072*768, b1 + l*3072, (void*)act, 32768, 3072, 768);
    k_gemm2<1><<<dim3(3, 128), 512, 0, stream>>>(act, W2T + (size_t)l*768*3072, b2 + l*768, (void*)C, 32768, 768, 3072);
    k_lnres<<<32768, 256, 0, stream>>>(C, ln2g + l*768, ln2b + l*768, h, hb);
  }

  k_dense<<<64, 256, 0, stream>>>(h, dW, db, xt);
  k_logits<<<64, 256, 0, stream>>>(xt, oW, ob, (float*)d_out);
}

// Round 7
// 2396.770 us; speedup vs baseline: 1.4055x; 1.4055x over previous
//
#include <hip/hip_runtime.h>

typedef unsigned short u16;
typedef unsigned int   u32;
typedef __bf16 bf16x8 __attribute__((ext_vector_type(8)));
typedef float  f32x4  __attribute__((ext_vector_type(4)));

#define DEVI __device__ __forceinline__

DEVI u16 f2bf(float f){
  u32 u = __builtin_bit_cast(u32, f);
  u32 r = (u + 0x7fffu + ((u >> 16) & 1u)) >> 16;   // RNE
  return (u16)r;
}

DEVI void gload16(const void* g, void* lds){
  __builtin_amdgcn_global_load_lds(
      (const __attribute__((address_space(1))) void*)g,
      (__attribute__((address_space(3))) void*)lds, 16, 0, 0);
}

DEVI f32x4 MFMA(bf16x8 a, bf16x8 b, f32x4 c){
  return __builtin_amdgcn_mfma_f32_16x16x32_bf16(a, b, c, 0, 0, 0);
}

// ---------------- mask dtype probe: 1 => uint8 bytes, 0 => int32 ----------------
__global__ void k_maskprobe(const unsigned char* __restrict__ m, int* __restrict__ flag){
  __shared__ int s;
  if (threadIdx.x == 0) s = 0;
  __syncthreads();
  int acc = 0;
  for (int i = threadIdx.x; i < 65536; i += 256)
    if ((i & 3) != 0 && m[i] != 0) acc++;
  atomicAdd(&s, acc);
  __syncthreads();
  if (threadIdx.x == 0) *flag = (s > 0) ? 1 : 0;
}

// ---------------- pack attn_mask to bitmask [B*S][16 words] ----------------
__global__ void k_maskbits(const void* __restrict__ mask, const int* __restrict__ flag,
                           u32* __restrict__ mb){
  int row  = blockIdx.x * 4 + (threadIdx.x >> 6);   // b*512+q
  int lane = threadIdx.x & 63;
  bool bytes = (*flag != 0);
  for (int c0 = 0; c0 < 512; c0 += 64){
    int v;
    if (bytes) v = ((const unsigned char*)mask)[(size_t)row * 512 + c0 + lane];
    else       v = ((const int*)mask)[(size_t)row * 512 + c0 + lane];
    unsigned long long bits = __ballot(v != 0);
    if (lane == 0){
      mb[(size_t)row * 16 + (c0 >> 5)]     = (u32)(bits & 0xffffffffull);
      mb[(size_t)row * 16 + (c0 >> 5) + 1] = (u32)(bits >> 32);
    }
  }
}

// ---------------- embedding gather ----------------
__global__ void k_embed(const int* __restrict__ ids, const float* __restrict__ wemb,
                        float* __restrict__ h){
  int row = blockIdx.x;
  const float* s = wemb + (size_t)ids[row] * 768;
  float* d = h + (size_t)row * 768;
  int t = threadIdx.x;
  d[t] = s[t]; d[t + 256] = s[t + 256]; d[t + 512] = s[t + 512];
}

// ---------------- node-average (rows with pos==0) ----------------
__global__ void k_nodeavg(const int* __restrict__ pos, const u32* __restrict__ mb,
                          float* __restrict__ h){
  int row = blockIdx.x;                 // b*512+n
  if (pos[row] != 0) return;
  int b = row >> 9;
  int c = blockIdx.y * 256 + threadIdx.x;
  const u32* mrow = mb + (size_t)row * 16;
  const int* pb = pos + ((size_t)b << 9);
  float a = 0.f, cnt = 0.f;
  #pragma unroll 4
  for (int t = 0; t < 512; t++){
    if (pb[t] >= 2 && ((mrow[t >> 5] >> (t & 31)) & 1)){
      a += h[(((size_t)b << 9) + t) * 768 + c];
      cnt += 1.f;
    }
  }
  h[(size_t)row * 768 + c] = a / (cnt + 1e-10f);
}

// ---------------- LN kernels ----------------
__global__ void k_ln0(const int* __restrict__ pos, const float* __restrict__ pemb,
                      const float* __restrict__ g, const float* __restrict__ be,
                      float* __restrict__ h, u16* __restrict__ hb){
  __shared__ float s1[4], s2[4];
  int row = blockIdx.x, t = threadIdx.x;
  float* hr = h + (size_t)row * 768;
  const float* pr = pemb + (size_t)pos[row] * 768;
  float x0 = hr[t] + pr[t], x1 = hr[t+256] + pr[t+256], x2 = hr[t+512] + pr[t+512];
  float s = x0 + x1 + x2, q = x0*x0 + x1*x1 + x2*x2;
  for (int o = 32; o; o >>= 1){ s += __shfl_down(s, o, 64); q += __shfl_down(q, o, 64); }
  int wv = t >> 6, ln = t & 63;
  if (!ln){ s1[wv] = s; s2[wv] = q; }
  __syncthreads();
  s = s1[0]+s1[1]+s1[2]+s1[3]; q = s2[0]+s2[1]+s2[2]+s2[3];
  float mu = s * (1.f/768.f);
  float rs = rsqrtf(q * (1.f/768.f) - mu*mu + 1e-5f);
  u16* hbr = hb + (size_t)row * 768;
  float y;
  y = (x0-mu)*rs*g[t]     + be[t];     hr[t]     = y; hbr[t]     = f2bf(y);
  y = (x1-mu)*rs*g[t+256] + be[t+256]; hr[t+256] = y; hbr[t+256] = f2bf(y);
  y = (x2-mu)*rs*g[t+512] + be[t+512]; hr[t+512] = y; hbr[t+512] = f2bf(y);
}

__global__ void k_lnres(const float* __restrict__ C, const float* __restrict__ g,
                        const float* __restrict__ be, float* __restrict__ h,
                        u16* __restrict__ hb){
  __shared__ float s1[4], s2[4];
  int row = blockIdx.x, t = threadIdx.x;
  float* hr = h + (size_t)row * 768;
  const float* cr = C + (size_t)row * 768;
  float x0 = hr[t] + cr[t], x1 = hr[t+256] + cr[t+256], x2 = hr[t+512] + cr[t+512];
  float s = x0 + x1 + x2, q = x0*x0 + x1*x1 + x2*x2;
  for (int o = 32; o; o >>= 1){ s += __shfl_down(s, o, 64); q += __shfl_down(q, o, 64); }
  int wv = t >> 6, ln = t & 63;
  if (!ln){ s1[wv] = s; s2[wv] = q; }
  __syncthreads();
  s = s1[0]+s1[1]+s1[2]+s1[3]; q = s2[0]+s2[1]+s2[2]+s2[3];
  float mu = s * (1.f/768.f);
  float rs = rsqrtf(q * (1.f/768.f) - mu*mu + 1e-5f);
  u16* hbr = hb + (size_t)row * 768;
  float y;
  y = (x0-mu)*rs*g[t]     + be[t];     hr[t]     = y; hbr[t]     = f2bf(y);
  y = (x1-mu)*rs*g[t+256] + be[t+256]; hr[t+256] = y; hbr[t+256] = f2bf(y);
  y = (x2-mu)*rs*g[t+512] + be[t+512]; hr[t+512] = y; hbr[t+512] = f2bf(y);
}

// ---------------- weight transpose+cast: src[K][N] f32 -> dst[N][K] bf16 ----------------
__global__ void k_transpose(const float* __restrict__ src, u16* __restrict__ dst,
                            int K, int N){
  __shared__ float tile[32][33];
  int k0 = blockIdx.x * 32, n0 = blockIdx.y * 32;
  int tx = threadIdx.x & 31, ty = threadIdx.x >> 5;   // ty 0..7
  #pragma unroll
  for (int i = 0; i < 32; i += 8)
    tile[ty + i][tx] = src[(size_t)(k0 + ty + i) * N + n0 + tx];
  __syncthreads();
  #pragma unroll
  for (int i = 0; i < 32; i += 8)
    dst[(size_t)(n0 + ty + i) * K + k0 + tx] = f2bf(tile[tx][ty + i]);
}

// ================== 256x256 8-phase GEMM (T1+T2+T3+T4+T5), BT = [N][K] ==================
// EPI 0: bf16 out + bias; 1: f32 out + bias; 2: bf16 + bias + GELU;
// EPI 3: qkv scatter -> head-packed q/k/v buffers [b*12+h][512][64] bf16

DEVI void stage_half(const u16* __restrict__ P, int row0, int K, int kt, int h,
                     int boff, u16* sm, int w, int lane){
  #pragma unroll
  for (int j = 0; j < 2; j++){
    int ob = ((w*2 + j) << 10);          // wave-uniform byte offset within half
    int o  = ob + lane*16;
    int r  = (h << 7) + (o >> 7);
    int c  = ((o >> 4) & 7) ^ (r & 7);   // inverse-swizzled source chunk
    gload16(P + (size_t)(row0 + r)*K + (size_t)kt*64 + c*8,
            &sm[boff + (h << 13) + (ob >> 1)]);
  }
}

#define BAR() do { asm volatile("s_barrier" ::: "memory"); \
                   __builtin_amdgcn_sched_barrier(0); } while(0)

template<int EPI>
__global__ __launch_bounds__(512, 2)
void k_gemm2(const u16* __restrict__ A, const u16* __restrict__ BT,
             const float* __restrict__ bias, void* __restrict__ out,
             int M, int N, int K){
  __shared__ __align__(16) u16 sm[65536];   // 128 KiB
  const int tid = threadIdx.x;
  const int w = tid >> 6, lane = tid & 63;
  const int wm = w >> 2, wn = w & 3;
  const int cr = lane & 15, cg = lane >> 4;

  // bijective XCD-chunked remap (m204)
  const int nbn = gridDim.x;
  const int nwg = nbn * gridDim.y;
  const int d   = blockIdx.y * nbn + blockIdx.x;
  const int xcd = d & 7, qq = nwg >> 3, rr = nwg & 7;
  const int logical = (xcd < rr ? xcd*(qq+1) : rr*(qq+1) + (xcd-rr)*qq) + (d >> 3);
  const int m0 = (logical / nbn) * 256;
  const int n0 = (logical % nbn) * 256;

  const int NT = K >> 6;
  const int rowA = wm*128 + cr;
  const int rowB = wn*64  + cr;
  int slot[2];
  slot[0] = ((cg     ^ (cr & 7)) << 3);
  slot[1] = (((4+cg) ^ (cr & 7)) << 3);

  f32x4 acc[8][4] = {};
  bf16x8 bfr[4][2], afr[2][2];

#define LOADA(mf0) \
  _Pragma("unroll") for (int i = 0; i < 2; i++) \
    _Pragma("unroll") for (int s = 0; s < 2; s++) \
      afr[i][s] = *(const bf16x8*)&sm[ab + (rowA + ((mf0)+i)*16)*64 + slot[s]];

#define FMA2(mf0) \
  __builtin_amdgcn_s_setprio(1); \
  _Pragma("unroll") for (int n = 0; n < 4; n++){ \
    acc[(mf0)][n]   = MFMA(afr[0][0], bfr[n][0], acc[(mf0)][n]); \
    acc[(mf0)][n]   = MFMA(afr[0][1], bfr[n][1], acc[(mf0)][n]); \
    acc[(mf0)+1][n] = MFMA(afr[1][0], bfr[n][0], acc[(mf0)+1][n]); \
    acc[(mf0)+1][n] = MFMA(afr[1][1], bfr[n][1], acc[(mf0)+1][n]); \
  } \
  __builtin_amdgcn_s_setprio(0);

  // ---- prologue: tile0 (A+B) into buf0, B of tile1 into buf1
  stage_half(A,  m0, K, 0, 0, 0,     sm, w, lane);
  stage_half(A,  m0, K, 0, 1, 0,     sm, w, lane);
  stage_half(BT, n0, K, 0, 0, 32768, sm, w, lane);
  stage_half(BT, n0, K, 0, 1, 32768, sm, w, lane);
  if (NT > 1){
    stage_half(BT, n0, K, 1, 0, 32768+16384, sm, w, lane);
    stage_half(BT, n0, K, 1, 1, 32768+16384, sm, w, lane);
    asm volatile("s_waitcnt vmcnt(4)" ::: "memory");
  } else {
    asm volatile("s_waitcnt vmcnt(0)" ::: "memory");
  }
  __builtin_amdgcn_sched_barrier(0);
  BAR();

  for (int t = 0; t < NT; ++t){
    const int ab  = (t & 1) << 14;
    const int bb  = 32768 + ab;
    const int nb1 = ((t + 1) & 1) << 14;

    // ---- phase 0: all B-frags + A mf0-1; stage A0(t+1)
    #pragma unroll
    for (int n = 0; n < 4; n++)
      #pragma unroll
      for (int s = 0; s < 2; s++)
        bfr[n][s] = *(const bf16x8*)&sm[bb + (rowB + n*16)*64 + slot[s]];
    LOADA(0);
    if (t + 1 < NT) stage_half(A, m0, K, t+1, 0, nb1, sm, w, lane);
    BAR();
    FMA2(0);
    BAR();

    // ---- phase 1: A mf2-3; stage A1(t+1)
    LOADA(2);
    if (t + 1 < NT) stage_half(A, m0, K, t+1, 1, nb1, sm, w, lane);
    BAR();
    FMA2(2);
    BAR();

    // ---- phase 2: A mf4-5; stage B0(t+2)
    LOADA(4);
    if (t + 2 < NT) stage_half(BT, n0, K, t+2, 0, bb, sm, w, lane);
    BAR();
    FMA2(4);
    BAR();

    // ---- phase 3: A mf6-7; stage B1(t+2); counted vmcnt once per K-tile
    LOADA(6);
    if (t + 2 < NT) stage_half(BT, n0, K, t+2, 1, bb, sm, w, lane);
    BAR();
    FMA2(6);
    if (t + 2 < NT) { asm volatile("s_waitcnt vmcnt(4)" ::: "memory"); }
    else            { asm volatile("s_waitcnt vmcnt(0)" ::: "memory"); }
    __builtin_amdgcn_sched_barrier(0);
    BAR();
  }

  // ---- epilogue
  #pragma unroll
  for (int n = 0; n < 4; n++){
    int col = n0 + wn*64 + n*16 + cr;
    float bv = bias[col];
    int sec = 0, hd = 0, dcol = 0;
    if (EPI == 3){
      sec = (col >= 1536) ? 2 : (col >= 768 ? 1 : 0);
      hd  = (col - sec*768) >> 6;
      dcol = col & 63;
    }
    #pragma unroll
    for (int mf = 0; mf < 8; mf++){
      #pragma unroll
      for (int j = 0; j < 4; j++){
        int row = m0 + wm*128 + mf*16 + cg*4 + j;
        float v = acc[mf][n][j] + bv;
        if (EPI == 2) v = 0.5f * v * (1.f + erff(v * 0.70710678118654752f));
        if (EPI == 1)      ((float*)out)[(size_t)row * N + col] = v;
        else if (EPI == 3){
          int b = row >> 9, s = row & 511;
          ((u16*)out)[(size_t)sec*25165824 + (((size_t)(b*12 + hd)*512 + s) << 6) + dcol] = f2bf(v);
        }
        else               ((u16*) out)[(size_t)row * N + col] = f2bf(v);
      }
    }
  }
#undef LOADA
#undef FMA2
}

// ---------------- V^T repack: vbuf[bh][512][64] -> vt[bh][64][512] ----------------
__global__ void k_vtrep(const u16* __restrict__ vbuf, u16* __restrict__ vt){
  __shared__ u16 tile[64][72];
  int bh = blockIdx.y;               // b*12+h
  int t0 = blockIdx.x * 64;
  int tid = threadIdx.x;
  #pragma unroll
  for (int i = 0; i < 16; i++){
    int idx = tid + i * 256;
    int tt = idx >> 6, d = idx & 63;
    tile[tt][d] = vbuf[((size_t)bh * 512 + t0 + tt) * 64 + d];
  }
  __syncthreads();
  #pragma unroll
  for (int i = 0; i < 16; i++){
    int idx = tid + i * 256;
    int d = idx >> 6, tt = idx & 63;
    vt[((size_t)bh * 64 + d) * 512 + t0 + tt] = tile[tt][d];
  }
}

// ---------------- attention v3: flash/online, swapped QK^T, LDS-staged K & V^T ----------
// qp/kp: [bh][512][64] bf16; vt: [bh][64][512].
// Block = 4 waves (256 thr); wave owns 16 q-rows (q = qblk*64 + wv*16 + cr via C-col).
// 8 kv-steps of 64; K-tile [64][64] and V^T-tile [64 d][64 kv] double-buffered in LDS,
// both stored with 16B-chunk XOR swizzle (chunk ^= row&7), staged via inverse-swizzled
// global_load_lds sources (rule #21). Online softmax per lane (full row in-register).
// PV uses per-lane kv-permutation: pa[e] = P[kv 32c+4cg+e / 32c+16+4cg+e-4]; vb matches.

DEVI void stage64(const u16* __restrict__ src, int stride, u16* lds, int w, int lane){
  #pragma unroll
  for (int j = 0; j < 2; j++){
    int p  = j*256 + w*64 + lane;        // piece 0..511 (16B each)
    int r  = p >> 3;                     // row 0..63
    int c8 = (p & 7) ^ (r & 7);          // inverse-swizzled source chunk
    gload16(src + (size_t)r*stride + c8*8, lds + (size_t)p*8);
  }
}

__global__ __launch_bounds__(256, 4)
void k_attn3(const u16* __restrict__ qp, const u16* __restrict__ kp,
             const u16* __restrict__ vt, const u32* __restrict__ mb,
             u16* __restrict__ ctx){
  __shared__ __align__(16) u16 Ks[8192];   // 2 x [64][64]
  __shared__ __align__(16) u16 Vs[8192];   // 2 x [64 d][64 kv]
  const int tid = threadIdx.x, wv = tid >> 6, lane = tid & 63;
  const int cr = lane & 15, cg = lane >> 4;
  const int cg4 = cg * 4;
  const int r7 = cr & 7;

  // XCD-chunked remap: 6144 blocks, 768/XCD => 96 whole heads per XCD
  const int dd = blockIdx.x + (blockIdx.y << 3);
  const int logical = (dd & 7) * 768 + (dd >> 3);
  const int bh = logical >> 3;
  const int qblk = logical & 7;
  const int b = bh / 12, hh = bh % 12;
  const int qw = qblk * 64 + wv * 16;
  const int qrow = qw + cr;
  const size_t base = (size_t)bh * 512 * 64;
  const u16* vtb = vt + (size_t)bh * 64 * 512;

  const int slot0 = ((cg    ) ^ r7) << 3;
  const int slot1 = ((4 + cg) ^ r7) << 3;

  // Q B-operand fragments (d 0-31, 32-63)
  bf16x8 qB[2];
  #pragma unroll
  for (int ks = 0; ks < 2; ks++)
    qB[ks] = *(const bf16x8*)&qp[base + (size_t)qrow * 64 + ks*32 + cg*8];

  // mask words for this lane's q-row
  u32 mw[16];
  {
    const u32* mrow = mb + ((size_t)b * 512 + qrow) * 16;
    #pragma unroll
    for (int i = 0; i < 4; i++){
      uint4 v4 = *(const uint4*)&mrow[i*4];
      mw[i*4+0] = v4.x; mw[i*4+1] = v4.y; mw[i*4+2] = v4.z; mw[i*4+3] = v4.w;
    }
  }

  // prologue: stage step 0 into buf 0
  stage64(kp + base, 64, Ks, wv, lane);
  stage64(vtb,      512, Vs, wv, lane);
  asm volatile("s_waitcnt vmcnt(0)" ::: "memory");
  __builtin_amdgcn_sched_barrier(0);
  BAR();

  float m = -3e38f, vs = 0.f;
  f32x4 oacc[4] = {};

  for (int s = 0; s < 8; ++s){
    const int buf = (s & 1) << 12;       // u16 offset of current buffer
    const int nbf = ((s + 1) & 1) << 12;

    if (s + 1 < 8){
      stage64(kp + base + (size_t)(s+1)*4096, 64, Ks + nbf, wv, lane);
      stage64(vtb + (size_t)(s+1)*64,        512, Vs + nbf, wv, lane);
    }

    // ---- QK^T: 4 tiles of 16 kv from LDS
    f32x4 pacc[4];
    #pragma unroll
    for (int tt = 0; tt < 4; tt++){
      bf16x8 a0 = *(const bf16x8*)&Ks[buf + (tt*16 + cr)*64 + slot0];
      bf16x8 a1 = *(const bf16x8*)&Ks[buf + (tt*16 + cr)*64 + slot1];
      f32x4 z = {0.f, 0.f, 0.f, 0.f};
      z = MFMA(a0, qB[0], z);
      z = MFMA(a1, qB[1], z);
      pacc[tt] = z;
    }

    // ---- mask + scale + tile-max
    const u32 w0 = mw[2*s], w1 = mw[2*s+1];
    f32x4 vmx = {-3e38f, -3e38f, -3e38f, -3e38f};
    #pragma unroll
    for (int tt = 0; tt < 4; tt++){
      u32 nib = (((tt < 2) ? w0 : w1) >> (16*(tt & 1) + cg4)) & 0xFu;
      #pragma unroll
      for (int j = 0; j < 4; j++){
        float v = pacc[tt][j] * 0.125f + (((nib >> j) & 1u) ? 0.f : -10000.f);
        pacc[tt][j] = v;
        vmx[j] = fmaxf(vmx[j], v);
      }
    }
    float tm = fmaxf(fmaxf(vmx[0], vmx[1]), fmaxf(vmx[2], vmx[3]));
    tm = fmaxf(tm, __shfl_xor(tm, 16, 64));
    tm = fmaxf(tm, __shfl_xor(tm, 32, 64));

    float mnew = fmaxf(m, tm);
    float alpha = __expf(m - mnew);
    m = mnew;
    #pragma unroll
    for (int db = 0; db < 4; db++) oacc[db] *= alpha;

    // ---- exp + partial sum (per-lane slice; m is row-uniform)
    f32x4 vsum = {0.f, 0.f, 0.f, 0.f};
    #pragma unroll
    for (int tt = 0; tt < 4; tt++){
      #pragma unroll
      for (int j = 0; j < 4; j++){
        float e = __expf(pacc[tt][j] - m);
        pacc[tt][j] = e;
        vsum[j] += e;
      }
    }
    vs = vs * alpha + (vsum[0] + vsum[1] + vsum[2] + vsum[3]);

    // ---- P -> bf16 with kv permutation
    bf16x8 pa[2];
    #pragma unroll
    for (int c = 0; c < 2; c++)
      #pragma unroll
      for (int e = 0; e < 4; e++){
        pa[c][e]   = (__bf16)pacc[2*c][e];
        pa[c][4+e] = (__bf16)pacc[2*c+1][e];
      }

    // ---- PV from swizzled Vs: vb[e] = V^T[d][32c+4cg+e], [32c+16+4cg+e-4]
    #pragma unroll
    for (int c = 0; c < 2; c++){
      const int ch0 = ((4*c     + (cg >> 1)) ^ r7);
      const int ch1 = ((4*c + 2 + (cg >> 1)) ^ r7);
      const int sub = (cg & 1) << 3;
      #pragma unroll
      for (int db = 0; db < 4; db++){
        const char* vrow = (const char*)&Vs[buf + (db*16 + cr)*64];
        bf16x8 vb;
        ((uint2*)&vb)[0] = *(const uint2*)(vrow + (ch0 << 4) + sub);
        ((uint2*)&vb)[1] = *(const uint2*)(vrow + (ch1 << 4) + sub);
        oacc[db] = MFMA(pa[c], vb, oacc[db]);
      }
    }

    if (s + 1 < 8) { asm volatile("s_waitcnt vmcnt(0)" ::: "memory"); }
    __builtin_amdgcn_sched_barrier(0);
    BAR();
  }

  // ---- epilogue: O[q=qw+cg4+j][d=16db+cr] / rowsum
  vs += __shfl_xor(vs, 16, 64);
  vs += __shfl_xor(vs, 32, 64);
  #pragma unroll
  for (int j = 0; j < 4; j++){
    float ds = __shfl(vs, cg4 + j, 64);
    float inv = 1.0f / ds;
    #pragma unroll
    for (int db = 0; db < 4; db++)
      ctx[((size_t)b * 512 + qw + cg4 + j) * 768 + hh*64 + 16*db + cr] = f2bf(oacc[db][j] * inv);
  }
}

// ---------------- head: dense+tanh then scalar logit ----------------
__global__ void k_dense(const float* __restrict__ h, const float* __restrict__ W,
                        const float* __restrict__ bias, float* __restrict__ xt){
  __shared__ float xs[768];
  int b = blockIdx.x, t = threadIdx.x;
  const float* hr = h + (size_t)b * 512 * 768;
  xs[t] = hr[t]; xs[t+256] = hr[t+256]; xs[t+512] = hr[t+512];
  __syncthreads();
  for (int j = t; j < 768; j += 256){
    float a = bias[j];
    #pragma unroll 4
    for (int k = 0; k < 768; k++) a += xs[k] * W[(size_t)k * 768 + j];
    xt[(size_t)b * 768 + j] = tanhf(a);
  }
}

__global__ void k_logits(const float* __restrict__ xt, const float* __restrict__ ow,
                         const float* __restrict__ ob, float* __restrict__ out){
  __shared__ float sb[4];
  int b = blockIdx.x, t = threadIdx.x;
  const float* x = xt + (size_t)b * 768;
  float s = x[t]*ow[t] + x[t+256]*ow[t+256] + x[t+512]*ow[t+512];
  for (int o = 32; o; o >>= 1) s += __shfl_down(s, o, 64);
  int wv = t >> 6, ln = t & 63;
  if (!ln) sb[wv] = s;
  __syncthreads();
  if (t == 0) out[b] = sb[0] + sb[1] + sb[2] + sb[3] + ob[0];
}

// ---------------- launch ----------------
extern "C" void kernel_launch(void* const* d_in, const int* in_sizes, int n_in,
                              void* d_out, int out_size, void* d_ws, size_t ws_size,
                              hipStream_t stream){
  if (n_in < 23) return;
  if (ws_size < 534000000ull) return;

  const int*   ids  = (const int*)  d_in[0];
  const int*   pos  = (const int*)  d_in[1];
  const void*  amsk =               d_in[2];
  const float* wemb = (const float*)d_in[3];
  const float* pemb = (const float*)d_in[4];
  const float* lng  = (const float*)d_in[5];
  const float* lnb  = (const float*)d_in[6];
  const float* Wqkv = (const float*)d_in[7];
  const float* bqkv = (const float*)d_in[8];
  const float* Wo   = (const float*)d_in[9];
  const float* bo   = (const float*)d_in[10];
  const float* ln1g = (const float*)d_in[11];
  const float* ln1b = (const float*)d_in[12];
  const float* W1   = (const float*)d_in[13];
  const float* b1   = (const float*)d_in[14];
  const float* W2   = (const float*)d_in[15];
  const float* b2   = (const float*)d_in[16];
  const float* ln2g = (const float*)d_in[17];
  const float* ln2b = (const float*)d_in[18];
  const float* dW   = (const float*)d_in[19];
  const float* db   = (const float*)d_in[20];
  const float* oW   = (const float*)d_in[21];
  const float* ob   = (const float*)d_in[22];

  char* ws = (char*)d_ws;
  float* h    = (float*)(ws);
  u16*   hb   = (u16*)  (ws + 100663296);
  float* C    = (float*)(ws + 150994944);
  u16*   qkvp = (u16*)  (ws + 251658240);   // qp | kp | vbuf, each 50331648 B
  u16*   vt   = (u16*)  (ws + 402653184);
  u16*   act  = (u16*)  (ws + 251658240);   // aliases qkvp+vt (disjoint lifetime)
  u16*   ctx  = (u16*)  (ws + 452984832);
  u32*   mbit = (u32*)  (ws + 503316480);
  u16*   wt   = (u16*)  (ws + 505413632);
  float* xt   = (float*)(ws + 533725184);
  int*   flag = (int*)  (ws + 533921792);

  u16* qp   = qkvp;
  u16* kp   = qkvp + (size_t)25165824;
  u16* vbuf = qkvp + (size_t)50331648;

  u16* WqkvT = wt;                                  // [l][2304][768]
  u16* WoT   = WqkvT + (size_t)2*2304*768;          // [l][768][768]
  u16* W1T   = WoT   + (size_t)2*768*768;           // [l][3072][768]
  u16* W2T   = W1T   + (size_t)2*3072*768;          // [l][768][3072]

  k_maskprobe<<<1, 256, 0, stream>>>((const unsigned char*)amsk, flag);
  k_maskbits<<<8192, 256, 0, stream>>>(amsk, flag, mbit);

  for (int l = 0; l < 2; l++){
    k_transpose<<<dim3(24, 72), 256, 0, stream>>>(Wqkv + (size_t)l*768*2304, WqkvT + (size_t)l*2304*768, 768, 2304);
    k_transpose<<<dim3(24, 24), 256, 0, stream>>>(Wo   + (size_t)l*768*768,  WoT   + (size_t)l*768*768,  768, 768);
    k_transpose<<<dim3(24, 96), 256, 0, stream>>>(W1   + (size_t)l*768*3072, W1T   + (size_t)l*3072*768, 768, 3072);
    k_transpose<<<dim3(96, 24), 256, 0, stream>>>(W2   + (size_t)l*3072*768, W2T   + (size_t)l*768*3072, 3072, 768);
  }

  k_embed<<<32768, 256, 0, stream>>>(ids, wemb, h);
  k_nodeavg<<<dim3(32768, 3), 256, 0, stream>>>(pos, mbit, h);
  k_ln0<<<32768, 256, 0, stream>>>(pos, pemb, lng, lnb, h, hb);

  for (int l = 0; l < 2; l++){
    k_gemm2<3><<<dim3(9, 128), 512, 0, stream>>>(hb, WqkvT + (size_t)l*2304*768, bqkv + l*2304, (void*)qkvp, 32768, 2304, 768);
    k_vtrep<<<dim3(8, 768), 256, 0, stream>>>(vbuf, vt);
    k_attn3<<<dim3(8, 768), 256, 0, stream>>>(qp, kp, vt, mbit, ctx);
    k_gemm2<1><<<dim3(3, 128), 512, 0, stream>>>(ctx, WoT + (size_t)l*768*768, bo + l*768, (void*)C, 32768, 768, 768);
    k_lnres<<<32768, 256, 0, stream>>>(C, ln1g + l*768, ln1b + l*768, h, hb);
    k_gemm2<2><<<dim3(12, 128), 512, 0, stream>>>(hb, W1T + (size_t)l*3072*768, b1 + l*3072, (void*)act, 32768, 3072, 768);
    k_gemm2<1><<<dim3(3, 128), 512, 0, stream>>>(act, W2T + (size_t)l*768*3072, b2 + l*768, (void*)C, 32768, 768, 3072);
    k_lnres<<<32768, 256, 0, stream>>>(C, ln2g + l*768, ln2b + l*768, h, hb);
  }

  k_dense<<<64, 256, 0, stream>>>(h, dW, db, xt);
  k_logits<<<64, 256, 0, stream>>>(xt, oW, ob, (float*)d_out);
}

// Round 8
// 2388.127 us; speedup vs baseline: 1.4106x; 1.0036x over previous
//
#include <hip/hip_runtime.h>

typedef unsigned short u16;
typedef unsigned int   u32;
typedef __bf16 bf16x8 __attribute__((ext_vector_type(8)));
typedef float  f32x4  __attribute__((ext_vector_type(4)));

#define DEVI __device__ __forceinline__

DEVI u16 f2bf(float f){
  u32 u = __builtin_bit_cast(u32, f);
  u32 r = (u + 0x7fffu + ((u >> 16) & 1u)) >> 16;   // RNE
  return (u16)r;
}

DEVI void gload16(const void* g, void* lds){
  __builtin_amdgcn_global_load_lds(
      (const __attribute__((address_space(1))) void*)g,
      (__attribute__((address_space(3))) void*)lds, 16, 0, 0);
}

DEVI f32x4 MFMA(bf16x8 a, bf16x8 b, f32x4 c){
  return __builtin_amdgcn_mfma_f32_16x16x32_bf16(a, b, c, 0, 0, 0);
}

#define BAR() do { asm volatile("s_barrier" ::: "memory"); \
                   __builtin_amdgcn_sched_barrier(0); } while(0)

// ---------------- mask dtype probe: 1 => uint8 bytes, 0 => int32 ----------------
__global__ void k_maskprobe(const unsigned char* __restrict__ m, int* __restrict__ flag){
  __shared__ int s;
  if (threadIdx.x == 0) s = 0;
  __syncthreads();
  int acc = 0;
  for (int i = threadIdx.x; i < 65536; i += 256)
    if ((i & 3) != 0 && m[i] != 0) acc++;
  atomicAdd(&s, acc);
  __syncthreads();
  if (threadIdx.x == 0) *flag = (s > 0) ? 1 : 0;
}

// ---------------- pack attn_mask to bitmask [B*S][16 words] ----------------
__global__ void k_maskbits(const void* __restrict__ mask, const int* __restrict__ flag,
                           u32* __restrict__ mb){
  int row  = blockIdx.x * 4 + (threadIdx.x >> 6);   // b*512+q
  int lane = threadIdx.x & 63;
  bool bytes = (*flag != 0);
  for (int c0 = 0; c0 < 512; c0 += 64){
    int v;
    if (bytes) v = ((const unsigned char*)mask)[(size_t)row * 512 + c0 + lane];
    else       v = ((const int*)mask)[(size_t)row * 512 + c0 + lane];
    unsigned long long bits = __ballot(v != 0);
    if (lane == 0){
      mb[(size_t)row * 16 + (c0 >> 5)]     = (u32)(bits & 0xffffffffull);
      mb[(size_t)row * 16 + (c0 >> 5) + 1] = (u32)(bits >> 32);
    }
  }
}

// ---------------- embedding gather ----------------
__global__ void k_embed(const int* __restrict__ ids, const float* __restrict__ wemb,
                        float* __restrict__ h){
  int row = blockIdx.x;
  const float* s = wemb + (size_t)ids[row] * 768;
  float* d = h + (size_t)row * 768;
  int t = threadIdx.x;
  d[t] = s[t]; d[t + 256] = s[t + 256]; d[t + 512] = s[t + 512];
}

// ---------------- node-average (rows with pos==0) ----------------
__global__ void k_nodeavg(const int* __restrict__ pos, const u32* __restrict__ mb,
                          float* __restrict__ h){
  int row = blockIdx.x;                 // b*512+n
  if (pos[row] != 0) return;
  int b = row >> 9;
  int c = blockIdx.y * 256 + threadIdx.x;
  const u32* mrow = mb + (size_t)row * 16;
  const int* pb = pos + ((size_t)b << 9);
  float a = 0.f, cnt = 0.f;
  #pragma unroll 4
  for (int t = 0; t < 512; t++){
    if (pb[t] >= 2 && ((mrow[t >> 5] >> (t & 31)) & 1)){
      a += h[(((size_t)b << 9) + t) * 768 + c];
      cnt += 1.f;
    }
  }
  h[(size_t)row * 768 + c] = a / (cnt + 1e-10f);
}

// ---------------- LN kernels ----------------
__global__ void k_ln0(const int* __restrict__ pos, const float* __restrict__ pemb,
                      const float* __restrict__ g, const float* __restrict__ be,
                      float* __restrict__ h, u16* __restrict__ hb){
  __shared__ float s1[4], s2[4];
  int row = blockIdx.x, t = threadIdx.x;
  float* hr = h + (size_t)row * 768;
  const float* pr = pemb + (size_t)pos[row] * 768;
  float x0 = hr[t] + pr[t], x1 = hr[t+256] + pr[t+256], x2 = hr[t+512] + pr[t+512];
  float s = x0 + x1 + x2, q = x0*x0 + x1*x1 + x2*x2;
  for (int o = 32; o; o >>= 1){ s += __shfl_down(s, o, 64); q += __shfl_down(q, o, 64); }
  int wv = t >> 6, ln = t & 63;
  if (!ln){ s1[wv] = s; s2[wv] = q; }
  __syncthreads();
  s = s1[0]+s1[1]+s1[2]+s1[3]; q = s2[0]+s2[1]+s2[2]+s2[3];
  float mu = s * (1.f/768.f);
  float rs = rsqrtf(q * (1.f/768.f) - mu*mu + 1e-5f);
  u16* hbr = hb + (size_t)row * 768;
  float y;
  y = (x0-mu)*rs*g[t]     + be[t];     hr[t]     = y; hbr[t]     = f2bf(y);
  y = (x1-mu)*rs*g[t+256] + be[t+256]; hr[t+256] = y; hbr[t+256] = f2bf(y);
  y = (x2-mu)*rs*g[t+512] + be[t+512]; hr[t+512] = y; hbr[t+512] = f2bf(y);
}

__global__ void k_lnres(const float* __restrict__ C, const float* __restrict__ g,
                        const float* __restrict__ be, float* __restrict__ h,
                        u16* __restrict__ hb){
  __shared__ float s1[4], s2[4];
  int row = blockIdx.x, t = threadIdx.x;
  float* hr = h + (size_t)row * 768;
  const float* cr = C + (size_t)row * 768;
  float x0 = hr[t] + cr[t], x1 = hr[t+256] + cr[t+256], x2 = hr[t+512] + cr[t+512];
  float s = x0 + x1 + x2, q = x0*x0 + x1*x1 + x2*x2;
  for (int o = 32; o; o >>= 1){ s += __shfl_down(s, o, 64); q += __shfl_down(q, o, 64); }
  int wv = t >> 6, ln = t & 63;
  if (!ln){ s1[wv] = s; s2[wv] = q; }
  __syncthreads();
  s = s1[0]+s1[1]+s1[2]+s1[3]; q = s2[0]+s2[1]+s2[2]+s2[3];
  float mu = s * (1.f/768.f);
  float rs = rsqrtf(q * (1.f/768.f) - mu*mu + 1e-5f);
  u16* hbr = hb + (size_t)row * 768;
  float y;
  y = (x0-mu)*rs*g[t]     + be[t];     hr[t]     = y; hbr[t]     = f2bf(y);
  y = (x1-mu)*rs*g[t+256] + be[t+256]; hr[t+256] = y; hbr[t+256] = f2bf(y);
  y = (x2-mu)*rs*g[t+512] + be[t+512]; hr[t+512] = y; hbr[t+512] = f2bf(y);
}

// ---------------- weight transpose+cast: src[K][N] f32 -> dst[N][K] bf16 ----------------
__global__ void k_transpose(const float* __restrict__ src, u16* __restrict__ dst,
                            int K, int N){
  __shared__ float tile[32][33];
  int k0 = blockIdx.x * 32, n0 = blockIdx.y * 32;
  int tx = threadIdx.x & 31, ty = threadIdx.x >> 5;   // ty 0..7
  #pragma unroll
  for (int i = 0; i < 32; i += 8)
    tile[ty + i][tx] = src[(size_t)(k0 + ty + i) * N + n0 + tx];
  __syncthreads();
  #pragma unroll
  for (int i = 0; i < 32; i += 8)
    dst[(size_t)(n0 + ty + i) * K + k0 + tx] = f2bf(tile[tx][ty + i]);
}

// ================== 128x256 BK=32 GEMM, 2 blocks/CU, BT = [N][K] ==================
// LDS 64 KiB: A 2x[128][32] (16 KB) | B 3x[256][32] (48 KB). Rows are 4 chunks of 16B,
// stored at slot = chunk ^ ((row>>1)&3) (conflict-free b128 reads; staged via
// inverse-swizzled global source, rule #21). One barrier per K-tile; counted vmcnt(2).
// EPI 0: bf16+bias; 1: f32+bias; 2: bf16+bias+GELU; 3: qkv scatter to head-packed.

DEVI void stageA32(const u16* __restrict__ src, int K, u16* lds, int tid){
  int r = tid >> 2, c = tid & 3;
  int sc = c ^ ((r >> 1) & 3);
  gload16(src + (size_t)r*K + sc*8, lds + (size_t)tid*8);
}
DEVI void stageB32(const u16* __restrict__ src, int K, u16* lds, int tid){
  #pragma unroll
  for (int j = 0; j < 2; j++){
    int p = j*512 + tid;
    int r = p >> 2, c = p & 3;
    int sc = c ^ ((r >> 1) & 3);
    gload16(src + (size_t)r*K + sc*8, lds + (size_t)p*8);
  }
}

template<int EPI>
__global__ __launch_bounds__(512, 4)
void k_gemm3(const u16* __restrict__ A, const u16* __restrict__ BT,
             const float* __restrict__ bias, void* __restrict__ out,
             int M, int N, int K){
  __shared__ __align__(16) u16 sm[32768];   // 64 KiB
  const int tid = threadIdx.x;
  const int w = tid >> 6, lane = tid & 63;
  const int wm = w >> 2, wn = w & 3;
  const int cr = lane & 15, cg = lane >> 4;

  // bijective XCD-chunked remap (m204)
  const int nbn = gridDim.x;
  const int nwg = nbn * gridDim.y;
  const int d   = blockIdx.y * nbn + blockIdx.x;
  const int xcd = d & 7, qq = nwg >> 3, rr = nwg & 7;
  const int logical = (xcd < rr ? xcd*(qq+1) : rr*(qq+1) + (xcd-rr)*qq) + (d >> 3);
  const int m0 = (logical / nbn) * 128;
  const int n0 = (logical % nbn) * 256;

  const int NT = K >> 5;
  const u16* Abase = A  + (size_t)m0 * K;
  const u16* Bbase = BT + (size_t)n0 * K;
  const int rowA = wm*64 + cr;
  const int rowB = wn*64 + cr;

  f32x4 acc[4][4] = {};
  bf16x8 afr[4], bfr[4];

  // B buffers at u16 8192 + {0,8192,16384}; A buffers at {0,4096}
  // prologue: A(0)->Ab0, B(0)->Bb0, B(1)->Bb1
  stageA32(Abase, K, sm, tid);
  stageB32(Bbase, K, sm + 8192, tid);
  if (NT > 1){
    stageB32(Bbase + 32, K, sm + 16384, tid);
    asm volatile("s_waitcnt vmcnt(2)" ::: "memory");
  } else {
    asm volatile("s_waitcnt vmcnt(0)" ::: "memory");
  }
  __builtin_amdgcn_sched_barrier(0);
  BAR();

  int bcur = 0;
  for (int t = 0; t < NT; ++t){
    const int ab = (t & 1) << 12;
    const int bb = 8192 + (bcur << 13);
    int bn2 = bcur + 2; if (bn2 >= 3) bn2 -= 3;

    #pragma unroll
    for (int n = 0; n < 4; n++){
      int r = rowB + n*16;
      bfr[n] = *(const bf16x8*)&sm[bb + r*32 + ((cg ^ ((r >> 1) & 3)) << 3)];
    }
    #pragma unroll
    for (int i = 0; i < 4; i++){
      int r = rowA + i*16;
      afr[i] = *(const bf16x8*)&sm[ab + r*32 + ((cg ^ ((r >> 1) & 3)) << 3)];
    }
    if (t + 1 < NT) stageA32(Abase + (size_t)(t+1)*32, K, sm + (((t+1) & 1) << 12), tid);
    if (t + 2 < NT) stageB32(Bbase + (size_t)(t+2)*32, K, sm + 8192 + (bn2 << 13), tid);

    __builtin_amdgcn_s_setprio(1);
    #pragma unroll
    for (int i = 0; i < 4; i++)
      #pragma unroll
      for (int n = 0; n < 4; n++)
        acc[i][n] = MFMA(afr[i], bfr[n], acc[i][n]);
    __builtin_amdgcn_s_setprio(0);

    if (t + 2 < NT) { asm volatile("s_waitcnt vmcnt(2)" ::: "memory"); }
    else            { asm volatile("s_waitcnt vmcnt(0)" ::: "memory"); }
    __builtin_amdgcn_sched_barrier(0);
    BAR();
    bcur = bcur + 1; if (bcur >= 3) bcur = 0;
  }

  // ---- epilogue
  #pragma unroll
  for (int n = 0; n < 4; n++){
    int col = n0 + wn*64 + n*16 + cr;
    float bv = bias[col];
    int sec = 0, hd = 0, dcol = 0;
    if (EPI == 3){
      sec = (col >= 1536) ? 2 : (col >= 768 ? 1 : 0);
      hd  = (col - sec*768) >> 6;
      dcol = col & 63;
    }
    #pragma unroll
    for (int i = 0; i < 4; i++){
      #pragma unroll
      for (int j = 0; j < 4; j++){
        int row = m0 + wm*64 + i*16 + cg*4 + j;
        float v = acc[i][n][j] + bv;
        if (EPI == 2) v = 0.5f * v * (1.f + erff(v * 0.70710678118654752f));
        if (EPI == 1)      ((float*)out)[(size_t)row * N + col] = v;
        else if (EPI == 3){
          int b = row >> 9, s = row & 511;
          ((u16*)out)[(size_t)sec*25165824 + (((size_t)(b*12 + hd)*512 + s) << 6) + dcol] = f2bf(v);
        }
        else               ((u16*) out)[(size_t)row * N + col] = f2bf(v);
      }
    }
  }
}

// ---------------- V^T repack: vbuf[bh][512][64] -> vt[bh][64][512] ----------------
__global__ void k_vtrep(const u16* __restrict__ vbuf, u16* __restrict__ vt){
  __shared__ u16 tile[64][72];
  int bh = blockIdx.y;               // b*12+h
  int t0 = blockIdx.x * 64;
  int tid = threadIdx.x;
  #pragma unroll
  for (int i = 0; i < 16; i++){
    int idx = tid + i * 256;
    int tt = idx >> 6, d = idx & 63;
    tile[tt][d] = vbuf[((size_t)bh * 512 + t0 + tt) * 64 + d];
  }
  __syncthreads();
  #pragma unroll
  for (int i = 0; i < 16; i++){
    int idx = tid + i * 256;
    int d = idx >> 6, tt = idx & 63;
    vt[((size_t)bh * 64 + d) * 512 + t0 + tt] = tile[tt][d];
  }
}

// ---------------- attention v3: flash/online, swapped QK^T, LDS-staged K & V^T ----------
DEVI void stage64(const u16* __restrict__ src, int stride, u16* lds, int w, int lane){
  #pragma unroll
  for (int j = 0; j < 2; j++){
    int p  = j*256 + w*64 + lane;        // piece 0..511 (16B each)
    int r  = p >> 3;                     // row 0..63
    int c8 = (p & 7) ^ (r & 7);          // inverse-swizzled source chunk
    gload16(src + (size_t)r*stride + c8*8, lds + (size_t)p*8);
  }
}

__global__ __launch_bounds__(256, 4)
void k_attn3(const u16* __restrict__ qp, const u16* __restrict__ kp,
             const u16* __restrict__ vt, const u32* __restrict__ mb,
             u16* __restrict__ ctx){
  __shared__ __align__(16) u16 Ks[8192];   // 2 x [64][64]
  __shared__ __align__(16) u16 Vs[8192];   // 2 x [64 d][64 kv]
  const int tid = threadIdx.x, wv = tid >> 6, lane = tid & 63;
  const int cr = lane & 15, cg = lane >> 4;
  const int cg4 = cg * 4;
  const int r7 = cr & 7;

  // XCD-chunked remap: 6144 blocks, 768/XCD => 96 whole heads per XCD
  const int dd = blockIdx.x + (blockIdx.y << 3);
  const int logical = (dd & 7) * 768 + (dd >> 3);
  const int bh = logical >> 3;
  const int qblk = logical & 7;
  const int b = bh / 12, hh = bh % 12;
  const int qw = qblk * 64 + wv * 16;
  const int qrow = qw + cr;
  const size_t base = (size_t)bh * 512 * 64;
  const u16* vtb = vt + (size_t)bh * 64 * 512;

  const int slot0 = ((cg    ) ^ r7) << 3;
  const int slot1 = ((4 + cg) ^ r7) << 3;

  bf16x8 qB[2];
  #pragma unroll
  for (int ks = 0; ks < 2; ks++)
    qB[ks] = *(const bf16x8*)&qp[base + (size_t)qrow * 64 + ks*32 + cg*8];

  u32 mw[16];
  {
    const u32* mrow = mb + ((size_t)b * 512 + qrow) * 16;
    #pragma unroll
    for (int i = 0; i < 4; i++){
      uint4 v4 = *(const uint4*)&mrow[i*4];
      mw[i*4+0] = v4.x; mw[i*4+1] = v4.y; mw[i*4+2] = v4.z; mw[i*4+3] = v4.w;
    }
  }

  stage64(kp + base, 64, Ks, wv, lane);
  stage64(vtb,      512, Vs, wv, lane);
  asm volatile("s_waitcnt vmcnt(0)" ::: "memory");
  __builtin_amdgcn_sched_barrier(0);
  BAR();

  float m = -3e38f, vs = 0.f;
  f32x4 oacc[4] = {};

  for (int s = 0; s < 8; ++s){
    const int buf = (s & 1) << 12;
    const int nbf = ((s + 1) & 1) << 12;

    if (s + 1 < 8){
      stage64(kp + base + (size_t)(s+1)*4096, 64, Ks + nbf, wv, lane);
      stage64(vtb + (size_t)(s+1)*64,        512, Vs + nbf, wv, lane);
    }

    f32x4 pacc[4];
    #pragma unroll
    for (int tt = 0; tt < 4; tt++){
      bf16x8 a0 = *(const bf16x8*)&Ks[buf + (tt*16 + cr)*64 + slot0];
      bf16x8 a1 = *(const bf16x8*)&Ks[buf + (tt*16 + cr)*64 + slot1];
      f32x4 z = {0.f, 0.f, 0.f, 0.f};
      z = MFMA(a0, qB[0], z);
      z = MFMA(a1, qB[1], z);
      pacc[tt] = z;
    }

    const u32 w0 = mw[2*s], w1 = mw[2*s+1];
    f32x4 vmx = {-3e38f, -3e38f, -3e38f, -3e38f};
    #pragma unroll
    for (int tt = 0; tt < 4; tt++){
      u32 nib = (((tt < 2) ? w0 : w1) >> (16*(tt & 1) + cg4)) & 0xFu;
      #pragma unroll
      for (int j = 0; j < 4; j++){
        float v = pacc[tt][j] * 0.125f + (((nib >> j) & 1u) ? 0.f : -10000.f);
        pacc[tt][j] = v;
        vmx[j] = fmaxf(vmx[j], v);
      }
    }
    float tm = fmaxf(fmaxf(vmx[0], vmx[1]), fmaxf(vmx[2], vmx[3]));
    tm = fmaxf(tm, __shfl_xor(tm, 16, 64));
    tm = fmaxf(tm, __shfl_xor(tm, 32, 64));

    float mnew = fmaxf(m, tm);
    float alpha = __expf(m - mnew);
    m = mnew;
    #pragma unroll
    for (int db = 0; db < 4; db++) oacc[db] *= alpha;

    f32x4 vsum = {0.f, 0.f, 0.f, 0.f};
    #pragma unroll
    for (int tt = 0; tt < 4; tt++){
      #pragma unroll
      for (int j = 0; j < 4; j++){
        float e = __expf(pacc[tt][j] - m);
        pacc[tt][j] = e;
        vsum[j] += e;
      }
    }
    vs = vs * alpha + (vsum[0] + vsum[1] + vsum[2] + vsum[3]);

    bf16x8 pa[2];
    #pragma unroll
    for (int c = 0; c < 2; c++)
      #pragma unroll
      for (int e = 0; e < 4; e++){
        pa[c][e]   = (__bf16)pacc[2*c][e];
        pa[c][4+e] = (__bf16)pacc[2*c+1][e];
      }

    #pragma unroll
    for (int c = 0; c < 2; c++){
      const int ch0 = ((4*c     + (cg >> 1)) ^ r7);
      const int ch1 = ((4*c + 2 + (cg >> 1)) ^ r7);
      const int sub = (cg & 1) << 3;
      #pragma unroll
      for (int db = 0; db < 4; db++){
        const char* vrow = (const char*)&Vs[buf + (db*16 + cr)*64];
        bf16x8 vb;
        ((uint2*)&vb)[0] = *(const uint2*)(vrow + (ch0 << 4) + sub);
        ((uint2*)&vb)[1] = *(const uint2*)(vrow + (ch1 << 4) + sub);
        oacc[db] = MFMA(pa[c], vb, oacc[db]);
      }
    }

    if (s + 1 < 8) { asm volatile("s_waitcnt vmcnt(0)" ::: "memory"); }
    __builtin_amdgcn_sched_barrier(0);
    BAR();
  }

  vs += __shfl_xor(vs, 16, 64);
  vs += __shfl_xor(vs, 32, 64);
  #pragma unroll
  for (int j = 0; j < 4; j++){
    float ds = __shfl(vs, cg4 + j, 64);
    float inv = 1.0f / ds;
    #pragma unroll
    for (int db = 0; db < 4; db++)
      ctx[((size_t)b * 512 + qw + cg4 + j) * 768 + hh*64 + 16*db + cr] = f2bf(oacc[db][j] * inv);
  }
}

// ---------------- head: dense+tanh then scalar logit ----------------
__global__ void k_dense(const float* __restrict__ h, const float* __restrict__ W,
                        const float* __restrict__ bias, float* __restrict__ xt){
  __shared__ float xs[768];
  int b = blockIdx.x, t = threadIdx.x;
  const float* hr = h + (size_t)b * 512 * 768;
  xs[t] = hr[t]; xs[t+256] = hr[t+256]; xs[t+512] = hr[t+512];
  __syncthreads();
  for (int j = t; j < 768; j += 256){
    float a = bias[j];
    #pragma unroll 4
    for (int k = 0; k < 768; k++) a += xs[k] * W[(size_t)k * 768 + j];
    xt[(size_t)b * 768 + j] = tanhf(a);
  }
}

__global__ void k_logits(const float* __restrict__ xt, const float* __restrict__ ow,
                         const float* __restrict__ ob, float* __restrict__ out){
  __shared__ float sb[4];
  int b = blockIdx.x, t = threadIdx.x;
  const float* x = xt + (size_t)b * 768;
  float s = x[t]*ow[t] + x[t+256]*ow[t+256] + x[t+512]*ow[t+512];
  for (int o = 32; o; o >>= 1) s += __shfl_down(s, o, 64);
  int wv = t >> 6, ln = t & 63;
  if (!ln) sb[wv] = s;
  __syncthreads();
  if (t == 0) out[b] = sb[0] + sb[1] + sb[2] + sb[3] + ob[0];
}

// ---------------- launch ----------------
extern "C" void kernel_launch(void* const* d_in, const int* in_sizes, int n_in,
                              void* d_out, int out_size, void* d_ws, size_t ws_size,
                              hipStream_t stream){
  if (n_in < 23) return;
  if (ws_size < 534000000ull) return;

  const int*   ids  = (const int*)  d_in[0];
  const int*   pos  = (const int*)  d_in[1];
  const void*  amsk =               d_in[2];
  const float* wemb = (const float*)d_in[3];
  const float* pemb = (const float*)d_in[4];
  const float* lng  = (const float*)d_in[5];
  const float* lnb  = (const float*)d_in[6];
  const float* Wqkv = (const float*)d_in[7];
  const float* bqkv = (const float*)d_in[8];
  const float* Wo   = (const float*)d_in[9];
  const float* bo   = (const float*)d_in[10];
  const float* ln1g = (const float*)d_in[11];
  const float* ln1b = (const float*)d_in[12];
  const float* W1   = (const float*)d_in[13];
  const float* b1   = (const float*)d_in[14];
  const float* W2   = (const float*)d_in[15];
  const float* b2   = (const float*)d_in[16];
  const float* ln2g = (const float*)d_in[17];
  const float* ln2b = (const float*)d_in[18];
  const float* dW   = (const float*)d_in[19];
  const float* db   = (const float*)d_in[20];
  const float* oW   = (const float*)d_in[21];
  const float* ob   = (const float*)d_in[22];

  char* ws = (char*)d_ws;
  float* h    = (float*)(ws);
  u16*   hb   = (u16*)  (ws + 100663296);
  float* C    = (float*)(ws + 150994944);
  u16*   qkvp = (u16*)  (ws + 251658240);   // qp | kp | vbuf, each 50331648 B
  u16*   vt   = (u16*)  (ws + 402653184);
  u16*   act  = (u16*)  (ws + 251658240);   // aliases qkvp+vt (disjoint lifetime)
  u16*   ctx  = (u16*)  (ws + 452984832);
  u32*   mbit = (u32*)  (ws + 503316480);
  u16*   wt   = (u16*)  (ws + 505413632);
  float* xt   = (float*)(ws + 533725184);
  int*   flag = (int*)  (ws + 533921792);

  u16* qp   = qkvp;
  u16* kp   = qkvp + (size_t)25165824;
  u16* vbuf = qkvp + (size_t)50331648;

  u16* WqkvT = wt;                                  // [l][2304][768]
  u16* WoT   = WqkvT + (size_t)2*2304*768;          // [l][768][768]
  u16* W1T   = WoT   + (size_t)2*768*768;           // [l][3072][768]
  u16* W2T   = W1T   + (size_t)2*3072*768;          // [l][768][3072]

  k_maskprobe<<<1, 256, 0, stream>>>((const unsigned char*)amsk, flag);
  k_maskbits<<<8192, 256, 0, stream>>>(amsk, flag, mbit);

  for (int l = 0; l < 2; l++){
    k_transpose<<<dim3(24, 72), 256, 0, stream>>>(Wqkv + (size_t)l*768*2304, WqkvT + (size_t)l*2304*768, 768, 2304);
    k_transpose<<<dim3(24, 24), 256, 0, stream>>>(Wo   + (size_t)l*768*768,  WoT   + (size_t)l*768*768,  768, 768);
    k_transpose<<<dim3(24, 96), 256, 0, stream>>>(W1   + (size_t)l*768*3072, W1T   + (size_t)l*3072*768, 768, 3072);
    k_transpose<<<dim3(96, 24), 256, 0, stream>>>(W2   + (size_t)l*3072*768, W2T   + (size_t)l*768*3072, 3072, 768);
  }

  k_embed<<<32768, 256, 0, stream>>>(ids, wemb, h);
  k_nodeavg<<<dim3(32768, 3), 256, 0, stream>>>(pos, mbit, h);
  k_ln0<<<32768, 256, 0, stream>>>(pos, pemb, lng, lnb, h, hb);

  for (int l = 0; l < 2; l++){
    k_gemm3<3><<<dim3(9, 256), 512, 0, stream>>>(hb, WqkvT + (size_t)l*2304*768, bqkv + l*2304, (void*)qkvp, 32768, 2304, 768);
    k_vtrep<<<dim3(8, 768), 256, 0, stream>>>(vbuf, vt);
    k_attn3<<<dim3(8, 768), 256, 0, stream>>>(qp, kp, vt, mbit, ctx);
    k_gemm3<1><<<dim3(3, 256), 512, 0, stream>>>(ctx, WoT + (size_t)l*768*768, bo + l*768, (void*)C, 32768, 768, 768);
    k_lnres<<<32768, 256, 0, stream>>>(C, ln1g + l*768, ln1b + l*768, h, hb);
    k_gemm3<2><<<dim3(12, 256), 512, 0, stream>>>(hb, W1T + (size_t)l*3072*768, b1 + l*3072, (void*)act, 32768, 3072, 768);
    k_gemm3<1><<<dim3(3, 256), 512, 0, stream>>>(act, W2T + (size_t)l*768*3072, b2 + l*768, (void*)C, 32768, 768, 3072);
    k_lnres<<<32768, 256, 0, stream>>>(C, ln2g + l*768, ln2b + l*768, h, hb);
  }

  k_dense<<<64, 256, 0, stream>>>(h, dW, db, xt);
  k_logits<<<64, 256, 0, stream>>>(xt, oW, ob, (float*)d_out);
}

// Round 9
// 2223.744 us; speedup vs baseline: 1.5149x; 1.0739x over previous
//
#include <hip/hip_runtime.h>

typedef unsigned short u16;
typedef unsigned int   u32;
typedef __bf16 bf16x8 __attribute__((ext_vector_type(8)));
typedef float  f32x4  __attribute__((ext_vector_type(4)));

#define DEVI __device__ __forceinline__

DEVI u16 f2bf(float f){
  u32 u = __builtin_bit_cast(u32, f);
  u32 r = (u + 0x7fffu + ((u >> 16) & 1u)) >> 16;   // RNE
  return (u16)r;
}
DEVI float bf2f(u16 u){
  u32 x = ((u32)u) << 16;
  return __builtin_bit_cast(float, x);
}

DEVI void gload16(const void* g, void* lds){
  __builtin_amdgcn_global_load_lds(
      (const __attribute__((address_space(1))) void*)g,
      (__attribute__((address_space(3))) void*)lds, 16, 0, 0);
}

DEVI f32x4 MFMA(bf16x8 a, bf16x8 b, f32x4 c){
  return __builtin_amdgcn_mfma_f32_16x16x32_bf16(a, b, c, 0, 0, 0);
}

#define BAR() do { asm volatile("s_barrier" ::: "memory"); \
                   __builtin_amdgcn_sched_barrier(0); } while(0)

// ---------------- mask dtype probe: 1 => uint8 bytes, 0 => int32 ----------------
__global__ void k_maskprobe(const unsigned char* __restrict__ m, int* __restrict__ flag){
  __shared__ int s;
  if (threadIdx.x == 0) s = 0;
  __syncthreads();
  int acc = 0;
  for (int i = threadIdx.x; i < 65536; i += 256)
    if ((i & 3) != 0 && m[i] != 0) acc++;
  atomicAdd(&s, acc);
  __syncthreads();
  if (threadIdx.x == 0) *flag = (s > 0) ? 1 : 0;
}

// ---------------- pack attn_mask to bitmask [B*S][16 words] ----------------
__global__ void k_maskbits(const void* __restrict__ mask, const int* __restrict__ flag,
                           u32* __restrict__ mb){
  int row  = blockIdx.x * 4 + (threadIdx.x >> 6);   // b*512+q
  int lane = threadIdx.x & 63;
  bool bytes = (*flag != 0);
  for (int c0 = 0; c0 < 512; c0 += 64){
    int v;
    if (bytes) v = ((const unsigned char*)mask)[(size_t)row * 512 + c0 + lane];
    else       v = ((const int*)mask)[(size_t)row * 512 + c0 + lane];
    unsigned long long bits = __ballot(v != 0);
    if (lane == 0){
      mb[(size_t)row * 16 + (c0 >> 5)]     = (u32)(bits & 0xffffffffull);
      mb[(size_t)row * 16 + (c0 >> 5) + 1] = (u32)(bits >> 32);
    }
  }
}

// ---------------- embedding gather ----------------
__global__ void k_embed(const int* __restrict__ ids, const float* __restrict__ wemb,
                        float* __restrict__ h){
  int row = blockIdx.x;
  const float* s = wemb + (size_t)ids[row] * 768;
  float* d = h + (size_t)row * 768;
  int t = threadIdx.x;
  d[t] = s[t]; d[t + 256] = s[t + 256]; d[t + 512] = s[t + 512];
}

// ---------------- node-average (rows with pos==0) ----------------
__global__ void k_nodeavg(const int* __restrict__ pos, const u32* __restrict__ mb,
                          float* __restrict__ h){
  int row = blockIdx.x;                 // b*512+n
  if (pos[row] != 0) return;
  int b = row >> 9;
  int c = blockIdx.y * 256 + threadIdx.x;
  const u32* mrow = mb + (size_t)row * 16;
  const int* pb = pos + ((size_t)b << 9);
  float a = 0.f, cnt = 0.f;
  #pragma unroll 4
  for (int t = 0; t < 512; t++){
    if (pb[t] >= 2 && ((mrow[t >> 5] >> (t & 31)) & 1)){
      a += h[(((size_t)b << 9) + t) * 768 + c];
      cnt += 1.f;
    }
  }
  h[(size_t)row * 768 + c] = a / (cnt + 1e-10f);
}

// ---------------- LN kernels ----------------
// ln0: reads f32 h (+pos emb), writes ONLY bf16 hb (residual stream is bf16 from here on)
__global__ void k_ln0(const int* __restrict__ pos, const float* __restrict__ pemb,
                      const float* __restrict__ g, const float* __restrict__ be,
                      const float* __restrict__ h, u16* __restrict__ hb){
  __shared__ float s1[4], s2[4];
  int row = blockIdx.x, t = threadIdx.x;
  const float* hr = h + (size_t)row * 768;
  const float* pr = pemb + (size_t)pos[row] * 768;
  float x0 = hr[t] + pr[t], x1 = hr[t+256] + pr[t+256], x2 = hr[t+512] + pr[t+512];
  float s = x0 + x1 + x2, q = x0*x0 + x1*x1 + x2*x2;
  for (int o = 32; o; o >>= 1){ s += __shfl_down(s, o, 64); q += __shfl_down(q, o, 64); }
  int wv = t >> 6, ln = t & 63;
  if (!ln){ s1[wv] = s; s2[wv] = q; }
  __syncthreads();
  s = s1[0]+s1[1]+s1[2]+s1[3]; q = s2[0]+s2[1]+s2[2]+s2[3];
  float mu = s * (1.f/768.f);
  float rs = rsqrtf(q * (1.f/768.f) - mu*mu + 1e-5f);
  u16* hbr = hb + (size_t)row * 768;
  hbr[t]     = f2bf((x0-mu)*rs*g[t]     + be[t]);
  hbr[t+256] = f2bf((x1-mu)*rs*g[t+256] + be[t+256]);
  hbr[t+512] = f2bf((x2-mu)*rs*g[t+512] + be[t+512]);
}

// lnres: hb (bf16, in-place) + C (f32) -> LN -> hb
__global__ void k_lnres(const float* __restrict__ C, const float* __restrict__ g,
                        const float* __restrict__ be, u16* __restrict__ hb){
  __shared__ float s1[4], s2[4];
  int row = blockIdx.x, t = threadIdx.x;
  u16* hr = hb + (size_t)row * 768;
  const float* cr = C + (size_t)row * 768;
  float x0 = bf2f(hr[t])     + cr[t];
  float x1 = bf2f(hr[t+256]) + cr[t+256];
  float x2 = bf2f(hr[t+512]) + cr[t+512];
  float s = x0 + x1 + x2, q = x0*x0 + x1*x1 + x2*x2;
  for (int o = 32; o; o >>= 1){ s += __shfl_down(s, o, 64); q += __shfl_down(q, o, 64); }
  int wv = t >> 6, ln = t & 63;
  if (!ln){ s1[wv] = s; s2[wv] = q; }
  __syncthreads();
  s = s1[0]+s1[1]+s1[2]+s1[3]; q = s2[0]+s2[1]+s2[2]+s2[3];
  float mu = s * (1.f/768.f);
  float rs = rsqrtf(q * (1.f/768.f) - mu*mu + 1e-5f);
  hr[t]     = f2bf((x0-mu)*rs*g[t]     + be[t]);
  hr[t+256] = f2bf((x1-mu)*rs*g[t+256] + be[t+256]);
  hr[t+512] = f2bf((x2-mu)*rs*g[t+512] + be[t+512]);
}

// ---------------- weight transpose+cast: src[K][N] f32 -> dst[N][K] bf16 ----------------
__global__ void k_transpose(const float* __restrict__ src, u16* __restrict__ dst,
                            int K, int N){
  __shared__ float tile[32][33];
  int k0 = blockIdx.x * 32, n0 = blockIdx.y * 32;
  int tx = threadIdx.x & 31, ty = threadIdx.x >> 5;   // ty 0..7
  #pragma unroll
  for (int i = 0; i < 32; i += 8)
    tile[ty + i][tx] = src[(size_t)(k0 + ty + i) * N + n0 + tx];
  __syncthreads();
  #pragma unroll
  for (int i = 0; i < 32; i += 8)
    dst[(size_t)(n0 + ty + i) * K + k0 + tx] = f2bf(tile[tx][ty + i]);
}

// ========== 128x256 BK=32 GEMM, prefetch-distance-2 (A & B triple-buffered) ==========
// LDS 72 KiB: A 3x[128][32] (24 KB at u16 0/4096/8192) | B 3x[256][32] (48 KB at
// 12288 + 0/8192/16384). Rows = 4 chunks of 16B at slot = chunk ^ ((row>>1)&3)
// (conflict-free b128; inverse-swizzled global source per rule #21).
// Per K-tile: read frags(t) -> stage A/B(t+2) -> MFMA -> vmcnt(3) -> barrier.
// vmcnt(3) retires the (t+1) batch issued a FULL tile earlier (covers HBM latency).
// EPI 0: bf16+bias; 1: f32+bias; 2: bf16+bias+GELU; 3: qkv scatter to head-packed.

DEVI void stageA32(const u16* __restrict__ src, int K, u16* lds, int tid){
  int r = tid >> 2, c = tid & 3;
  int sc = c ^ ((r >> 1) & 3);
  gload16(src + (size_t)r*K + sc*8, lds + (size_t)tid*8);
}
DEVI void stageB32(const u16* __restrict__ src, int K, u16* lds, int tid){
  #pragma unroll
  for (int j = 0; j < 2; j++){
    int p = j*512 + tid;
    int r = p >> 2, c = p & 3;
    int sc = c ^ ((r >> 1) & 3);
    gload16(src + (size_t)r*K + sc*8, lds + (size_t)p*8);
  }
}

template<int EPI>
__global__ __launch_bounds__(512, 4)
void k_gemm3(const u16* __restrict__ A, const u16* __restrict__ BT,
             const float* __restrict__ bias, void* __restrict__ out,
             int M, int N, int K){
  __shared__ __align__(16) u16 sm[36864];   // 72 KiB
  const int tid = threadIdx.x;
  const int w = tid >> 6, lane = tid & 63;
  const int wm = w >> 2, wn = w & 3;
  const int cr = lane & 15, cg = lane >> 4;

  // bijective XCD-chunked remap (m204)
  const int nbn = gridDim.x;
  const int nwg = nbn * gridDim.y;
  const int d   = blockIdx.y * nbn + blockIdx.x;
  const int xcd = d & 7, qq = nwg >> 3, rr = nwg & 7;
  const int logical = (xcd < rr ? xcd*(qq+1) : rr*(qq+1) + (xcd-rr)*qq) + (d >> 3);
  const int m0 = (logical / nbn) * 128;
  const int n0 = (logical % nbn) * 256;

  const int NT = K >> 5;
  const u16* Abase = A  + (size_t)m0 * K;
  const u16* Bbase = BT + (size_t)n0 * K;
  const int rowA = wm*64 + cr;
  const int rowB = wn*64 + cr;

  f32x4 acc[4][4] = {};
  bf16x8 afr[4], bfr[4];

  // prologue: tiles 0 and 1 into bufs 0 and 1
  stageA32(Abase, K, sm, tid);
  stageB32(Bbase, K, sm + 12288, tid);
  if (NT > 1){
    stageA32(Abase + 32, K, sm + 4096, tid);
    stageB32(Bbase + 32, K, sm + 12288 + 8192, tid);
    asm volatile("s_waitcnt vmcnt(3)" ::: "memory");
  } else {
    asm volatile("s_waitcnt vmcnt(0)" ::: "memory");
  }
  __builtin_amdgcn_sched_barrier(0);
  BAR();

  int bcur = 0;
  for (int t = 0; t < NT; ++t){
    const int ab = bcur << 12;             // A buf: 4096 u16 each
    const int bb = 12288 + (bcur << 13);   // B buf: 8192 u16 each
    int bn2 = bcur + 2; if (bn2 >= 3) bn2 -= 3;

    #pragma unroll
    for (int n = 0; n < 4; n++){
      int r = rowB + n*16;
      bfr[n] = *(const bf16x8*)&sm[bb + r*32 + ((cg ^ ((r >> 1) & 3)) << 3)];
    }
    #pragma unroll
    for (int i = 0; i < 4; i++){
      int r = rowA + i*16;
      afr[i] = *(const bf16x8*)&sm[ab + r*32 + ((cg ^ ((r >> 1) & 3)) << 3)];
    }
    if (t + 2 < NT){
      stageA32(Abase + (size_t)(t+2)*32, K, sm + (bn2 << 12), tid);
      stageB32(Bbase + (size_t)(t+2)*32, K, sm + 12288 + (bn2 << 13), tid);
    }

    __builtin_amdgcn_s_setprio(1);
    #pragma unroll
    for (int i = 0; i < 4; i++)
      #pragma unroll
      for (int n = 0; n < 4; n++)
        acc[i][n] = MFMA(afr[i], bfr[n], acc[i][n]);
    __builtin_amdgcn_s_setprio(0);

    if (t + 2 < NT) { asm volatile("s_waitcnt vmcnt(3)" ::: "memory"); }
    else            { asm volatile("s_waitcnt vmcnt(0)" ::: "memory"); }
    __builtin_amdgcn_sched_barrier(0);
    BAR();
    bcur = bcur + 1; if (bcur >= 3) bcur = 0;
  }

  // ---- epilogue
  #pragma unroll
  for (int n = 0; n < 4; n++){
    int col = n0 + wn*64 + n*16 + cr;
    float bv = bias[col];
    int sec = 0, hd = 0, dcol = 0;
    if (EPI == 3){
      sec = (col >= 1536) ? 2 : (col >= 768 ? 1 : 0);
      hd  = (col - sec*768) >> 6;
      dcol = col & 63;
    }
    #pragma unroll
    for (int i = 0; i < 4; i++){
      #pragma unroll
      for (int j = 0; j < 4; j++){
        int row = m0 + wm*64 + i*16 + cg*4 + j;
        float v = acc[i][n][j] + bv;
        if (EPI == 2) v = 0.5f * v * (1.f + erff(v * 0.70710678118654752f));
        if (EPI == 1)      ((float*)out)[(size_t)row * N + col] = v;
        else if (EPI == 3){
          int b = row >> 9, s = row & 511;
          ((u16*)out)[(size_t)sec*25165824 + (((size_t)(b*12 + hd)*512 + s) << 6) + dcol] = f2bf(v);
        }
        else               ((u16*) out)[(size_t)row * N + col] = f2bf(v);
      }
    }
  }
}

// ---------------- V^T repack: vbuf[bh][512][64] -> vt[bh][64][512] ----------------
__global__ void k_vtrep(const u16* __restrict__ vbuf, u16* __restrict__ vt){
  __shared__ u16 tile[64][72];
  int bh = blockIdx.y;               // b*12+h
  int t0 = blockIdx.x * 64;
  int tid = threadIdx.x;
  #pragma unroll
  for (int i = 0; i < 16; i++){
    int idx = tid + i * 256;
    int tt = idx >> 6, d = idx & 63;
    tile[tt][d] = vbuf[((size_t)bh * 512 + t0 + tt) * 64 + d];
  }
  __syncthreads();
  #pragma unroll
  for (int i = 0; i < 16; i++){
    int idx = tid + i * 256;
    int d = idx >> 6, tt = idx & 63;
    vt[((size_t)bh * 64 + d) * 512 + t0 + tt] = tile[tt][d];
  }
}

// ---------------- attention v3: flash/online, swapped QK^T, LDS-staged K & V^T ----------
DEVI void stage64(const u16* __restrict__ src, int stride, u16* lds, int w, int lane){
  #pragma unroll
  for (int j = 0; j < 2; j++){
    int p  = j*256 + w*64 + lane;        // piece 0..511 (16B each)
    int r  = p >> 3;                     // row 0..63
    int c8 = (p & 7) ^ (r & 7);          // inverse-swizzled source chunk
    gload16(src + (size_t)r*stride + c8*8, lds + (size_t)p*8);
  }
}

__global__ __launch_bounds__(256, 4)
void k_attn3(const u16* __restrict__ qp, const u16* __restrict__ kp,
             const u16* __restrict__ vt, const u32* __restrict__ mb,
             u16* __restrict__ ctx){
  __shared__ __align__(16) u16 Ks[8192];   // 2 x [64][64]
  __shared__ __align__(16) u16 Vs[8192];   // 2 x [64 d][64 kv]
  const int tid = threadIdx.x, wv = tid >> 6, lane = tid & 63;
  const int cr = lane & 15, cg = lane >> 4;
  const int cg4 = cg * 4;
  const int r7 = cr & 7;

  const int dd = blockIdx.x + (blockIdx.y << 3);
  const int logical = (dd & 7) * 768 + (dd >> 3);
  const int bh = logical >> 3;
  const int qblk = logical & 7;
  const int b = bh / 12, hh = bh % 12;
  const int qw = qblk * 64 + wv * 16;
  const int qrow = qw + cr;
  const size_t base = (size_t)bh * 512 * 64;
  const u16* vtb = vt + (size_t)bh * 64 * 512;

  const int slot0 = ((cg    ) ^ r7) << 3;
  const int slot1 = ((4 + cg) ^ r7) << 3;

  bf16x8 qB[2];
  #pragma unroll
  for (int ks = 0; ks < 2; ks++)
    qB[ks] = *(const bf16x8*)&qp[base + (size_t)qrow * 64 + ks*32 + cg*8];

  u32 mw[16];
  {
    const u32* mrow = mb + ((size_t)b * 512 + qrow) * 16;
    #pragma unroll
    for (int i = 0; i < 4; i++){
      uint4 v4 = *(const uint4*)&mrow[i*4];
      mw[i*4+0] = v4.x; mw[i*4+1] = v4.y; mw[i*4+2] = v4.z; mw[i*4+3] = v4.w;
    }
  }

  stage64(kp + base, 64, Ks, wv, lane);
  stage64(vtb,      512, Vs, wv, lane);
  asm volatile("s_waitcnt vmcnt(0)" ::: "memory");
  __builtin_amdgcn_sched_barrier(0);
  BAR();

  float m = -3e38f, vs = 0.f;
  f32x4 oacc[4] = {};

  for (int s = 0; s < 8; ++s){
    const int buf = (s & 1) << 12;
    const int nbf = ((s + 1) & 1) << 12;

    if (s + 1 < 8){
      stage64(kp + base + (size_t)(s+1)*4096, 64, Ks + nbf, wv, lane);
      stage64(vtb + (size_t)(s+1)*64,        512, Vs + nbf, wv, lane);
    }

    f32x4 pacc[4];
    #pragma unroll
    for (int tt = 0; tt < 4; tt++){
      bf16x8 a0 = *(const bf16x8*)&Ks[buf + (tt*16 + cr)*64 + slot0];
      bf16x8 a1 = *(const bf16x8*)&Ks[buf + (tt*16 + cr)*64 + slot1];
      f32x4 z = {0.f, 0.f, 0.f, 0.f};
      z = MFMA(a0, qB[0], z);
      z = MFMA(a1, qB[1], z);
      pacc[tt] = z;
    }

    const u32 w0 = mw[2*s], w1 = mw[2*s+1];
    f32x4 vmx = {-3e38f, -3e38f, -3e38f, -3e38f};
    #pragma unroll
    for (int tt = 0; tt < 4; tt++){
      u32 nib = (((tt < 2) ? w0 : w1) >> (16*(tt & 1) + cg4)) & 0xFu;
      #pragma unroll
      for (int j = 0; j < 4; j++){
        float v = pacc[tt][j] * 0.125f + (((nib >> j) & 1u) ? 0.f : -10000.f);
        pacc[tt][j] = v;
        vmx[j] = fmaxf(vmx[j], v);
      }
    }
    float tm = fmaxf(fmaxf(vmx[0], vmx[1]), fmaxf(vmx[2], vmx[3]));
    tm = fmaxf(tm, __shfl_xor(tm, 16, 64));
    tm = fmaxf(tm, __shfl_xor(tm, 32, 64));

    float mnew = fmaxf(m, tm);
    float alpha = __expf(m - mnew);
    m = mnew;
    #pragma unroll
    for (int db = 0; db < 4; db++) oacc[db] *= alpha;

    f32x4 vsum = {0.f, 0.f, 0.f, 0.f};
    #pragma unroll
    for (int tt = 0; tt < 4; tt++){
      #pragma unroll
      for (int j = 0; j < 4; j++){
        float e = __expf(pacc[tt][j] - m);
        pacc[tt][j] = e;
        vsum[j] += e;
      }
    }
    vs = vs * alpha + (vsum[0] + vsum[1] + vsum[2] + vsum[3]);

    bf16x8 pa[2];
    #pragma unroll
    for (int c = 0; c < 2; c++)
      #pragma unroll
      for (int e = 0; e < 4; e++){
        pa[c][e]   = (__bf16)pacc[2*c][e];
        pa[c][4+e] = (__bf16)pacc[2*c+1][e];
      }

    #pragma unroll
    for (int c = 0; c < 2; c++){
      const int ch0 = ((4*c     + (cg >> 1)) ^ r7);
      const int ch1 = ((4*c + 2 + (cg >> 1)) ^ r7);
      const int sub = (cg & 1) << 3;
      #pragma unroll
      for (int db = 0; db < 4; db++){
        const char* vrow = (const char*)&Vs[buf + (db*16 + cr)*64];
        bf16x8 vb;
        ((uint2*)&vb)[0] = *(const uint2*)(vrow + (ch0 << 4) + sub);
        ((uint2*)&vb)[1] = *(const uint2*)(vrow + (ch1 << 4) + sub);
        oacc[db] = MFMA(pa[c], vb, oacc[db]);
      }
    }

    if (s + 1 < 8) { asm volatile("s_waitcnt vmcnt(0)" ::: "memory"); }
    __builtin_amdgcn_sched_barrier(0);
    BAR();
  }

  vs += __shfl_xor(vs, 16, 64);
  vs += __shfl_xor(vs, 32, 64);
  #pragma unroll
  for (int j = 0; j < 4; j++){
    float ds = __shfl(vs, cg4 + j, 64);
    float inv = 1.0f / ds;
    #pragma unroll
    for (int db = 0; db < 4; db++)
      ctx[((size_t)b * 512 + qw + cg4 + j) * 768 + hh*64 + 16*db + cr] = f2bf(oacc[db][j] * inv);
  }
}

// ---------------- head: dense+tanh then scalar logit ----------------
__global__ void k_dense(const u16* __restrict__ hb, const float* __restrict__ W,
                        const float* __restrict__ bias, float* __restrict__ xt){
  __shared__ float xs[768];
  int b = blockIdx.x, t = threadIdx.x;
  const u16* hr = hb + (size_t)b * 512 * 768;
  xs[t] = bf2f(hr[t]); xs[t+256] = bf2f(hr[t+256]); xs[t+512] = bf2f(hr[t+512]);
  __syncthreads();
  for (int j = t; j < 768; j += 256){
    float a = bias[j];
    #pragma unroll 4
    for (int k = 0; k < 768; k++) a += xs[k] * W[(size_t)k * 768 + j];
    xt[(size_t)b * 768 + j] = tanhf(a);
  }
}

__global__ void k_logits(const float* __restrict__ xt, const float* __restrict__ ow,
                         const float* __restrict__ ob, float* __restrict__ out){
  __shared__ float sb[4];
  int b = blockIdx.x, t = threadIdx.x;
  const float* x = xt + (size_t)b * 768;
  float s = x[t]*ow[t] + x[t+256]*ow[t+256] + x[t+512]*ow[t+512];
  for (int o = 32; o; o >>= 1) s += __shfl_down(s, o, 64);
  int wv = t >> 6, ln = t & 63;
  if (!ln) sb[wv] = s;
  __syncthreads();
  if (t == 0) out[b] = sb[0] + sb[1] + sb[2] + sb[3] + ob[0];
}

// ---------------- launch ----------------
extern "C" void kernel_launch(void* const* d_in, const int* in_sizes, int n_in,
                              void* d_out, int out_size, void* d_ws, size_t ws_size,
                              hipStream_t stream){
  if (n_in < 23) return;
  if (ws_size < 534000000ull) return;

  const int*   ids  = (const int*)  d_in[0];
  const int*   pos  = (const int*)  d_in[1];
  const void*  amsk =               d_in[2];
  const float* wemb = (const float*)d_in[3];
  const float* pemb = (const float*)d_in[4];
  const float* lng  = (const float*)d_in[5];
  const float* lnb  = (const float*)d_in[6];
  const float* Wqkv = (const float*)d_in[7];
  const float* bqkv = (const float*)d_in[8];
  const float* Wo   = (const float*)d_in[9];
  const float* bo   = (const float*)d_in[10];
  const float* ln1g = (const float*)d_in[11];
  const float* ln1b = (const float*)d_in[12];
  const float* W1   = (const float*)d_in[13];
  const float* b1   = (const float*)d_in[14];
  const float* W2   = (const float*)d_in[15];
  const float* b2   = (const float*)d_in[16];
  const float* ln2g = (const float*)d_in[17];
  const float* ln2b = (const float*)d_in[18];
  const float* dW   = (const float*)d_in[19];
  const float* db   = (const float*)d_in[20];
  const float* oW   = (const float*)d_in[21];
  const float* ob   = (const float*)d_in[22];

  char* ws = (char*)d_ws;
  float* h    = (float*)(ws);
  u16*   hb   = (u16*)  (ws + 100663296);
  float* C    = (float*)(ws + 150994944);
  u16*   qkvp = (u16*)  (ws + 251658240);   // qp | kp | vbuf, each 50331648 B
  u16*   vt   = (u16*)  (ws + 402653184);
  u16*   act  = (u16*)  (ws + 251658240);   // aliases qkvp+vt (disjoint lifetime)
  u16*   ctx  = (u16*)  (ws + 452984832);
  u32*   mbit = (u32*)  (ws + 503316480);
  u16*   wt   = (u16*)  (ws + 505413632);
  float* xt   = (float*)(ws + 533725184);
  int*   flag = (int*)  (ws + 533921792);

  u16* qp   = qkvp;
  u16* kp   = qkvp + (size_t)25165824;
  u16* vbuf = qkvp + (size_t)50331648;

  u16* WqkvT = wt;                                  // [l][2304][768]
  u16* WoT   = WqkvT + (size_t)2*2304*768;          // [l][768][768]
  u16* W1T   = WoT   + (size_t)2*768*768;           // [l][3072][768]
  u16* W2T   = W1T   + (size_t)2*3072*768;          // [l][768][3072]

  k_maskprobe<<<1, 256, 0, stream>>>((const unsigned char*)amsk, flag);
  k_maskbits<<<8192, 256, 0, stream>>>(amsk, flag, mbit);

  for (int l = 0; l < 2; l++){
    k_transpose<<<dim3(24, 72), 256, 0, stream>>>(Wqkv + (size_t)l*768*2304, WqkvT + (size_t)l*2304*768, 768, 2304);
    k_transpose<<<dim3(24, 24), 256, 0, stream>>>(Wo   + (size_t)l*768*768,  WoT   + (size_t)l*768*768,  768, 768);
    k_transpose<<<dim3(24, 96), 256, 0, stream>>>(W1   + (size_t)l*768*3072, W1T   + (size_t)l*3072*768, 768, 3072);
    k_transpose<<<dim3(96, 24), 256, 0, stream>>>(W2   + (size_t)l*3072*768, W2T   + (size_t)l*768*3072, 3072, 768);
  }

  k_embed<<<32768, 256, 0, stream>>>(ids, wemb, h);
  k_nodeavg<<<dim3(32768, 3), 256, 0, stream>>>(pos, mbit, h);
  k_ln0<<<32768, 256, 0, stream>>>(pos, pemb, lng, lnb, h, hb);

  for (int l = 0; l < 2; l++){
    k_gemm3<3><<<dim3(9, 256), 512, 0, stream>>>(hb, WqkvT + (size_t)l*2304*768, bqkv + l*2304, (void*)qkvp, 32768, 2304, 768);
    k_vtrep<<<dim3(8, 768), 256, 0, stream>>>(vbuf, vt);
    k_attn3<<<dim3(8, 768), 256, 0, stream>>>(qp, kp, vt, mbit, ctx);
    k_gemm3<1><<<dim3(3, 256), 512, 0, stream>>>(ctx, WoT + (size_t)l*768*768, bo + l*768, (void*)C, 32768, 768, 768);
    k_lnres<<<32768, 256, 0, stream>>>(C, ln1g + l*768, ln1b + l*768, hb);
    k_gemm3<2><<<dim3(12, 256), 512, 0, stream>>>(hb, W1T + (size_t)l*3072*768, b1 + l*3072, (void*)act, 32768, 3072, 768);
    k_gemm3<1><<<dim3(3, 256), 512, 0, stream>>>(act, W2T + (size_t)l*768*3072, b2 + l*768, (void*)C, 32768, 768, 3072);
    k_lnres<<<32768, 256, 0, stream>>>(C, ln2g + l*768, ln2b + l*768, hb);
  }

  k_dense<<<64, 256, 0, stream>>>(hb, dW, db, xt);
  k_logits<<<64, 256, 0, stream>>>(xt, oW, ob, (float*)d_out);
}

// Round 10
// 2012.996 us; speedup vs baseline: 1.6735x; 1.1047x over previous
//
#include <hip/hip_runtime.h>

typedef unsigned short u16;
typedef unsigned int   u32;
typedef __bf16 bf16x8 __attribute__((ext_vector_type(8)));
typedef float  f32x4  __attribute__((ext_vector_type(4)));

#define DEVI __device__ __forceinline__

DEVI u16 f2bf(float f){
  u32 u = __builtin_bit_cast(u32, f);
  u32 r = (u + 0x7fffu + ((u >> 16) & 1u)) >> 16;   // RNE
  return (u16)r;
}
DEVI float bf2f(u16 u){
  u32 x = ((u32)u) << 16;
  return __builtin_bit_cast(float, x);
}

DEVI void gload16(const void* g, void* lds){
  __builtin_amdgcn_global_load_lds(
      (const __attribute__((address_space(1))) void*)g,
      (__attribute__((address_space(3))) void*)lds, 16, 0, 0);
}

DEVI f32x4 MFMA(bf16x8 a, bf16x8 b, f32x4 c){
  return __builtin_amdgcn_mfma_f32_16x16x32_bf16(a, b, c, 0, 0, 0);
}

#define BAR() do { asm volatile("s_barrier" ::: "memory"); \
                   __builtin_amdgcn_sched_barrier(0); } while(0)

// ---------------- mask dtype probe: 1 => uint8 bytes, 0 => int32 ----------------
__global__ void k_maskprobe(const unsigned char* __restrict__ m, int* __restrict__ flag){
  __shared__ int s;
  if (threadIdx.x == 0) s = 0;
  __syncthreads();
  int acc = 0;
  for (int i = threadIdx.x; i < 65536; i += 256)
    if ((i & 3) != 0 && m[i] != 0) acc++;
  atomicAdd(&s, acc);
  __syncthreads();
  if (threadIdx.x == 0) *flag = (s > 0) ? 1 : 0;
}

// ---------------- pack attn_mask to bitmask [B*S][16 words] ----------------
__global__ void k_maskbits(const void* __restrict__ mask, const int* __restrict__ flag,
                           u32* __restrict__ mb){
  int row  = blockIdx.x * 4 + (threadIdx.x >> 6);   // b*512+q
  int lane = threadIdx.x & 63;
  bool bytes = (*flag != 0);
  for (int c0 = 0; c0 < 512; c0 += 64){
    int v;
    if (bytes) v = ((const unsigned char*)mask)[(size_t)row * 512 + c0 + lane];
    else       v = ((const int*)mask)[(size_t)row * 512 + c0 + lane];
    unsigned long long bits = __ballot(v != 0);
    if (lane == 0){
      mb[(size_t)row * 16 + (c0 >> 5)]     = (u32)(bits & 0xffffffffull);
      mb[(size_t)row * 16 + (c0 >> 5) + 1] = (u32)(bits >> 32);
    }
  }
}

// ---------------- embedding gather ----------------
__global__ void k_embed(const int* __restrict__ ids, const float* __restrict__ wemb,
                        float* __restrict__ h){
  int row = blockIdx.x;
  const float* s = wemb + (size_t)ids[row] * 768;
  float* d = h + (size_t)row * 768;
  int t = threadIdx.x;
  d[t] = s[t]; d[t + 256] = s[t + 256]; d[t + 512] = s[t + 512];
}

// ---------------- node-average (rows with pos==0) ----------------
__global__ void k_nodeavg(const int* __restrict__ pos, const u32* __restrict__ mb,
                          float* __restrict__ h){
  int row = blockIdx.x;                 // b*512+n
  if (pos[row] != 0) return;
  int b = row >> 9;
  int c = blockIdx.y * 256 + threadIdx.x;
  const u32* mrow = mb + (size_t)row * 16;
  const int* pb = pos + ((size_t)b << 9);
  float a = 0.f, cnt = 0.f;
  #pragma unroll 4
  for (int t = 0; t < 512; t++){
    if (pb[t] >= 2 && ((mrow[t >> 5] >> (t & 31)) & 1)){
      a += h[(((size_t)b << 9) + t) * 768 + c];
      cnt += 1.f;
    }
  }
  h[(size_t)row * 768 + c] = a / (cnt + 1e-10f);
}

// ---------------- LN kernels ----------------
// ln0: reads f32 h (+pos emb), writes ONLY bf16 hb (residual stream is bf16 from here on)
__global__ void k_ln0(const int* __restrict__ pos, const float* __restrict__ pemb,
                      const float* __restrict__ g, const float* __restrict__ be,
                      const float* __restrict__ h, u16* __restrict__ hb){
  __shared__ float s1[4], s2[4];
  int row = blockIdx.x, t = threadIdx.x;
  const float* hr = h + (size_t)row * 768;
  const float* pr = pemb + (size_t)pos[row] * 768;
  float x0 = hr[t] + pr[t], x1 = hr[t+256] + pr[t+256], x2 = hr[t+512] + pr[t+512];
  float s = x0 + x1 + x2, q = x0*x0 + x1*x1 + x2*x2;
  for (int o = 32; o; o >>= 1){ s += __shfl_down(s, o, 64); q += __shfl_down(q, o, 64); }
  int wv = t >> 6, ln = t & 63;
  if (!ln){ s1[wv] = s; s2[wv] = q; }
  __syncthreads();
  s = s1[0]+s1[1]+s1[2]+s1[3]; q = s2[0]+s2[1]+s2[2]+s2[3];
  float mu = s * (1.f/768.f);
  float rs = rsqrtf(q * (1.f/768.f) - mu*mu + 1e-5f);
  u16* hbr = hb + (size_t)row * 768;
  hbr[t]     = f2bf((x0-mu)*rs*g[t]     + be[t]);
  hbr[t+256] = f2bf((x1-mu)*rs*g[t+256] + be[t+256]);
  hbr[t+512] = f2bf((x2-mu)*rs*g[t+512] + be[t+512]);
}

// lnres: hb (bf16, in-place) + C (f32) -> LN -> hb
__global__ void k_lnres(const float* __restrict__ C, const float* __restrict__ g,
                        const float* __restrict__ be, u16* __restrict__ hb){
  __shared__ float s1[4], s2[4];
  int row = blockIdx.x, t = threadIdx.x;
  u16* hr = hb + (size_t)row * 768;
  const float* cr = C + (size_t)row * 768;
  float x0 = bf2f(hr[t])     + cr[t];
  float x1 = bf2f(hr[t+256]) + cr[t+256];
  float x2 = bf2f(hr[t+512]) + cr[t+512];
  float s = x0 + x1 + x2, q = x0*x0 + x1*x1 + x2*x2;
  for (int o = 32; o; o >>= 1){ s += __shfl_down(s, o, 64); q += __shfl_down(q, o, 64); }
  int wv = t >> 6, ln = t & 63;
  if (!ln){ s1[wv] = s; s2[wv] = q; }
  __syncthreads();
  s = s1[0]+s1[1]+s1[2]+s1[3]; q = s2[0]+s2[1]+s2[2]+s2[3];
  float mu = s * (1.f/768.f);
  float rs = rsqrtf(q * (1.f/768.f) - mu*mu + 1e-5f);
  hr[t]     = f2bf((x0-mu)*rs*g[t]     + be[t]);
  hr[t+256] = f2bf((x1-mu)*rs*g[t+256] + be[t+256]);
  hr[t+512] = f2bf((x2-mu)*rs*g[t+512] + be[t+512]);
}

// ---------------- weight transpose+cast: src[K][N] f32 -> dst[N][K] bf16 ----------------
__global__ void k_transpose(const float* __restrict__ src, u16* __restrict__ dst,
                            int K, int N){
  __shared__ float tile[32][33];
  int k0 = blockIdx.x * 32, n0 = blockIdx.y * 32;
  int tx = threadIdx.x & 31, ty = threadIdx.x >> 5;   // ty 0..7
  #pragma unroll
  for (int i = 0; i < 32; i += 8)
    tile[ty + i][tx] = src[(size_t)(k0 + ty + i) * N + n0 + tx];
  __syncthreads();
  #pragma unroll
  for (int i = 0; i < 32; i += 8)
    dst[(size_t)(n0 + ty + i) * K + k0 + tx] = f2bf(tile[tx][ty + i]);
}

// ========== 128x256 BK=32 GEMM, prefetch-distance-2 (A & B triple-buffered) ==========
DEVI void stageA32(const u16* __restrict__ src, int K, u16* lds, int tid){
  int r = tid >> 2, c = tid & 3;
  int sc = c ^ ((r >> 1) & 3);
  gload16(src + (size_t)r*K + sc*8, lds + (size_t)tid*8);
}
DEVI void stageB32(const u16* __restrict__ src, int K, u16* lds, int tid){
  #pragma unroll
  for (int j = 0; j < 2; j++){
    int p = j*512 + tid;
    int r = p >> 2, c = p & 3;
    int sc = c ^ ((r >> 1) & 3);
    gload16(src + (size_t)r*K + sc*8, lds + (size_t)p*8);
  }
}

template<int EPI>
__global__ __launch_bounds__(512, 4)
void k_gemm3(const u16* __restrict__ A, const u16* __restrict__ BT,
             const float* __restrict__ bias, void* __restrict__ out,
             int M, int N, int K){
  __shared__ __align__(16) u16 sm[36864];   // 72 KiB
  const int tid = threadIdx.x;
  const int w = tid >> 6, lane = tid & 63;
  const int wm = w >> 2, wn = w & 3;
  const int cr = lane & 15, cg = lane >> 4;

  // bijective XCD-chunked remap (m204)
  const int nbn = gridDim.x;
  const int nwg = nbn * gridDim.y;
  const int d   = blockIdx.y * nbn + blockIdx.x;
  const int xcd = d & 7, qq = nwg >> 3, rr = nwg & 7;
  const int logical = (xcd < rr ? xcd*(qq+1) : rr*(qq+1) + (xcd-rr)*qq) + (d >> 3);
  const int m0 = (logical / nbn) * 128;
  const int n0 = (logical % nbn) * 256;

  const int NT = K >> 5;
  const u16* Abase = A  + (size_t)m0 * K;
  const u16* Bbase = BT + (size_t)n0 * K;
  const int rowA = wm*64 + cr;
  const int rowB = wn*64 + cr;

  f32x4 acc[4][4] = {};
  bf16x8 afr[4], bfr[4];

  stageA32(Abase, K, sm, tid);
  stageB32(Bbase, K, sm + 12288, tid);
  if (NT > 1){
    stageA32(Abase + 32, K, sm + 4096, tid);
    stageB32(Bbase + 32, K, sm + 12288 + 8192, tid);
    asm volatile("s_waitcnt vmcnt(3)" ::: "memory");
  } else {
    asm volatile("s_waitcnt vmcnt(0)" ::: "memory");
  }
  __builtin_amdgcn_sched_barrier(0);
  BAR();

  int bcur = 0;
  for (int t = 0; t < NT; ++t){
    const int ab = bcur << 12;
    const int bb = 12288 + (bcur << 13);
    int bn2 = bcur + 2; if (bn2 >= 3) bn2 -= 3;

    #pragma unroll
    for (int n = 0; n < 4; n++){
      int r = rowB + n*16;
      bfr[n] = *(const bf16x8*)&sm[bb + r*32 + ((cg ^ ((r >> 1) & 3)) << 3)];
    }
    #pragma unroll
    for (int i = 0; i < 4; i++){
      int r = rowA + i*16;
      afr[i] = *(const bf16x8*)&sm[ab + r*32 + ((cg ^ ((r >> 1) & 3)) << 3)];
    }
    if (t + 2 < NT){
      stageA32(Abase + (size_t)(t+2)*32, K, sm + (bn2 << 12), tid);
      stageB32(Bbase + (size_t)(t+2)*32, K, sm + 12288 + (bn2 << 13), tid);
    }

    __builtin_amdgcn_s_setprio(1);
    #pragma unroll
    for (int i = 0; i < 4; i++)
      #pragma unroll
      for (int n = 0; n < 4; n++)
        acc[i][n] = MFMA(afr[i], bfr[n], acc[i][n]);
    __builtin_amdgcn_s_setprio(0);

    if (t + 2 < NT) { asm volatile("s_waitcnt vmcnt(3)" ::: "memory"); }
    else            { asm volatile("s_waitcnt vmcnt(0)" ::: "memory"); }
    __builtin_amdgcn_sched_barrier(0);
    BAR();
    bcur = bcur + 1; if (bcur >= 3) bcur = 0;
  }

  // ---- epilogue
  #pragma unroll
  for (int n = 0; n < 4; n++){
    int col = n0 + wn*64 + n*16 + cr;
    float bv = bias[col];
    int sec = 0, hd = 0, dcol = 0;
    if (EPI == 3){
      sec = (col >= 1536) ? 2 : (col >= 768 ? 1 : 0);
      hd  = (col - sec*768) >> 6;
      dcol = col & 63;
    }
    #pragma unroll
    for (int i = 0; i < 4; i++){
      #pragma unroll
      for (int j = 0; j < 4; j++){
        int row = m0 + wm*64 + i*16 + cg*4 + j;
        float v = acc[i][n][j] + bv;
        if (EPI == 2) v = 0.5f * v * (1.f + erff(v * 0.70710678118654752f));
        if (EPI == 1)      ((float*)out)[(size_t)row * N + col] = v;
        else if (EPI == 3){
          int b = row >> 9, s = row & 511;
          ((u16*)out)[(size_t)sec*25165824 + (((size_t)(b*12 + hd)*512 + s) << 6) + dcol] = f2bf(v);
        }
        else               ((u16*) out)[(size_t)row * N + col] = f2bf(v);
      }
    }
  }
}

// ---------------- V^T repack: vbuf[bh][512][64] -> vt[bh][64][512] ----------------
__global__ void k_vtrep(const u16* __restrict__ vbuf, u16* __restrict__ vt){
  __shared__ u16 tile[64][72];
  int bh = blockIdx.y;               // b*12+h
  int t0 = blockIdx.x * 64;
  int tid = threadIdx.x;
  #pragma unroll
  for (int i = 0; i < 16; i++){
    int idx = tid + i * 256;
    int tt = idx >> 6, d = idx & 63;
    tile[tt][d] = vbuf[((size_t)bh * 512 + t0 + tt) * 64 + d];
  }
  __syncthreads();
  #pragma unroll
  for (int i = 0; i < 16; i++){
    int idx = tid + i * 256;
    int d = idx >> 6, tt = idx & 63;
    vt[((size_t)bh * 64 + d) * 512 + t0 + tt] = tile[tt][d];
  }
}

// ---------------- attention v3: flash/online, swapped QK^T, LDS-staged K & V^T ----------
DEVI void stage64(const u16* __restrict__ src, int stride, u16* lds, int w, int lane){
  #pragma unroll
  for (int j = 0; j < 2; j++){
    int p  = j*256 + w*64 + lane;        // piece 0..511 (16B each)
    int r  = p >> 3;                     // row 0..63
    int c8 = (p & 7) ^ (r & 7);          // inverse-swizzled source chunk
    gload16(src + (size_t)r*stride + c8*8, lds + (size_t)p*8);
  }
}

__global__ __launch_bounds__(256, 4)
void k_attn3(const u16* __restrict__ qp, const u16* __restrict__ kp,
             const u16* __restrict__ vt, const u32* __restrict__ mb,
             u16* __restrict__ ctx){
  __shared__ __align__(16) u16 Ks[8192];   // 2 x [64][64]
  __shared__ __align__(16) u16 Vs[8192];   // 2 x [64 d][64 kv]
  const int tid = threadIdx.x, wv = tid >> 6, lane = tid & 63;
  const int cr = lane & 15, cg = lane >> 4;
  const int cg4 = cg * 4;
  const int r7 = cr & 7;

  const int dd = blockIdx.x + (blockIdx.y << 3);
  const int logical = (dd & 7) * 768 + (dd >> 3);
  const int bh = logical >> 3;
  const int qblk = logical & 7;
  const int b = bh / 12, hh = bh % 12;
  const int qw = qblk * 64 + wv * 16;
  const int qrow = qw + cr;
  const size_t base = (size_t)bh * 512 * 64;
  const u16* vtb = vt + (size_t)bh * 64 * 512;

  const int slot0 = ((cg    ) ^ r7) << 3;
  const int slot1 = ((4 + cg) ^ r7) << 3;

  bf16x8 qB[2];
  #pragma unroll
  for (int ks = 0; ks < 2; ks++)
    qB[ks] = *(const bf16x8*)&qp[base + (size_t)qrow * 64 + ks*32 + cg*8];

  u32 mw[16];
  {
    const u32* mrow = mb + ((size_t)b * 512 + qrow) * 16;
    #pragma unroll
    for (int i = 0; i < 4; i++){
      uint4 v4 = *(const uint4*)&mrow[i*4];
      mw[i*4+0] = v4.x; mw[i*4+1] = v4.y; mw[i*4+2] = v4.z; mw[i*4+3] = v4.w;
    }
  }

  stage64(kp + base, 64, Ks, wv, lane);
  stage64(vtb,      512, Vs, wv, lane);
  asm volatile("s_waitcnt vmcnt(0)" ::: "memory");
  __builtin_amdgcn_sched_barrier(0);
  BAR();

  float m = -3e38f, vs = 0.f;
  f32x4 oacc[4] = {};

  for (int s = 0; s < 8; ++s){
    const int buf = (s & 1) << 12;
    const int nbf = ((s + 1) & 1) << 12;

    if (s + 1 < 8){
      stage64(kp + base + (size_t)(s+1)*4096, 64, Ks + nbf, wv, lane);
      stage64(vtb + (size_t)(s+1)*64,        512, Vs + nbf, wv, lane);
    }

    f32x4 pacc[4];
    #pragma unroll
    for (int tt = 0; tt < 4; tt++){
      bf16x8 a0 = *(const bf16x8*)&Ks[buf + (tt*16 + cr)*64 + slot0];
      bf16x8 a1 = *(const bf16x8*)&Ks[buf + (tt*16 + cr)*64 + slot1];
      f32x4 z = {0.f, 0.f, 0.f, 0.f};
      z = MFMA(a0, qB[0], z);
      z = MFMA(a1, qB[1], z);
      pacc[tt] = z;
    }

    const u32 w0 = mw[2*s], w1 = mw[2*s+1];
    f32x4 vmx = {-3e38f, -3e38f, -3e38f, -3e38f};
    #pragma unroll
    for (int tt = 0; tt < 4; tt++){
      u32 nib = (((tt < 2) ? w0 : w1) >> (16*(tt & 1) + cg4)) & 0xFu;
      #pragma unroll
      for (int j = 0; j < 4; j++){
        float v = pacc[tt][j] * 0.125f + (((nib >> j) & 1u) ? 0.f : -10000.f);
        pacc[tt][j] = v;
        vmx[j] = fmaxf(vmx[j], v);
      }
    }
    float tm = fmaxf(fmaxf(vmx[0], vmx[1]), fmaxf(vmx[2], vmx[3]));
    tm = fmaxf(tm, __shfl_xor(tm, 16, 64));
    tm = fmaxf(tm, __shfl_xor(tm, 32, 64));

    float mnew = fmaxf(m, tm);
    float alpha = __expf(m - mnew);
    m = mnew;
    #pragma unroll
    for (int db = 0; db < 4; db++) oacc[db] *= alpha;

    f32x4 vsum = {0.f, 0.f, 0.f, 0.f};
    #pragma unroll
    for (int tt = 0; tt < 4; tt++){
      #pragma unroll
      for (int j = 0; j < 4; j++){
        float e = __expf(pacc[tt][j] - m);
        pacc[tt][j] = e;
        vsum[j] += e;
      }
    }
    vs = vs * alpha + (vsum[0] + vsum[1] + vsum[2] + vsum[3]);

    bf16x8 pa[2];
    #pragma unroll
    for (int c = 0; c < 2; c++)
      #pragma unroll
      for (int e = 0; e < 4; e++){
        pa[c][e]   = (__bf16)pacc[2*c][e];
        pa[c][4+e] = (__bf16)pacc[2*c+1][e];
      }

    #pragma unroll
    for (int c = 0; c < 2; c++){
      const int ch0 = ((4*c     + (cg >> 1)) ^ r7);
      const int ch1 = ((4*c + 2 + (cg >> 1)) ^ r7);
      const int sub = (cg & 1) << 3;
      #pragma unroll
      for (int db = 0; db < 4; db++){
        const char* vrow = (const char*)&Vs[buf + (db*16 + cr)*64];
        bf16x8 vb;
        ((uint2*)&vb)[0] = *(const uint2*)(vrow + (ch0 << 4) + sub);
        ((uint2*)&vb)[1] = *(const uint2*)(vrow + (ch1 << 4) + sub);
        oacc[db] = MFMA(pa[c], vb, oacc[db]);
      }
    }

    if (s + 1 < 8) { asm volatile("s_waitcnt vmcnt(0)" ::: "memory"); }
    __builtin_amdgcn_sched_barrier(0);
    BAR();
  }

  vs += __shfl_xor(vs, 16, 64);
  vs += __shfl_xor(vs, 32, 64);
  #pragma unroll
  for (int j = 0; j < 4; j++){
    float ds = __shfl(vs, cg4 + j, 64);
    float inv = 1.0f / ds;
    #pragma unroll
    for (int db = 0; db < 4; db++)
      ctx[((size_t)b * 512 + qw + cg4 + j) * 768 + hh*64 + 16*db + cr] = f2bf(oacc[db][j] * inv);
  }
}

// ---------------- head: K-split dense+tanh (grid = 12 col-chunks x 64 batches) ---------
__global__ __launch_bounds__(256)
void k_dense(const u16* __restrict__ hb, const float* __restrict__ W,
             const float* __restrict__ bias, float* __restrict__ xt){
  __shared__ float xs[768];
  __shared__ float red[256];
  const int b = blockIdx.y, t = threadIdx.x;
  const u16* hr = hb + (size_t)b * 512 * 768;   // row 0 of batch b
  xs[t] = bf2f(hr[t]); xs[t+256] = bf2f(hr[t+256]); xs[t+512] = bf2f(hr[t+512]);
  __syncthreads();
  const int col = blockIdx.x * 64 + (t & 63);
  const int ks  = t >> 6;                        // 0..3, k-slice of 192
  const float* Wp = W + (size_t)(ks * 192) * 768 + col;
  const float* xp = xs + ks * 192;
  float a = 0.f;
  #pragma unroll 8
  for (int k = 0; k < 192; k++) a += xp[k] * Wp[(size_t)k * 768];
  red[t] = a;
  __syncthreads();
  if (t < 64){
    float y = red[t] + red[t+64] + red[t+128] + red[t+192] + bias[col];
    xt[(size_t)b * 768 + col] = tanhf(y);
  }
}

__global__ void k_logits(const float* __restrict__ xt, const float* __restrict__ ow,
                         const float* __restrict__ ob, float* __restrict__ out){
  __shared__ float sb[4];
  int b = blockIdx.x, t = threadIdx.x;
  const float* x = xt + (size_t)b * 768;
  float s = x[t]*ow[t] + x[t+256]*ow[t+256] + x[t+512]*ow[t+512];
  for (int o = 32; o; o >>= 1) s += __shfl_down(s, o, 64);
  int wv = t >> 6, ln = t & 63;
  if (!ln) sb[wv] = s;
  __syncthreads();
  if (t == 0) out[b] = sb[0] + sb[1] + sb[2] + sb[3] + ob[0];
}

// ---------------- launch ----------------
extern "C" void kernel_launch(void* const* d_in, const int* in_sizes, int n_in,
                              void* d_out, int out_size, void* d_ws, size_t ws_size,
                              hipStream_t stream){
  if (n_in < 23) return;
  if (ws_size < 534000000ull) return;

  const int*   ids  = (const int*)  d_in[0];
  const int*   pos  = (const int*)  d_in[1];
  const void*  amsk =               d_in[2];
  const float* wemb = (const float*)d_in[3];
  const float* pemb = (const float*)d_in[4];
  const float* lng  = (const float*)d_in[5];
  const float* lnb  = (const float*)d_in[6];
  const float* Wqkv = (const float*)d_in[7];
  const float* bqkv = (const float*)d_in[8];
  const float* Wo   = (const float*)d_in[9];
  const float* bo   = (const float*)d_in[10];
  const float* ln1g = (const float*)d_in[11];
  const float* ln1b = (const float*)d_in[12];
  const float* W1   = (const float*)d_in[13];
  const float* b1   = (const float*)d_in[14];
  const float* W2   = (const float*)d_in[15];
  const float* b2   = (const float*)d_in[16];
  const float* ln2g = (const float*)d_in[17];
  const float* ln2b = (const float*)d_in[18];
  const float* dW   = (const float*)d_in[19];
  const float* db   = (const float*)d_in[20];
  const float* oW   = (const float*)d_in[21];
  const float* ob   = (const float*)d_in[22];

  char* ws = (char*)d_ws;
  float* h    = (float*)(ws);
  u16*   hb   = (u16*)  (ws + 100663296);
  float* C    = (float*)(ws + 150994944);
  u16*   qkvp = (u16*)  (ws + 251658240);   // qp | kp | vbuf, each 50331648 B
  u16*   vt   = (u16*)  (ws + 402653184);
  u16*   act  = (u16*)  (ws + 251658240);   // aliases qkvp+vt (disjoint lifetime)
  u16*   ctx  = (u16*)  (ws + 452984832);
  u32*   mbit = (u32*)  (ws + 503316480);
  u16*   wt   = (u16*)  (ws + 505413632);
  float* xt   = (float*)(ws + 533725184);
  int*   flag = (int*)  (ws + 533921792);

  u16* qp   = qkvp;
  u16* kp   = qkvp + (size_t)25165824;
  u16* vbuf = qkvp + (size_t)50331648;

  u16* WqkvT = wt;                                  // [l][2304][768]
  u16* WoT   = WqkvT + (size_t)2*2304*768;          // [l][768][768]
  u16* W1T   = WoT   + (size_t)2*768*768;           // [l][3072][768]
  u16* W2T   = W1T   + (size_t)2*3072*768;          // [l][768][3072]

  k_maskprobe<<<1, 256, 0, stream>>>((const unsigned char*)amsk, flag);
  k_maskbits<<<8192, 256, 0, stream>>>(amsk, flag, mbit);

  for (int l = 0; l < 2; l++){
    k_transpose<<<dim3(24, 72), 256, 0, stream>>>(Wqkv + (size_t)l*768*2304, WqkvT + (size_t)l*2304*768, 768, 2304);
    k_transpose<<<dim3(24, 24), 256, 0, stream>>>(Wo   + (size_t)l*768*768,  WoT   + (size_t)l*768*768,  768, 768);
    k_transpose<<<dim3(24, 96), 256, 0, stream>>>(W1   + (size_t)l*768*3072, W1T   + (size_t)l*3072*768, 768, 3072);
    k_transpose<<<dim3(96, 24), 256, 0, stream>>>(W2   + (size_t)l*3072*768, W2T   + (size_t)l*768*3072, 3072, 768);
  }

  k_embed<<<32768, 256, 0, stream>>>(ids, wemb, h);
  k_nodeavg<<<dim3(32768, 3), 256, 0, stream>>>(pos, mbit, h);
  k_ln0<<<32768, 256, 0, stream>>>(pos, pemb, lng, lnb, h, hb);

  for (int l = 0; l < 2; l++){
    k_gemm3<3><<<dim3(9, 256), 512, 0, stream>>>(hb, WqkvT + (size_t)l*2304*768, bqkv + l*2304, (void*)qkvp, 32768, 2304, 768);
    k_vtrep<<<dim3(8, 768), 256, 0, stream>>>(vbuf, vt);
    k_attn3<<<dim3(8, 768), 256, 0, stream>>>(qp, kp, vt, mbit, ctx);
    k_gemm3<1><<<dim3(3, 256), 512, 0, stream>>>(ctx, WoT + (size_t)l*768*768, bo + l*768, (void*)C, 32768, 768, 768);
    k_lnres<<<32768, 256, 0, stream>>>(C, ln1g + l*768, ln1b + l*768, hb);
    k_gemm3<2><<<dim3(12, 256), 512, 0, stream>>>(hb, W1T + (size_t)l*3072*768, b1 + l*3072, (void*)act, 32768, 3072, 768);
    k_gemm3<1><<<dim3(3, 256), 512, 0, stream>>>(act, W2T + (size_t)l*768*3072, b2 + l*768, (void*)C, 32768, 768, 3072);
    k_lnres<<<32768, 256, 0, stream>>>(C, ln2g + l*768, ln2b + l*768, hb);
  }

  k_dense<<<dim3(12, 64), 256, 0, stream>>>(hb, dW, db, xt);
  k_logits<<<64, 256, 0, stream>>>(xt, oW, ob, (float*)d_out);
}

// Round 11
// 1888.278 us; speedup vs baseline: 1.7840x; 1.0660x over previous
//
#include <hip/hip_runtime.h>

typedef unsigned short u16;
typedef unsigned int   u32;
typedef __bf16 bf16x8 __attribute__((ext_vector_type(8)));
typedef float  f32x4  __attribute__((ext_vector_type(4)));

#define DEVI __device__ __forceinline__

DEVI u16 f2bf(float f){
  u32 u = __builtin_bit_cast(u32, f);
  u32 r = (u + 0x7fffu + ((u >> 16) & 1u)) >> 16;   // RNE
  return (u16)r;
}
DEVI float bf2f(u16 u){
  u32 x = ((u32)u) << 16;
  return __builtin_bit_cast(float, x);
}

DEVI void gload16(const void* g, void* lds){
  __builtin_amdgcn_global_load_lds(
      (const __attribute__((address_space(1))) void*)g,
      (__attribute__((address_space(3))) void*)lds, 16, 0, 0);
}

DEVI f32x4 MFMA(bf16x8 a, bf16x8 b, f32x4 c){
  return __builtin_amdgcn_mfma_f32_16x16x32_bf16(a, b, c, 0, 0, 0);
}

#define BAR() do { asm volatile("s_barrier" ::: "memory"); \
                   __builtin_amdgcn_sched_barrier(0); } while(0)

// ---------------- mask dtype probe: 1 => uint8 bytes, 0 => int32 ----------------
__global__ void k_maskprobe(const unsigned char* __restrict__ m, int* __restrict__ flag){
  __shared__ int s;
  if (threadIdx.x == 0) s = 0;
  __syncthreads();
  int acc = 0;
  for (int i = threadIdx.x; i < 65536; i += 256)
    if ((i & 3) != 0 && m[i] != 0) acc++;
  atomicAdd(&s, acc);
  __syncthreads();
  if (threadIdx.x == 0) *flag = (s > 0) ? 1 : 0;
}

// ---------------- pack attn_mask to bitmask [B*S][16 words] ----------------
__global__ void k_maskbits(const void* __restrict__ mask, const int* __restrict__ flag,
                           u32* __restrict__ mb){
  int row  = blockIdx.x * 4 + (threadIdx.x >> 6);   // b*512+q
  int lane = threadIdx.x & 63;
  bool bytes = (*flag != 0);
  for (int c0 = 0; c0 < 512; c0 += 64){
    int v;
    if (bytes) v = ((const unsigned char*)mask)[(size_t)row * 512 + c0 + lane];
    else       v = ((const int*)mask)[(size_t)row * 512 + c0 + lane];
    unsigned long long bits = __ballot(v != 0);
    if (lane == 0){
      mb[(size_t)row * 16 + (c0 >> 5)]     = (u32)(bits & 0xffffffffull);
      mb[(size_t)row * 16 + (c0 >> 5) + 1] = (u32)(bits >> 32);
    }
  }
}

// ---------------- embedding gather ----------------
__global__ void k_embed(const int* __restrict__ ids, const float* __restrict__ wemb,
                        float* __restrict__ h){
  int row = blockIdx.x;
  const float* s = wemb + (size_t)ids[row] * 768;
  float* d = h + (size_t)row * 768;
  int t = threadIdx.x;
  d[t] = s[t]; d[t + 256] = s[t + 256]; d[t + 512] = s[t + 512];
}

// ---------------- node-average (rows with pos==0) ----------------
__global__ void k_nodeavg(const int* __restrict__ pos, const u32* __restrict__ mb,
                          float* __restrict__ h){
  int row = blockIdx.x;                 // b*512+n
  if (pos[row] != 0) return;
  int b = row >> 9;
  int c = blockIdx.y * 256 + threadIdx.x;
  const u32* mrow = mb + (size_t)row * 16;
  const int* pb = pos + ((size_t)b << 9);
  float a = 0.f, cnt = 0.f;
  #pragma unroll 4
  for (int t = 0; t < 512; t++){
    if (pb[t] >= 2 && ((mrow[t >> 5] >> (t & 31)) & 1)){
      a += h[(((size_t)b << 9) + t) * 768 + c];
      cnt += 1.f;
    }
  }
  h[(size_t)row * 768 + c] = a / (cnt + 1e-10f);
}

// ---------------- LN kernels ----------------
__global__ void k_ln0(const int* __restrict__ pos, const float* __restrict__ pemb,
                      const float* __restrict__ g, const float* __restrict__ be,
                      const float* __restrict__ h, u16* __restrict__ hb){
  __shared__ float s1[4], s2[4];
  int row = blockIdx.x, t = threadIdx.x;
  const float* hr = h + (size_t)row * 768;
  const float* pr = pemb + (size_t)pos[row] * 768;
  float x0 = hr[t] + pr[t], x1 = hr[t+256] + pr[t+256], x2 = hr[t+512] + pr[t+512];
  float s = x0 + x1 + x2, q = x0*x0 + x1*x1 + x2*x2;
  for (int o = 32; o; o >>= 1){ s += __shfl_down(s, o, 64); q += __shfl_down(q, o, 64); }
  int wv = t >> 6, ln = t & 63;
  if (!ln){ s1[wv] = s; s2[wv] = q; }
  __syncthreads();
  s = s1[0]+s1[1]+s1[2]+s1[3]; q = s2[0]+s2[1]+s2[2]+s2[3];
  float mu = s * (1.f/768.f);
  float rs = rsqrtf(q * (1.f/768.f) - mu*mu + 1e-5f);
  u16* hbr = hb + (size_t)row * 768;
  hbr[t]     = f2bf((x0-mu)*rs*g[t]     + be[t]);
  hbr[t+256] = f2bf((x1-mu)*rs*g[t+256] + be[t+256]);
  hbr[t+512] = f2bf((x2-mu)*rs*g[t+512] + be[t+512]);
}

__global__ void k_lnres(const float* __restrict__ C, const float* __restrict__ g,
                        const float* __restrict__ be, u16* __restrict__ hb){
  __shared__ float s1[4], s2[4];
  int row = blockIdx.x, t = threadIdx.x;
  u16* hr = hb + (size_t)row * 768;
  const float* cr = C + (size_t)row * 768;
  float x0 = bf2f(hr[t])     + cr[t];
  float x1 = bf2f(hr[t+256]) + cr[t+256];
  float x2 = bf2f(hr[t+512]) + cr[t+512];
  float s = x0 + x1 + x2, q = x0*x0 + x1*x1 + x2*x2;
  for (int o = 32; o; o >>= 1){ s += __shfl_down(s, o, 64); q += __shfl_down(q, o, 64); }
  int wv = t >> 6, ln = t & 63;
  if (!ln){ s1[wv] = s; s2[wv] = q; }
  __syncthreads();
  s = s1[0]+s1[1]+s1[2]+s1[3]; q = s2[0]+s2[1]+s2[2]+s2[3];
  float mu = s * (1.f/768.f);
  float rs = rsqrtf(q * (1.f/768.f) - mu*mu + 1e-5f);
  hr[t]     = f2bf((x0-mu)*rs*g[t]     + be[t]);
  hr[t+256] = f2bf((x1-mu)*rs*g[t+256] + be[t+256]);
  hr[t+512] = f2bf((x2-mu)*rs*g[t+512] + be[t+512]);
}

// ---------------- weight transpose+cast: src[K][N] f32 -> dst[N][K] bf16 ----------------
__global__ void k_transpose(const float* __restrict__ src, u16* __restrict__ dst,
                            int K, int N){
  __shared__ float tile[32][33];
  int k0 = blockIdx.x * 32, n0 = blockIdx.y * 32;
  int tx = threadIdx.x & 31, ty = threadIdx.x >> 5;   // ty 0..7
  #pragma unroll
  for (int i = 0; i < 32; i += 8)
    tile[ty + i][tx] = src[(size_t)(k0 + ty + i) * N + n0 + tx];
  __syncthreads();
  #pragma unroll
  for (int i = 0; i < 32; i += 8)
    dst[(size_t)(n0 + ty + i) * K + k0 + tx] = f2bf(tile[tx][ty + i]);
}

// ========== 128x256 BK=32 GEMM, prefetch-distance-2, LDS-staged bf16 epilogue ==========
// Main loop unchanged from round 9. Epilogue for bf16 outputs (EPI 0/2/3) now stages the
// C tile in LDS ([128][264] u16, padded rows) and writes dwordx4 full-line stores —
// kills the 32B-partial-line RMW (FETCH/WRITE amplification seen in round-10 profile).
// EPI=1 (f32) already writes full 64B lines; kept direct.

DEVI void stageA32(const u16* __restrict__ src, int K, u16* lds, int tid){
  int r = tid >> 2, c = tid & 3;
  int sc = c ^ ((r >> 1) & 3);
  gload16(src + (size_t)r*K + sc*8, lds + (size_t)tid*8);
}
DEVI void stageB32(const u16* __restrict__ src, int K, u16* lds, int tid){
  #pragma unroll
  for (int j = 0; j < 2; j++){
    int p = j*512 + tid;
    int r = p >> 2, c = p & 3;
    int sc = c ^ ((r >> 1) & 3);
    gload16(src + (size_t)r*K + sc*8, lds + (size_t)p*8);
  }
}

template<int EPI>
__global__ __launch_bounds__(512, 4)
void k_gemm3(const u16* __restrict__ A, const u16* __restrict__ BT,
             const float* __restrict__ bias, void* __restrict__ out,
             int M, int N, int K){
  __shared__ __align__(16) u16 sm[36864];   // 72 KiB
  const int tid = threadIdx.x;
  const int w = tid >> 6, lane = tid & 63;
  const int wm = w >> 2, wn = w & 3;
  const int cr = lane & 15, cg = lane >> 4;

  // bijective XCD-chunked remap (m204)
  const int nbn = gridDim.x;
  const int nwg = nbn * gridDim.y;
  const int d   = blockIdx.y * nbn + blockIdx.x;
  const int xcd = d & 7, qq = nwg >> 3, rr = nwg & 7;
  const int logical = (xcd < rr ? xcd*(qq+1) : rr*(qq+1) + (xcd-rr)*qq) + (d >> 3);
  const int m0 = (logical / nbn) * 128;
  const int n0 = (logical % nbn) * 256;

  const int NT = K >> 5;
  const u16* Abase = A  + (size_t)m0 * K;
  const u16* Bbase = BT + (size_t)n0 * K;
  const int rowA = wm*64 + cr;
  const int rowB = wn*64 + cr;

  f32x4 acc[4][4] = {};
  bf16x8 afr[4], bfr[4];

  stageA32(Abase, K, sm, tid);
  stageB32(Bbase, K, sm + 12288, tid);
  if (NT > 1){
    stageA32(Abase + 32, K, sm + 4096, tid);
    stageB32(Bbase + 32, K, sm + 12288 + 8192, tid);
    asm volatile("s_waitcnt vmcnt(3)" ::: "memory");
  } else {
    asm volatile("s_waitcnt vmcnt(0)" ::: "memory");
  }
  __builtin_amdgcn_sched_barrier(0);
  BAR();

  int bcur = 0;
  for (int t = 0; t < NT; ++t){
    const int ab = bcur << 12;
    const int bb = 12288 + (bcur << 13);
    int bn2 = bcur + 2; if (bn2 >= 3) bn2 -= 3;

    #pragma unroll
    for (int n = 0; n < 4; n++){
      int r = rowB + n*16;
      bfr[n] = *(const bf16x8*)&sm[bb + r*32 + ((cg ^ ((r >> 1) & 3)) << 3)];
    }
    #pragma unroll
    for (int i = 0; i < 4; i++){
      int r = rowA + i*16;
      afr[i] = *(const bf16x8*)&sm[ab + r*32 + ((cg ^ ((r >> 1) & 3)) << 3)];
    }
    if (t + 2 < NT){
      stageA32(Abase + (size_t)(t+2)*32, K, sm + (bn2 << 12), tid);
      stageB32(Bbase + (size_t)(t+2)*32, K, sm + 12288 + (bn2 << 13), tid);
    }

    __builtin_amdgcn_s_setprio(1);
    #pragma unroll
    for (int i = 0; i < 4; i++)
      #pragma unroll
      for (int n = 0; n < 4; n++)
        acc[i][n] = MFMA(afr[i], bfr[n], acc[i][n]);
    __builtin_amdgcn_s_setprio(0);

    if (t + 2 < NT) { asm volatile("s_waitcnt vmcnt(3)" ::: "memory"); }
    else            { asm volatile("s_waitcnt vmcnt(0)" ::: "memory"); }
    __builtin_amdgcn_sched_barrier(0);
    BAR();
    bcur = bcur + 1; if (bcur >= 3) bcur = 0;
  }

  // ---- epilogue
  if (EPI == 1){
    // f32 direct stores: 16 lanes x 4B = full 64B line
    #pragma unroll
    for (int n = 0; n < 4; n++){
      int col = n0 + wn*64 + n*16 + cr;
      float bv = bias[col];
      #pragma unroll
      for (int i = 0; i < 4; i++){
        #pragma unroll
        for (int j = 0; j < 4; j++){
          int row = m0 + wm*64 + i*16 + cg*4 + j;
          ((float*)out)[(size_t)row * N + col] = acc[i][n][j] + bv;
        }
      }
    }
  } else {
    // bf16: stage tile to LDS, re-read contiguous, dwordx4 full-line stores
    const int LDC = 264;          // row stride (u16), 528 B: 16B-aligned, de-conflicted
    #pragma unroll
    for (int n = 0; n < 4; n++){
      int coll = wn*64 + n*16 + cr;
      float bv = bias[n0 + coll];
      #pragma unroll
      for (int i = 0; i < 4; i++){
        #pragma unroll
        for (int j = 0; j < 4; j++){
          int rowl = wm*64 + i*16 + cg*4 + j;
          float v = acc[i][n][j] + bv;
          if (EPI == 2) v = 0.5f * v * (1.f + erff(v * 0.70710678118654752f));
          sm[rowl*LDC + coll] = f2bf(v);
        }
      }
    }
    BAR();
    if (EPI == 3){
      // scatter to head-packed q/k/v: 16B chunks, 128B contiguous per (s,head)
      #pragma unroll
      for (int it = 0; it < 8; it++){
        int idx = it*512 + tid;            // (s:128)(h:4)(c:8)
        int c = idx & 7, hh2 = (idx >> 3) & 3, s = idx >> 5;
        uint4 v4 = *(const uint4*)&sm[s*LDC + hh2*64 + c*8];
        int col0 = n0 + hh2*64;
        int sec = (col0 >= 1536) ? 2 : (col0 >= 768 ? 1 : 0);
        int hd  = (col0 - sec*768) >> 6;
        int row = m0 + s;
        int b = row >> 9, sr = row & 511;
        *(uint4*)((u16*)out + (size_t)sec*25165824 +
                  (((size_t)(b*12 + hd)*512 + sr) << 6) + c*8) = v4;
      }
    } else {
      #pragma unroll
      for (int it = 0; it < 8; it++){
        int idx = it*512 + tid;            // (r:128)(c8:32)
        int r = idx >> 5, c8 = idx & 31;
        uint4 v4 = *(const uint4*)&sm[r*LDC + c8*8];
        *(uint4*)((u16*)out + (size_t)(m0 + r)*N + n0 + c8*8) = v4;
      }
    }
  }
}

// ---------------- V^T repack: vbuf[bh][512][64] -> vt[bh][64][512] ----------------
__global__ void k_vtrep(const u16* __restrict__ vbuf, u16* __restrict__ vt){
  __shared__ u16 tile[64][72];
  int bh = blockIdx.y;               // b*12+h
  int t0 = blockIdx.x * 64;
  int tid = threadIdx.x;
  #pragma unroll
  for (int i = 0; i < 16; i++){
    int idx = tid + i * 256;
    int tt = idx >> 6, d = idx & 63;
    tile[tt][d] = vbuf[((size_t)bh * 512 + t0 + tt) * 64 + d];
  }
  __syncthreads();
  #pragma unroll
  for (int i = 0; i < 16; i++){
    int idx = tid + i * 256;
    int d = idx >> 6, tt = idx & 63;
    vt[((size_t)bh * 64 + d) * 512 + t0 + tt] = tile[tt][d];
  }
}

// ---------------- attention v3: flash/online, swapped QK^T, LDS-staged K & V^T ----------
DEVI void stage64(const u16* __restrict__ src, int stride, u16* lds, int w, int lane){
  #pragma unroll
  for (int j = 0; j < 2; j++){
    int p  = j*256 + w*64 + lane;        // piece 0..511 (16B each)
    int r  = p >> 3;                     // row 0..63
    int c8 = (p & 7) ^ (r & 7);          // inverse-swizzled source chunk
    gload16(src + (size_t)r*stride + c8*8, lds + (size_t)p*8);
  }
}

__global__ __launch_bounds__(256, 4)
void k_attn3(const u16* __restrict__ qp, const u16* __restrict__ kp,
             const u16* __restrict__ vt, const u32* __restrict__ mb,
             u16* __restrict__ ctx){
  __shared__ __align__(16) u16 Ks[8192];   // 2 x [64][64]
  __shared__ __align__(16) u16 Vs[8192];   // 2 x [64 d][64 kv]
  const int tid = threadIdx.x, wv = tid >> 6, lane = tid & 63;
  const int cr = lane & 15, cg = lane >> 4;
  const int cg4 = cg * 4;
  const int r7 = cr & 7;

  const int dd = blockIdx.x + (blockIdx.y << 3);
  const int logical = (dd & 7) * 768 + (dd >> 3);
  const int bh = logical >> 3;
  const int qblk = logical & 7;
  const int b = bh / 12, hh = bh % 12;
  const int qw = qblk * 64 + wv * 16;
  const int qrow = qw + cr;
  const size_t base = (size_t)bh * 512 * 64;
  const u16* vtb = vt + (size_t)bh * 64 * 512;

  const int slot0 = ((cg    ) ^ r7) << 3;
  const int slot1 = ((4 + cg) ^ r7) << 3;

  bf16x8 qB[2];
  #pragma unroll
  for (int ks = 0; ks < 2; ks++)
    qB[ks] = *(const bf16x8*)&qp[base + (size_t)qrow * 64 + ks*32 + cg*8];

  u32 mw[16];
  {
    const u32* mrow = mb + ((size_t)b * 512 + qrow) * 16;
    #pragma unroll
    for (int i = 0; i < 4; i++){
      uint4 v4 = *(const uint4*)&mrow[i*4];
      mw[i*4+0] = v4.x; mw[i*4+1] = v4.y; mw[i*4+2] = v4.z; mw[i*4+3] = v4.w;
    }
  }

  stage64(kp + base, 64, Ks, wv, lane);
  stage64(vtb,      512, Vs, wv, lane);
  asm volatile("s_waitcnt vmcnt(0)" ::: "memory");
  __builtin_amdgcn_sched_barrier(0);
  BAR();

  float m = -3e38f, vs = 0.f;
  f32x4 oacc[4] = {};

  for (int s = 0; s < 8; ++s){
    const int buf = (s & 1) << 12;
    const int nbf = ((s + 1) & 1) << 12;

    if (s + 1 < 8){
      stage64(kp + base + (size_t)(s+1)*4096, 64, Ks + nbf, wv, lane);
      stage64(vtb + (size_t)(s+1)*64,        512, Vs + nbf, wv, lane);
    }

    f32x4 pacc[4];
    #pragma unroll
    for (int tt = 0; tt < 4; tt++){
      bf16x8 a0 = *(const bf16x8*)&Ks[buf + (tt*16 + cr)*64 + slot0];
      bf16x8 a1 = *(const bf16x8*)&Ks[buf + (tt*16 + cr)*64 + slot1];
      f32x4 z = {0.f, 0.f, 0.f, 0.f};
      z = MFMA(a0, qB[0], z);
      z = MFMA(a1, qB[1], z);
      pacc[tt] = z;
    }

    const u32 w0 = mw[2*s], w1 = mw[2*s+1];
    f32x4 vmx = {-3e38f, -3e38f, -3e38f, -3e38f};
    #pragma unroll
    for (int tt = 0; tt < 4; tt++){
      u32 nib = (((tt < 2) ? w0 : w1) >> (16*(tt & 1) + cg4)) & 0xFu;
      #pragma unroll
      for (int j = 0; j < 4; j++){
        float v = pacc[tt][j] * 0.125f + (((nib >> j) & 1u) ? 0.f : -10000.f);
        pacc[tt][j] = v;
        vmx[j] = fmaxf(vmx[j], v);
      }
    }
    float tm = fmaxf(fmaxf(vmx[0], vmx[1]), fmaxf(vmx[2], vmx[3]));
    tm = fmaxf(tm, __shfl_xor(tm, 16, 64));
    tm = fmaxf(tm, __shfl_xor(tm, 32, 64));

    float mnew = fmaxf(m, tm);
    float alpha = __expf(m - mnew);
    m = mnew;
    #pragma unroll
    for (int db = 0; db < 4; db++) oacc[db] *= alpha;

    f32x4 vsum = {0.f, 0.f, 0.f, 0.f};
    #pragma unroll
    for (int tt = 0; tt < 4; tt++){
      #pragma unroll
      for (int j = 0; j < 4; j++){
        float e = __expf(pacc[tt][j] - m);
        pacc[tt][j] = e;
        vsum[j] += e;
      }
    }
    vs = vs * alpha + (vsum[0] + vsum[1] + vsum[2] + vsum[3]);

    bf16x8 pa[2];
    #pragma unroll
    for (int c = 0; c < 2; c++)
      #pragma unroll
      for (int e = 0; e < 4; e++){
        pa[c][e]   = (__bf16)pacc[2*c][e];
        pa[c][4+e] = (__bf16)pacc[2*c+1][e];
      }

    #pragma unroll
    for (int c = 0; c < 2; c++){
      const int ch0 = ((4*c     + (cg >> 1)) ^ r7);
      const int ch1 = ((4*c + 2 + (cg >> 1)) ^ r7);
      const int sub = (cg & 1) << 3;
      #pragma unroll
      for (int db = 0; db < 4; db++){
        const char* vrow = (const char*)&Vs[buf + (db*16 + cr)*64];
        bf16x8 vb;
        ((uint2*)&vb)[0] = *(const uint2*)(vrow + (ch0 << 4) + sub);
        ((uint2*)&vb)[1] = *(const uint2*)(vrow + (ch1 << 4) + sub);
        oacc[db] = MFMA(pa[c], vb, oacc[db]);
      }
    }

    if (s + 1 < 8) { asm volatile("s_waitcnt vmcnt(0)" ::: "memory"); }
    __builtin_amdgcn_sched_barrier(0);
    BAR();
  }

  vs += __shfl_xor(vs, 16, 64);
  vs += __shfl_xor(vs, 32, 64);
  #pragma unroll
  for (int j = 0; j < 4; j++){
    float ds = __shfl(vs, cg4 + j, 64);
    float inv = 1.0f / ds;
    #pragma unroll
    for (int db = 0; db < 4; db++)
      ctx[((size_t)b * 512 + qw + cg4 + j) * 768 + hh*64 + 16*db + cr] = f2bf(oacc[db][j] * inv);
  }
}

// ---------------- head: K-split dense+tanh (grid = 12 col-chunks x 64 batches) ---------
__global__ __launch_bounds__(256)
void k_dense(const u16* __restrict__ hb, const float* __restrict__ W,
             const float* __restrict__ bias, float* __restrict__ xt){
  __shared__ float xs[768];
  __shared__ float red[256];
  const int b = blockIdx.y, t = threadIdx.x;
  const u16* hr = hb + (size_t)b * 512 * 768;   // row 0 of batch b
  xs[t] = bf2f(hr[t]); xs[t+256] = bf2f(hr[t+256]); xs[t+512] = bf2f(hr[t+512]);
  __syncthreads();
  const int col = blockIdx.x * 64 + (t & 63);
  const int ks  = t >> 6;                        // 0..3, k-slice of 192
  const float* Wp = W + (size_t)(ks * 192) * 768 + col;
  const float* xp = xs + ks * 192;
  float a = 0.f;
  #pragma unroll 8
  for (int k = 0; k < 192; k++) a += xp[k] * Wp[(size_t)k * 768];
  red[t] = a;
  __syncthreads();
  if (t < 64){
    float y = red[t] + red[t+64] + red[t+128] + red[t+192] + bias[col];
    xt[(size_t)b * 768 + col] = tanhf(y);
  }
}

__global__ void k_logits(const float* __restrict__ xt, const float* __restrict__ ow,
                         const float* __restrict__ ob, float* __restrict__ out){
  __shared__ float sb[4];
  int b = blockIdx.x, t = threadIdx.x;
  const float* x = xt + (size_t)b * 768;
  float s = x[t]*ow[t] + x[t+256]*ow[t+256] + x[t+512]*ow[t+512];
  for (int o = 32; o; o >>= 1) s += __shfl_down(s, o, 64);
  int wv = t >> 6, ln = t & 63;
  if (!ln) sb[wv] = s;
  __syncthreads();
  if (t == 0) out[b] = sb[0] + sb[1] + sb[2] + sb[3] + ob[0];
}

// ---------------- launch ----------------
extern "C" void kernel_launch(void* const* d_in, const int* in_sizes, int n_in,
                              void* d_out, int out_size, void* d_ws, size_t ws_size,
                              hipStream_t stream){
  if (n_in < 23) return;
  if (ws_size < 534000000ull) return;

  const int*   ids  = (const int*)  d_in[0];
  const int*   pos  = (const int*)  d_in[1];
  const void*  amsk =               d_in[2];
  const float* wemb = (const float*)d_in[3];
  const float* pemb = (const float*)d_in[4];
  const float* lng  = (const float*)d_in[5];
  const float* lnb  = (const float*)d_in[6];
  const float* Wqkv = (const float*)d_in[7];
  const float* bqkv = (const float*)d_in[8];
  const float* Wo   = (const float*)d_in[9];
  const float* bo   = (const float*)d_in[10];
  const float* ln1g = (const float*)d_in[11];
  const float* ln1b = (const float*)d_in[12];
  const float* W1   = (const float*)d_in[13];
  const float* b1   = (const float*)d_in[14];
  const float* W2   = (const float*)d_in[15];
  const float* b2   = (const float*)d_in[16];
  const float* ln2g = (const float*)d_in[17];
  const float* ln2b = (const float*)d_in[18];
  const float* dW   = (const float*)d_in[19];
  const float* db   = (const float*)d_in[20];
  const float* oW   = (const float*)d_in[21];
  const float* ob   = (const float*)d_in[22];

  char* ws = (char*)d_ws;
  float* h    = (float*)(ws);
  u16*   hb   = (u16*)  (ws + 100663296);
  float* C    = (float*)(ws + 150994944);
  u16*   qkvp = (u16*)  (ws + 251658240);   // qp | kp | vbuf, each 50331648 B
  u16*   vt   = (u16*)  (ws + 402653184);
  u16*   act  = (u16*)  (ws + 251658240);   // aliases qkvp+vt (disjoint lifetime)
  u16*   ctx  = (u16*)  (ws + 452984832);
  u32*   mbit = (u32*)  (ws + 503316480);
  u16*   wt   = (u16*)  (ws + 505413632);
  float* xt   = (float*)(ws + 533725184);
  int*   flag = (int*)  (ws + 533921792);

  u16* qp   = qkvp;
  u16* kp   = qkvp + (size_t)25165824;
  u16* vbuf = qkvp + (size_t)50331648;

  u16* WqkvT = wt;                                  // [l][2304][768]
  u16* WoT   = WqkvT + (size_t)2*2304*768;          // [l][768][768]
  u16* W1T   = WoT   + (size_t)2*768*768;           // [l][3072][768]
  u16* W2T   = W1T   + (size_t)2*3072*768;          // [l][768][3072]

  k_maskprobe<<<1, 256, 0, stream>>>((const unsigned char*)amsk, flag);
  k_maskbits<<<8192, 256, 0, stream>>>(amsk, flag, mbit);

  for (int l = 0; l < 2; l++){
    k_transpose<<<dim3(24, 72), 256, 0, stream>>>(Wqkv + (size_t)l*768*2304, WqkvT + (size_t)l*2304*768, 768, 2304);
    k_transpose<<<dim3(24, 24), 256, 0, stream>>>(Wo   + (size_t)l*768*768,  WoT   + (size_t)l*768*768,  768, 768);
    k_transpose<<<dim3(24, 96), 256, 0, stream>>>(W1   + (size_t)l*768*3072, W1T   + (size_t)l*3072*768, 768, 3072);
    k_transpose<<<dim3(96, 24), 256, 0, stream>>>(W2   + (size_t)l*3072*768, W2T   + (size_t)l*768*3072, 3072, 768);
  }

  k_embed<<<32768, 256, 0, stream>>>(ids, wemb, h);
  k_nodeavg<<<dim3(32768, 3), 256, 0, stream>>>(pos, mbit, h);
  k_ln0<<<32768, 256, 0, stream>>>(pos, pemb, lng, lnb, h, hb);

  for (int l = 0; l < 2; l++){
    k_gemm3<3><<<dim3(9, 256), 512, 0, stream>>>(hb, WqkvT + (size_t)l*2304*768, bqkv + l*2304, (void*)qkvp, 32768, 2304, 768);
    k_vtrep<<<dim3(8, 768), 256, 0, stream>>>(vbuf, vt);
    k_attn3<<<dim3(8, 768), 256, 0, stream>>>(qp, kp, vt, mbit, ctx);
    k_gemm3<1><<<dim3(3, 256), 512, 0, stream>>>(ctx, WoT + (size_t)l*768*768, bo + l*768, (void*)C, 32768, 768, 768);
    k_lnres<<<32768, 256, 0, stream>>>(C, ln1g + l*768, ln1b + l*768, hb);
    k_gemm3<2><<<dim3(12, 256), 512, 0, stream>>>(hb, W1T + (size_t)l*3072*768, b1 + l*3072, (void*)act, 32768, 3072, 768);
    k_gemm3<1><<<dim3(3, 256), 512, 0, stream>>>(act, W2T + (size_t)l*768*3072, b2 + l*768, (void*)C, 32768, 768, 3072);
    k_lnres<<<32768, 256, 0, stream>>>(C, ln2g + l*768, ln2b + l*768, hb);
  }

  k_dense<<<dim3(12, 64), 256, 0, stream>>>(hb, dW, db, xt);
  k_logits<<<64, 256, 0, stream>>>(xt, oW, ob, (float*)d_out);
}

// Round 12
// 1757.005 us; speedup vs baseline: 1.9173x; 1.0747x over previous
//
#include <hip/hip_runtime.h>

typedef unsigned short u16;
typedef unsigned int   u32;
typedef __bf16 bf16x8 __attribute__((ext_vector_type(8)));
typedef float  f32x4  __attribute__((ext_vector_type(4)));

#define DEVI __device__ __forceinline__

DEVI u16 f2bf(float f){
  u32 u = __builtin_bit_cast(u32, f);
  u32 r = (u + 0x7fffu + ((u >> 16) & 1u)) >> 16;   // RNE
  return (u16)r;
}
DEVI float bf2f(u16 u){
  u32 x = ((u32)u) << 16;
  return __builtin_bit_cast(float, x);
}

DEVI void gload16(const void* g, void* lds){
  __builtin_amdgcn_global_load_lds(
      (const __attribute__((address_space(1))) void*)g,
      (__attribute__((address_space(3))) void*)lds, 16, 0, 0);
}

DEVI f32x4 MFMA(bf16x8 a, bf16x8 b, f32x4 c){
  return __builtin_amdgcn_mfma_f32_16x16x32_bf16(a, b, c, 0, 0, 0);
}

#define BAR() do { asm volatile("s_barrier" ::: "memory"); \
                   __builtin_amdgcn_sched_barrier(0); } while(0)

// ---------------- mask dtype probe: 1 => uint8 bytes, 0 => int32 ----------------
__global__ void k_maskprobe(const unsigned char* __restrict__ m, int* __restrict__ flag){
  __shared__ int s;
  if (threadIdx.x == 0) s = 0;
  __syncthreads();
  int acc = 0;
  for (int i = threadIdx.x; i < 65536; i += 256)
    if ((i & 3) != 0 && m[i] != 0) acc++;
  atomicAdd(&s, acc);
  __syncthreads();
  if (threadIdx.x == 0) *flag = (s > 0) ? 1 : 0;
}

// ---------------- pack attn_mask to bitmask [B*S][16 words] ----------------
__global__ void k_maskbits(const void* __restrict__ mask, const int* __restrict__ flag,
                           u32* __restrict__ mb){
  int row  = blockIdx.x * 4 + (threadIdx.x >> 6);   // b*512+q
  int lane = threadIdx.x & 63;
  bool bytes = (*flag != 0);
  for (int c0 = 0; c0 < 512; c0 += 64){
    int v;
    if (bytes) v = ((const unsigned char*)mask)[(size_t)row * 512 + c0 + lane];
    else       v = ((const int*)mask)[(size_t)row * 512 + c0 + lane];
    unsigned long long bits = __ballot(v != 0);
    if (lane == 0){
      mb[(size_t)row * 16 + (c0 >> 5)]     = (u32)(bits & 0xffffffffull);
      mb[(size_t)row * 16 + (c0 >> 5) + 1] = (u32)(bits >> 32);
    }
  }
}

// ---------------- fused embed + node-average + LN0 -> bf16 hb ----------------
__global__ void k_embln(const int* __restrict__ ids, const int* __restrict__ pos,
                        const u32* __restrict__ mb, const float* __restrict__ wemb,
                        const float* __restrict__ pemb, const float* __restrict__ g,
                        const float* __restrict__ be, u16* __restrict__ hb){
  __shared__ float s1[4], s2[4];
  int row = blockIdx.x, t = threadIdx.x;
  int p = pos[row];
  float x0, x1, x2;
  if (p == 0){
    int b = row >> 9;
    const u32* mrow = mb + (size_t)row * 16;
    const int* pb = pos + ((size_t)b << 9);
    const int* ib = ids + ((size_t)b << 9);
    float a0 = 0.f, a1 = 0.f, a2 = 0.f, cnt = 0.f;
    #pragma unroll 8
    for (int k = 0; k < 512; k++){
      float w = (pb[k] >= 2 && ((mrow[k >> 5] >> (k & 31)) & 1)) ? 1.f : 0.f;
      const float* src = wemb + (size_t)ib[k] * 768;
      a0 += w * src[t]; a1 += w * src[t+256]; a2 += w * src[t+512];
      cnt += w;
    }
    float inv = 1.f / (cnt + 1e-10f);
    x0 = a0 * inv; x1 = a1 * inv; x2 = a2 * inv;
  } else {
    const float* src = wemb + (size_t)ids[row] * 768;
    x0 = src[t]; x1 = src[t+256]; x2 = src[t+512];
  }
  const float* pr = pemb + (size_t)p * 768;
  x0 += pr[t]; x1 += pr[t+256]; x2 += pr[t+512];
  float s = x0 + x1 + x2, q = x0*x0 + x1*x1 + x2*x2;
  for (int o = 32; o; o >>= 1){ s += __shfl_down(s, o, 64); q += __shfl_down(q, o, 64); }
  int wv = t >> 6, ln = t & 63;
  if (!ln){ s1[wv] = s; s2[wv] = q; }
  __syncthreads();
  s = s1[0]+s1[1]+s1[2]+s1[3]; q = s2[0]+s2[1]+s2[2]+s2[3];
  float mu = s * (1.f/768.f);
  float rs = rsqrtf(q * (1.f/768.f) - mu*mu + 1e-5f);
  u16* hbr = hb + (size_t)row * 768;
  hbr[t]     = f2bf((x0-mu)*rs*g[t]     + be[t]);
  hbr[t+256] = f2bf((x1-mu)*rs*g[t+256] + be[t+256]);
  hbr[t+512] = f2bf((x2-mu)*rs*g[t+512] + be[t+512]);
}

// lnres: hb (bf16, in-place) + C (f32) -> LN -> hb
__global__ void k_lnres(const float* __restrict__ C, const float* __restrict__ g,
                        const float* __restrict__ be, u16* __restrict__ hb){
  __shared__ float s1[4], s2[4];
  int row = blockIdx.x, t = threadIdx.x;
  u16* hr = hb + (size_t)row * 768;
  const float* cr = C + (size_t)row * 768;
  float x0 = bf2f(hr[t])     + cr[t];
  float x1 = bf2f(hr[t+256]) + cr[t+256];
  float x2 = bf2f(hr[t+512]) + cr[t+512];
  float s = x0 + x1 + x2, q = x0*x0 + x1*x1 + x2*x2;
  for (int o = 32; o; o >>= 1){ s += __shfl_down(s, o, 64); q += __shfl_down(q, o, 64); }
  int wv = t >> 6, ln = t & 63;
  if (!ln){ s1[wv] = s; s2[wv] = q; }
  __syncthreads();
  s = s1[0]+s1[1]+s1[2]+s1[3]; q = s2[0]+s2[1]+s2[2]+s2[3];
  float mu = s * (1.f/768.f);
  float rs = rsqrtf(q * (1.f/768.f) - mu*mu + 1e-5f);
  hr[t]     = f2bf((x0-mu)*rs*g[t]     + be[t]);
  hr[t+256] = f2bf((x1-mu)*rs*g[t+256] + be[t+256]);
  hr[t+512] = f2bf((x2-mu)*rs*g[t+512] + be[t+512]);
}

// ---------------- weight transpose+cast: src[K][N] f32 -> dst[N][K] bf16 ----------------
__global__ void k_transpose(const float* __restrict__ src, u16* __restrict__ dst,
                            int K, int N){
  __shared__ float tile[32][33];
  int k0 = blockIdx.x * 32, n0 = blockIdx.y * 32;
  int tx = threadIdx.x & 31, ty = threadIdx.x >> 5;   // ty 0..7
  #pragma unroll
  for (int i = 0; i < 32; i += 8)
    tile[ty + i][tx] = src[(size_t)(k0 + ty + i) * N + n0 + tx];
  __syncthreads();
  #pragma unroll
  for (int i = 0; i < 32; i += 8)
    dst[(size_t)(n0 + ty + i) * K + k0 + tx] = f2bf(tile[tx][ty + i]);
}

// ========== 128x256 BK=32 GEMM, prefetch-distance-2, LDS-staged bf16 epilogue ==========
// EPI 0: bf16+bias; 1: f32+bias; 2: bf16+bias+GELU;
// EPI 3: qkv -> head-packed q/k (n0<1536) or DIRECT transposed V write to vt (n0>=1536).

DEVI void stageA32(const u16* __restrict__ src, int K, u16* lds, int tid){
  int r = tid >> 2, c = tid & 3;
  int sc = c ^ ((r >> 1) & 3);
  gload16(src + (size_t)r*K + sc*8, lds + (size_t)tid*8);
}
DEVI void stageB32(const u16* __restrict__ src, int K, u16* lds, int tid){
  #pragma unroll
  for (int j = 0; j < 2; j++){
    int p = j*512 + tid;
    int r = p >> 2, c = p & 3;
    int sc = c ^ ((r >> 1) & 3);
    gload16(src + (size_t)r*K + sc*8, lds + (size_t)p*8);
  }
}

template<int EPI>
__global__ __launch_bounds__(512, 4)
void k_gemm3(const u16* __restrict__ A, const u16* __restrict__ BT,
             const float* __restrict__ bias, void* __restrict__ out,
             void* __restrict__ out2, int M, int N, int K){
  __shared__ __align__(16) u16 sm[36864];   // 72 KiB
  const int tid = threadIdx.x;
  const int w = tid >> 6, lane = tid & 63;
  const int wm = w >> 2, wn = w & 3;
  const int cr = lane & 15, cg = lane >> 4;

  // bijective XCD-chunked remap (m204)
  const int nbn = gridDim.x;
  const int nwg = nbn * gridDim.y;
  const int d   = blockIdx.y * nbn + blockIdx.x;
  const int xcd = d & 7, qq = nwg >> 3, rr = nwg & 7;
  const int logical = (xcd < rr ? xcd*(qq+1) : rr*(qq+1) + (xcd-rr)*qq) + (d >> 3);
  const int m0 = (logical / nbn) * 128;
  const int n0 = (logical % nbn) * 256;

  const int NT = K >> 5;
  const u16* Abase = A  + (size_t)m0 * K;
  const u16* Bbase = BT + (size_t)n0 * K;
  const int rowA = wm*64 + cr;
  const int rowB = wn*64 + cr;

  f32x4 acc[4][4] = {};
  bf16x8 afr[4], bfr[4];

  stageA32(Abase, K, sm, tid);
  stageB32(Bbase, K, sm + 12288, tid);
  if (NT > 1){
    stageA32(Abase + 32, K, sm + 4096, tid);
    stageB32(Bbase + 32, K, sm + 12288 + 8192, tid);
    asm volatile("s_waitcnt vmcnt(3)" ::: "memory");
  } else {
    asm volatile("s_waitcnt vmcnt(0)" ::: "memory");
  }
  __builtin_amdgcn_sched_barrier(0);
  BAR();

  int bcur = 0;
  for (int t = 0; t < NT; ++t){
    const int ab = bcur << 12;
    const int bb = 12288 + (bcur << 13);
    int bn2 = bcur + 2; if (bn2 >= 3) bn2 -= 3;

    #pragma unroll
    for (int n = 0; n < 4; n++){
      int r = rowB + n*16;
      bfr[n] = *(const bf16x8*)&sm[bb + r*32 + ((cg ^ ((r >> 1) & 3)) << 3)];
    }
    #pragma unroll
    for (int i = 0; i < 4; i++){
      int r = rowA + i*16;
      afr[i] = *(const bf16x8*)&sm[ab + r*32 + ((cg ^ ((r >> 1) & 3)) << 3)];
    }
    if (t + 2 < NT){
      stageA32(Abase + (size_t)(t+2)*32, K, sm + (bn2 << 12), tid);
      stageB32(Bbase + (size_t)(t+2)*32, K, sm + 12288 + (bn2 << 13), tid);
    }

    __builtin_amdgcn_s_setprio(1);
    #pragma unroll
    for (int i = 0; i < 4; i++)
      #pragma unroll
      for (int n = 0; n < 4; n++)
        acc[i][n] = MFMA(afr[i], bfr[n], acc[i][n]);
    __builtin_amdgcn_s_setprio(0);

    if (t + 2 < NT) { asm volatile("s_waitcnt vmcnt(3)" ::: "memory"); }
    else            { asm volatile("s_waitcnt vmcnt(0)" ::: "memory"); }
    __builtin_amdgcn_sched_barrier(0);
    BAR();
    bcur = bcur + 1; if (bcur >= 3) bcur = 0;
  }

  // ---- epilogue
  if (EPI == 1){
    #pragma unroll
    for (int n = 0; n < 4; n++){
      int col = n0 + wn*64 + n*16 + cr;
      float bv = bias[col];
      #pragma unroll
      for (int i = 0; i < 4; i++){
        #pragma unroll
        for (int j = 0; j < 4; j++){
          int row = m0 + wm*64 + i*16 + cg*4 + j;
          ((float*)out)[(size_t)row * N + col] = acc[i][n][j] + bv;
        }
      }
    }
  } else {
    const bool vblk = (EPI == 3) && (n0 >= 1536);
    const int LDC = vblk ? 266 : 264;
    #pragma unroll
    for (int n = 0; n < 4; n++){
      int coll = wn*64 + n*16 + cr;
      float bv = bias[n0 + coll];
      #pragma unroll
      for (int i = 0; i < 4; i++){
        #pragma unroll
        for (int j = 0; j < 4; j++){
          int rowl = wm*64 + i*16 + cg*4 + j;
          float v = acc[i][n][j] + bv;
          if (EPI == 2) v = 0.5f * v * (1.f + erff(v * 0.70710678118654752f));
          sm[rowl*LDC + coll] = f2bf(v);
        }
      }
    }
    BAR();
    if (EPI == 3){
      int b = m0 >> 9, s0 = m0 & 511;
      if (vblk){
        // direct transposed V write: vt[b*12+hd][d][s0..s0+127]
        int hd0 = (n0 - 1536) >> 6;
        int dl = lane >> 2, sc4 = lane & 3;
        #pragma unroll
        for (int it = 0; it < 8; it++){
          int gidx = it*8 + w;                 // 0..63
          int hh2 = gidx >> 4, dhi = (gidx >> 2) & 3, shi = gidx & 3;
          int dd2 = dhi*16 + dl;
          int schunk = shi*4 + sc4;
          u16 tmp[8];
          #pragma unroll
          for (int k = 0; k < 8; k++)
            tmp[k] = sm[(schunk*8 + k)*266 + hh2*64 + dd2];
          *(uint4*)((u16*)out2 + (((size_t)(b*12 + hd0 + hh2)*64 + dd2) << 9)
                    + s0 + schunk*8) = *(uint4*)tmp;
        }
      } else {
        // head-packed q/k scatter: 16B chunks, 128B contiguous per (s,head)
        #pragma unroll
        for (int it = 0; it < 8; it++){
          int idx = it*512 + tid;            // (s:128)(h:4)(c:8)
          int c = idx & 7, hh2 = (idx >> 3) & 3, s = idx >> 5;
          uint4 v4 = *(const uint4*)&sm[s*264 + hh2*64 + c*8];
          int col0 = n0 + hh2*64;
          int sec = (col0 >= 768) ? 1 : 0;
          int hd  = (col0 - sec*768) >> 6;
          *(uint4*)((u16*)out + (size_t)sec*25165824 +
                    (((size_t)(b*12 + hd)*512 + (m0 & 511) + s) << 6) + c*8) = v4;
        }
      }
    } else {
      #pragma unroll
      for (int it = 0; it < 8; it++){
        int idx = it*512 + tid;            // (r:128)(c8:32)
        int r = idx >> 5, c8 = idx & 31;
        uint4 v4 = *(const uint4*)&sm[r*264 + c8*8];
        *(uint4*)((u16*)out + (size_t)(m0 + r)*N + n0 + c8*8) = v4;
      }
    }
  }
}

// ---------------- attention v3: flash/online, swapped QK^T, LDS-staged K & V^T ----------
DEVI void stage64(const u16* __restrict__ src, int stride, u16* lds, int w, int lane){
  #pragma unroll
  for (int j = 0; j < 2; j++){
    int p  = j*256 + w*64 + lane;        // piece 0..511 (16B each)
    int r  = p >> 3;                     // row 0..63
    int c8 = (p & 7) ^ (r & 7);          // inverse-swizzled source chunk
    gload16(src + (size_t)r*stride + c8*8, lds + (size_t)p*8);
  }
}

__global__ __launch_bounds__(256, 4)
void k_attn3(const u16* __restrict__ qp, const u16* __restrict__ kp,
             const u16* __restrict__ vt, const u32* __restrict__ mb,
             u16* __restrict__ ctx){
  __shared__ __align__(16) u16 Ks[8192];   // 2 x [64][64]
  __shared__ __align__(16) u16 Vs[8192];   // 2 x [64 d][64 kv]
  const int tid = threadIdx.x, wv = tid >> 6, lane = tid & 63;
  const int cr = lane & 15, cg = lane >> 4;
  const int cg4 = cg * 4;
  const int r7 = cr & 7;

  const int dd = blockIdx.x + (blockIdx.y << 3);
  const int logical = (dd & 7) * 768 + (dd >> 3);
  const int bh = logical >> 3;
  const int qblk = logical & 7;
  const int b = bh / 12, hh = bh % 12;
  const int qw = qblk * 64 + wv * 16;
  const int qrow = qw + cr;
  const size_t base = (size_t)bh * 512 * 64;
  const u16* vtb = vt + (size_t)bh * 64 * 512;

  const int slot0 = ((cg    ) ^ r7) << 3;
  const int slot1 = ((4 + cg) ^ r7) << 3;

  bf16x8 qB[2];
  #pragma unroll
  for (int ks = 0; ks < 2; ks++)
    qB[ks] = *(const bf16x8*)&qp[base + (size_t)qrow * 64 + ks*32 + cg*8];

  u32 mw[16];
  {
    const u32* mrow = mb + ((size_t)b * 512 + qrow) * 16;
    #pragma unroll
    for (int i = 0; i < 4; i++){
      uint4 v4 = *(const uint4*)&mrow[i*4];
      mw[i*4+0] = v4.x; mw[i*4+1] = v4.y; mw[i*4+2] = v4.z; mw[i*4+3] = v4.w;
    }
  }

  stage64(kp + base, 64, Ks, wv, lane);
  stage64(vtb,      512, Vs, wv, lane);
  asm volatile("s_waitcnt vmcnt(0)" ::: "memory");
  __builtin_amdgcn_sched_barrier(0);
  BAR();

  float m = -3e38f, vs = 0.f;
  f32x4 oacc[4] = {};

  for (int s = 0; s < 8; ++s){
    const int buf = (s & 1) << 12;
    const int nbf = ((s + 1) & 1) << 12;

    if (s + 1 < 8){
      stage64(kp + base + (size_t)(s+1)*4096, 64, Ks + nbf, wv, lane);
      stage64(vtb + (size_t)(s+1)*64,        512, Vs + nbf, wv, lane);
    }

    f32x4 pacc[4];
    #pragma unroll
    for (int tt = 0; tt < 4; tt++){
      bf16x8 a0 = *(const bf16x8*)&Ks[buf + (tt*16 + cr)*64 + slot0];
      bf16x8 a1 = *(const bf16x8*)&Ks[buf + (tt*16 + cr)*64 + slot1];
      f32x4 z = {0.f, 0.f, 0.f, 0.f};
      z = MFMA(a0, qB[0], z);
      z = MFMA(a1, qB[1], z);
      pacc[tt] = z;
    }

    const u32 w0 = mw[2*s], w1 = mw[2*s+1];
    f32x4 vmx = {-3e38f, -3e38f, -3e38f, -3e38f};
    #pragma unroll
    for (int tt = 0; tt < 4; tt++){
      u32 nib = (((tt < 2) ? w0 : w1) >> (16*(tt & 1) + cg4)) & 0xFu;
      #pragma unroll
      for (int j = 0; j < 4; j++){
        float v = pacc[tt][j] * 0.125f + (((nib >> j) & 1u) ? 0.f : -10000.f);
        pacc[tt][j] = v;
        vmx[j] = fmaxf(vmx[j], v);
      }
    }
    float tm = fmaxf(fmaxf(vmx[0], vmx[1]), fmaxf(vmx[2], vmx[3]));
    tm = fmaxf(tm, __shfl_xor(tm, 16, 64));
    tm = fmaxf(tm, __shfl_xor(tm, 32, 64));

    float mnew = fmaxf(m, tm);
    float alpha = __expf(m - mnew);
    m = mnew;
    #pragma unroll
    for (int db = 0; db < 4; db++) oacc[db] *= alpha;

    f32x4 vsum = {0.f, 0.f, 0.f, 0.f};
    #pragma unroll
    for (int tt = 0; tt < 4; tt++){
      #pragma unroll
      for (int j = 0; j < 4; j++){
        float e = __expf(pacc[tt][j] - m);
        pacc[tt][j] = e;
        vsum[j] += e;
      }
    }
    vs = vs * alpha + (vsum[0] + vsum[1] + vsum[2] + vsum[3]);

    bf16x8 pa[2];
    #pragma unroll
    for (int c = 0; c < 2; c++)
      #pragma unroll
      for (int e = 0; e < 4; e++){
        pa[c][e]   = (__bf16)pacc[2*c][e];
        pa[c][4+e] = (__bf16)pacc[2*c+1][e];
      }

    #pragma unroll
    for (int c = 0; c < 2; c++){
      const int ch0 = ((4*c     + (cg >> 1)) ^ r7);
      const int ch1 = ((4*c + 2 + (cg >> 1)) ^ r7);
      const int sub = (cg & 1) << 3;
      #pragma unroll
      for (int db = 0; db < 4; db++){
        const char* vrow = (const char*)&Vs[buf + (db*16 + cr)*64];
        bf16x8 vb;
        ((uint2*)&vb)[0] = *(const uint2*)(vrow + (ch0 << 4) + sub);
        ((uint2*)&vb)[1] = *(const uint2*)(vrow + (ch1 << 4) + sub);
        oacc[db] = MFMA(pa[c], vb, oacc[db]);
      }
    }

    if (s + 1 < 8) { asm volatile("s_waitcnt vmcnt(0)" ::: "memory"); }
    __builtin_amdgcn_sched_barrier(0);
    BAR();
  }

  vs += __shfl_xor(vs, 16, 64);
  vs += __shfl_xor(vs, 32, 64);
  #pragma unroll
  for (int j = 0; j < 4; j++){
    float ds = __shfl(vs, cg4 + j, 64);
    float inv = 1.0f / ds;
    #pragma unroll
    for (int db = 0; db < 4; db++)
      ctx[((size_t)b * 512 + qw + cg4 + j) * 768 + hh*64 + 16*db + cr] = f2bf(oacc[db][j] * inv);
  }
}

// ---------------- head: K-split dense+tanh (grid = 12 col-chunks x 64 batches) ---------
__global__ __launch_bounds__(256)
void k_dense(const u16* __restrict__ hb, const float* __restrict__ W,
             const float* __restrict__ bias, float* __restrict__ xt){
  __shared__ float xs[768];
  __shared__ float red[256];
  const int b = blockIdx.y, t = threadIdx.x;
  const u16* hr = hb + (size_t)b * 512 * 768;   // row 0 of batch b
  xs[t] = bf2f(hr[t]); xs[t+256] = bf2f(hr[t+256]); xs[t+512] = bf2f(hr[t+512]);
  __syncthreads();
  const int col = blockIdx.x * 64 + (t & 63);
  const int ks  = t >> 6;                        // 0..3, k-slice of 192
  const float* Wp = W + (size_t)(ks * 192) * 768 + col;
  const float* xp = xs + ks * 192;
  float a = 0.f;
  #pragma unroll 8
  for (int k = 0; k < 192; k++) a += xp[k] * Wp[(size_t)k * 768];
  red[t] = a;
  __syncthreads();
  if (t < 64){
    float y = red[t] + red[t+64] + red[t+128] + red[t+192] + bias[col];
    xt[(size_t)b * 768 + col] = tanhf(y);
  }
}

__global__ void k_logits(const float* __restrict__ xt, const float* __restrict__ ow,
                         const float* __restrict__ ob, float* __restrict__ out){
  __shared__ float sb[4];
  int b = blockIdx.x, t = threadIdx.x;
  const float* x = xt + (size_t)b * 768;
  float s = x[t]*ow[t] + x[t+256]*ow[t+256] + x[t+512]*ow[t+512];
  for (int o = 32; o; o >>= 1) s += __shfl_down(s, o, 64);
  int wv = t >> 6, ln = t & 63;
  if (!ln) sb[wv] = s;
  __syncthreads();
  if (t == 0) out[b] = sb[0] + sb[1] + sb[2] + sb[3] + ob[0];
}

// ---------------- launch ----------------
extern "C" void kernel_launch(void* const* d_in, const int* in_sizes, int n_in,
                              void* d_out, int out_size, void* d_ws, size_t ws_size,
                              hipStream_t stream){
  if (n_in < 23) return;
  if (ws_size < 534000000ull) return;

  const int*   ids  = (const int*)  d_in[0];
  const int*   pos  = (const int*)  d_in[1];
  const void*  amsk =               d_in[2];
  const float* wemb = (const float*)d_in[3];
  const float* pemb = (const float*)d_in[4];
  const float* lng  = (const float*)d_in[5];
  const float* lnb  = (const float*)d_in[6];
  const float* Wqkv = (const float*)d_in[7];
  const float* bqkv = (const float*)d_in[8];
  const float* Wo   = (const float*)d_in[9];
  const float* bo   = (const float*)d_in[10];
  const float* ln1g = (const float*)d_in[11];
  const float* ln1b = (const float*)d_in[12];
  const float* W1   = (const float*)d_in[13];
  const float* b1   = (const float*)d_in[14];
  const float* W2   = (const float*)d_in[15];
  const float* b2   = (const float*)d_in[16];
  const float* ln2g = (const float*)d_in[17];
  const float* ln2b = (const float*)d_in[18];
  const float* dW   = (const float*)d_in[19];
  const float* db   = (const float*)d_in[20];
  const float* oW   = (const float*)d_in[21];
  const float* ob   = (const float*)d_in[22];

  char* ws = (char*)d_ws;
  u16*   hb   = (u16*)  (ws + 100663296);
  float* C    = (float*)(ws + 150994944);
  u16*   qkvp = (u16*)  (ws + 251658240);   // qp | kp (head-packed)
  u16*   vt   = (u16*)  (ws + 402653184);   // [bh][64][512]
  u16*   act  = (u16*)  (ws + 251658240);   // aliases qkvp+vt (disjoint lifetime)
  u16*   ctx  = (u16*)  (ws + 452984832);
  u32*   mbit = (u32*)  (ws + 503316480);
  u16*   wt   = (u16*)  (ws + 505413632);
  float* xt   = (float*)(ws + 533725184);
  int*   flag = (int*)  (ws + 533921792);

  u16* qp   = qkvp;
  u16* kp   = qkvp + (size_t)25165824;

  u16* WqkvT = wt;                                  // [l][2304][768]
  u16* WoT   = WqkvT + (size_t)2*2304*768;          // [l][768][768]
  u16* W1T   = WoT   + (size_t)2*768*768;           // [l][3072][768]
  u16* W2T   = W1T   + (size_t)2*3072*768;          // [l][768][3072]

  k_maskprobe<<<1, 256, 0, stream>>>((const unsigned char*)amsk, flag);
  k_maskbits<<<8192, 256, 0, stream>>>(amsk, flag, mbit);

  for (int l = 0; l < 2; l++){
    k_transpose<<<dim3(24, 72), 256, 0, stream>>>(Wqkv + (size_t)l*768*2304, WqkvT + (size_t)l*2304*768, 768, 2304);
    k_transpose<<<dim3(24, 24), 256, 0, stream>>>(Wo   + (size_t)l*768*768,  WoT   + (size_t)l*768*768,  768, 768);
    k_transpose<<<dim3(24, 96), 256, 0, stream>>>(W1   + (size_t)l*768*3072, W1T   + (size_t)l*3072*768, 768, 3072);
    k_transpose<<<dim3(96, 24), 256, 0, stream>>>(W2   + (size_t)l*3072*768, W2T   + (size_t)l*768*3072, 3072, 768);
  }

  k_embln<<<32768, 256, 0, stream>>>(ids, pos, mbit, wemb, pemb, lng, lnb, hb);

  for (int l = 0; l < 2; l++){
    k_gemm3<3><<<dim3(9, 256), 512, 0, stream>>>(hb, WqkvT + (size_t)l*2304*768, bqkv + l*2304, (void*)qkvp, (void*)vt, 32768, 2304, 768);
    k_attn3<<<dim3(8, 768), 256, 0, stream>>>(qp, kp, vt, mbit, ctx);
    k_gemm3<1><<<dim3(3, 256), 512, 0, stream>>>(ctx, WoT + (size_t)l*768*768, bo + l*768, (void*)C, nullptr, 32768, 768, 768);
    k_lnres<<<32768, 256, 0, stream>>>(C, ln1g + l*768, ln1b + l*768, hb);
    k_gemm3<2><<<dim3(12, 256), 512, 0, stream>>>(hb, W1T + (size_t)l*3072*768, b1 + l*3072, (void*)act, nullptr, 32768, 3072, 768);
    k_gemm3<1><<<dim3(3, 256), 512, 0, stream>>>(act, W2T + (size_t)l*768*3072, b2 + l*768, (void*)C, nullptr, 32768, 768, 3072);
    k_lnres<<<32768, 256, 0, stream>>>(C, ln2g + l*768, ln2b + l*768, hb);
  }

  k_dense<<<dim3(12, 64), 256, 0, stream>>>(hb, dW, db, xt);
  k_logits<<<64, 256, 0, stream>>>(xt, oW, ob, (float*)d_out);
}

// Round 13
// 1697.252 us; speedup vs baseline: 1.9848x; 1.0352x over previous
//
#include <hip/hip_runtime.h>

typedef unsigned short u16;
typedef unsigned int   u32;
typedef __bf16 bf16x8 __attribute__((ext_vector_type(8)));
typedef float  f32x4  __attribute__((ext_vector_type(4)));

#define DEVI __device__ __forceinline__

DEVI u16 f2bf(float f){
  u32 u = __builtin_bit_cast(u32, f);
  u32 r = (u + 0x7fffu + ((u >> 16) & 1u)) >> 16;   // RNE
  return (u16)r;
}
DEVI float bf2f(u16 u){
  u32 x = ((u32)u) << 16;
  return __builtin_bit_cast(float, x);
}

DEVI void gload16(const void* g, void* lds){
  __builtin_amdgcn_global_load_lds(
      (const __attribute__((address_space(1))) void*)g,
      (__attribute__((address_space(3))) void*)lds, 16, 0, 0);
}

DEVI f32x4 MFMA(bf16x8 a, bf16x8 b, f32x4 c){
  return __builtin_amdgcn_mfma_f32_16x16x32_bf16(a, b, c, 0, 0, 0);
}

#define BAR() do { asm volatile("s_barrier" ::: "memory"); \
                   __builtin_amdgcn_sched_barrier(0); } while(0)

// ---------------- mask dtype probe: 1 => uint8 bytes, 0 => int32 ----------------
__global__ void k_maskprobe(const unsigned char* __restrict__ m, int* __restrict__ flag){
  __shared__ int s;
  if (threadIdx.x == 0) s = 0;
  __syncthreads();
  int acc = 0;
  for (int i = threadIdx.x; i < 65536; i += 256)
    if ((i & 3) != 0 && m[i] != 0) acc++;
  atomicAdd(&s, acc);
  __syncthreads();
  if (threadIdx.x == 0) *flag = (s > 0) ? 1 : 0;
}

// ---------------- pack attn_mask to bitmask [B*S][16 words] ----------------
__global__ void k_maskbits(const void* __restrict__ mask, const int* __restrict__ flag,
                           u32* __restrict__ mb){
  int row  = blockIdx.x * 4 + (threadIdx.x >> 6);   // b*512+q
  int lane = threadIdx.x & 63;
  bool bytes = (*flag != 0);
  for (int c0 = 0; c0 < 512; c0 += 64){
    int v;
    if (bytes) v = ((const unsigned char*)mask)[(size_t)row * 512 + c0 + lane];
    else       v = ((const int*)mask)[(size_t)row * 512 + c0 + lane];
    unsigned long long bits = __ballot(v != 0);
    if (lane == 0){
      mb[(size_t)row * 16 + (c0 >> 5)]     = (u32)(bits & 0xffffffffull);
      mb[(size_t)row * 16 + (c0 >> 5) + 1] = (u32)(bits >> 32);
    }
  }
}

// ---------------- fused embed + node-average + LN0 -> bf16 hb ----------------
__global__ void k_embln(const int* __restrict__ ids, const int* __restrict__ pos,
                        const u32* __restrict__ mb, const float* __restrict__ wemb,
                        const float* __restrict__ pemb, const float* __restrict__ g,
                        const float* __restrict__ be, u16* __restrict__ hb){
  __shared__ float s1[4], s2[4];
  int row = blockIdx.x, t = threadIdx.x;
  int p = pos[row];
  float x0, x1, x2;
  if (p == 0){
    int b = row >> 9;
    const u32* mrow = mb + (size_t)row * 16;
    const int* pb = pos + ((size_t)b << 9);
    const int* ib = ids + ((size_t)b << 9);
    float a0 = 0.f, a1 = 0.f, a2 = 0.f, cnt = 0.f;
    #pragma unroll 8
    for (int k = 0; k < 512; k++){
      float w = (pb[k] >= 2 && ((mrow[k >> 5] >> (k & 31)) & 1)) ? 1.f : 0.f;
      const float* src = wemb + (size_t)ib[k] * 768;
      a0 += w * src[t]; a1 += w * src[t+256]; a2 += w * src[t+512];
      cnt += w;
    }
    float inv = 1.f / (cnt + 1e-10f);
    x0 = a0 * inv; x1 = a1 * inv; x2 = a2 * inv;
  } else {
    const float* src = wemb + (size_t)ids[row] * 768;
    x0 = src[t]; x1 = src[t+256]; x2 = src[t+512];
  }
  const float* pr = pemb + (size_t)p * 768;
  x0 += pr[t]; x1 += pr[t+256]; x2 += pr[t+512];
  float s = x0 + x1 + x2, q = x0*x0 + x1*x1 + x2*x2;
  for (int o = 32; o; o >>= 1){ s += __shfl_down(s, o, 64); q += __shfl_down(q, o, 64); }
  int wv = t >> 6, ln = t & 63;
  if (!ln){ s1[wv] = s; s2[wv] = q; }
  __syncthreads();
  s = s1[0]+s1[1]+s1[2]+s1[3]; q = s2[0]+s2[1]+s2[2]+s2[3];
  float mu = s * (1.f/768.f);
  float rs = rsqrtf(q * (1.f/768.f) - mu*mu + 1e-5f);
  u16* hbr = hb + (size_t)row * 768;
  hbr[t]     = f2bf((x0-mu)*rs*g[t]     + be[t]);
  hbr[t+256] = f2bf((x1-mu)*rs*g[t+256] + be[t+256]);
  hbr[t+512] = f2bf((x2-mu)*rs*g[t+512] + be[t+512]);
}

// lnres: hb (bf16, in-place) + C (bf16) -> LN -> hb
__global__ void k_lnres(const u16* __restrict__ C, const float* __restrict__ g,
                        const float* __restrict__ be, u16* __restrict__ hb){
  __shared__ float s1[4], s2[4];
  int row = blockIdx.x, t = threadIdx.x;
  u16* hr = hb + (size_t)row * 768;
  const u16* cr = C + (size_t)row * 768;
  float x0 = bf2f(hr[t])     + bf2f(cr[t]);
  float x1 = bf2f(hr[t+256]) + bf2f(cr[t+256]);
  float x2 = bf2f(hr[t+512]) + bf2f(cr[t+512]);
  float s = x0 + x1 + x2, q = x0*x0 + x1*x1 + x2*x2;
  for (int o = 32; o; o >>= 1){ s += __shfl_down(s, o, 64); q += __shfl_down(q, o, 64); }
  int wv = t >> 6, ln = t & 63;
  if (!ln){ s1[wv] = s; s2[wv] = q; }
  __syncthreads();
  s = s1[0]+s1[1]+s1[2]+s1[3]; q = s2[0]+s2[1]+s2[2]+s2[3];
  float mu = s * (1.f/768.f);
  float rs = rsqrtf(q * (1.f/768.f) - mu*mu + 1e-5f);
  hr[t]     = f2bf((x0-mu)*rs*g[t]     + be[t]);
  hr[t+256] = f2bf((x1-mu)*rs*g[t+256] + be[t+256]);
  hr[t+512] = f2bf((x2-mu)*rs*g[t+512] + be[t+512]);
}

// ---------------- weight transpose+cast: src[K][N] f32 -> dst[N][K] bf16 ----------------
__global__ void k_transpose(const float* __restrict__ src, u16* __restrict__ dst,
                            int K, int N){
  __shared__ float tile[32][33];
  int k0 = blockIdx.x * 32, n0 = blockIdx.y * 32;
  int tx = threadIdx.x & 31, ty = threadIdx.x >> 5;   // ty 0..7
  #pragma unroll
  for (int i = 0; i < 32; i += 8)
    tile[ty + i][tx] = src[(size_t)(k0 + ty + i) * N + n0 + tx];
  __syncthreads();
  #pragma unroll
  for (int i = 0; i < 32; i += 8)
    dst[(size_t)(n0 + ty + i) * K + k0 + tx] = f2bf(tile[tx][ty + i]);
}

// ========== 128x256 BK=32 GEMM, prefetch-distance-2, LDS-staged bf16 epilogue ==========
// EPI 0: bf16+bias; 1: f32+bias; 2: bf16+bias+GELU;
// EPI 3: qkv -> head-packed q/k (n0<1536) or DIRECT transposed V write to vt (n0>=1536).

DEVI void stageA32(const u16* __restrict__ src, int K, u16* lds, int tid){
  int r = tid >> 2, c = tid & 3;
  int sc = c ^ ((r >> 1) & 3);
  gload16(src + (size_t)r*K + sc*8, lds + (size_t)tid*8);
}
DEVI void stageB32(const u16* __restrict__ src, int K, u16* lds, int tid){
  #pragma unroll
  for (int j = 0; j < 2; j++){
    int p = j*512 + tid;
    int r = p >> 2, c = p & 3;
    int sc = c ^ ((r >> 1) & 3);
    gload16(src + (size_t)r*K + sc*8, lds + (size_t)p*8);
  }
}

template<int EPI>
__global__ __launch_bounds__(512, 4)
void k_gemm3(const u16* __restrict__ A, const u16* __restrict__ BT,
             const float* __restrict__ bias, void* __restrict__ out,
             void* __restrict__ out2, int M, int N, int K){
  __shared__ __align__(16) u16 sm[36864];   // 72 KiB
  const int tid = threadIdx.x;
  const int w = tid >> 6, lane = tid & 63;
  const int wm = w >> 2, wn = w & 3;
  const int cr = lane & 15, cg = lane >> 4;

  // bijective XCD-chunked remap (m204)
  const int nbn = gridDim.x;
  const int nwg = nbn * gridDim.y;
  const int d   = blockIdx.y * nbn + blockIdx.x;
  const int xcd = d & 7, qq = nwg >> 3, rr = nwg & 7;
  const int logical = (xcd < rr ? xcd*(qq+1) : rr*(qq+1) + (xcd-rr)*qq) + (d >> 3);
  const int m0 = (logical / nbn) * 128;
  const int n0 = (logical % nbn) * 256;

  const int NT = K >> 5;
  const u16* Abase = A  + (size_t)m0 * K;
  const u16* Bbase = BT + (size_t)n0 * K;
  const int rowA = wm*64 + cr;
  const int rowB = wn*64 + cr;

  f32x4 acc[4][4] = {};
  bf16x8 afr[4], bfr[4];

  stageA32(Abase, K, sm, tid);
  stageB32(Bbase, K, sm + 12288, tid);
  if (NT > 1){
    stageA32(Abase + 32, K, sm + 4096, tid);
    stageB32(Bbase + 32, K, sm + 12288 + 8192, tid);
    asm volatile("s_waitcnt vmcnt(3)" ::: "memory");
  } else {
    asm volatile("s_waitcnt vmcnt(0)" ::: "memory");
  }
  __builtin_amdgcn_sched_barrier(0);
  BAR();

  int bcur = 0;
  for (int t = 0; t < NT; ++t){
    const int ab = bcur << 12;
    const int bb = 12288 + (bcur << 13);
    int bn2 = bcur + 2; if (bn2 >= 3) bn2 -= 3;

    #pragma unroll
    for (int n = 0; n < 4; n++){
      int r = rowB + n*16;
      bfr[n] = *(const bf16x8*)&sm[bb + r*32 + ((cg ^ ((r >> 1) & 3)) << 3)];
    }
    #pragma unroll
    for (int i = 0; i < 4; i++){
      int r = rowA + i*16;
      afr[i] = *(const bf16x8*)&sm[ab + r*32 + ((cg ^ ((r >> 1) & 3)) << 3)];
    }
    if (t + 2 < NT){
      stageA32(Abase + (size_t)(t+2)*32, K, sm + (bn2 << 12), tid);
      stageB32(Bbase + (size_t)(t+2)*32, K, sm + 12288 + (bn2 << 13), tid);
    }

    __builtin_amdgcn_s_setprio(1);
    #pragma unroll
    for (int i = 0; i < 4; i++)
      #pragma unroll
      for (int n = 0; n < 4; n++)
        acc[i][n] = MFMA(afr[i], bfr[n], acc[i][n]);
    __builtin_amdgcn_s_setprio(0);

    if (t + 2 < NT) { asm volatile("s_waitcnt vmcnt(3)" ::: "memory"); }
    else            { asm volatile("s_waitcnt vmcnt(0)" ::: "memory"); }
    __builtin_amdgcn_sched_barrier(0);
    BAR();
    bcur = bcur + 1; if (bcur >= 3) bcur = 0;
  }

  // ---- epilogue
  if (EPI == 1){
    #pragma unroll
    for (int n = 0; n < 4; n++){
      int col = n0 + wn*64 + n*16 + cr;
      float bv = bias[col];
      #pragma unroll
      for (int i = 0; i < 4; i++){
        #pragma unroll
        for (int j = 0; j < 4; j++){
          int row = m0 + wm*64 + i*16 + cg*4 + j;
          ((float*)out)[(size_t)row * N + col] = acc[i][n][j] + bv;
        }
      }
    }
  } else {
    const bool vblk = (EPI == 3) && (n0 >= 1536);
    const int LDC = vblk ? 266 : 264;
    #pragma unroll
    for (int n = 0; n < 4; n++){
      int coll = wn*64 + n*16 + cr;
      float bv = bias[n0 + coll];
      #pragma unroll
      for (int i = 0; i < 4; i++){
        #pragma unroll
        for (int j = 0; j < 4; j++){
          int rowl = wm*64 + i*16 + cg*4 + j;
          float v = acc[i][n][j] + bv;
          if (EPI == 2) v = 0.5f * v * (1.f + erff(v * 0.70710678118654752f));
          sm[rowl*LDC + coll] = f2bf(v);
        }
      }
    }
    BAR();
    if (EPI == 3){
      int b = m0 >> 9, s0 = m0 & 511;
      if (vblk){
        // direct transposed V write: vt[b*12+hd][d][s0..s0+127]
        int hd0 = (n0 - 1536) >> 6;
        int dl = lane >> 2, sc4 = lane & 3;
        #pragma unroll
        for (int it = 0; it < 8; it++){
          int gidx = it*8 + w;                 // 0..63
          int hh2 = gidx >> 4, dhi = (gidx >> 2) & 3, shi = gidx & 3;
          int dd2 = dhi*16 + dl;
          int schunk = shi*4 + sc4;
          u16 tmp[8];
          #pragma unroll
          for (int k = 0; k < 8; k++)
            tmp[k] = sm[(schunk*8 + k)*266 + hh2*64 + dd2];
          *(uint4*)((u16*)out2 + (((size_t)(b*12 + hd0 + hh2)*64 + dd2) << 9)
                    + s0 + schunk*8) = *(uint4*)tmp;
        }
      } else {
        // head-packed q/k scatter: 16B chunks, 128B contiguous per (s,head)
        #pragma unroll
        for (int it = 0; it < 8; it++){
          int idx = it*512 + tid;            // (s:128)(h:4)(c:8)
          int c = idx & 7, hh2 = (idx >> 3) & 3, s = idx >> 5;
          uint4 v4 = *(const uint4*)&sm[s*264 + hh2*64 + c*8];
          int col0 = n0 + hh2*64;
          int sec = (col0 >= 768) ? 1 : 0;
          int hd  = (col0 - sec*768) >> 6;
          *(uint4*)((u16*)out + (size_t)sec*25165824 +
                    (((size_t)(b*12 + hd)*512 + (m0 & 511) + s) << 6) + c*8) = v4;
        }
      }
    } else {
      #pragma unroll
      for (int it = 0; it < 8; it++){
        int idx = it*512 + tid;            // (r:128)(c8:32)
        int r = idx >> 5, c8 = idx & 31;
        uint4 v4 = *(const uint4*)&sm[r*264 + c8*8];
        *(uint4*)((u16*)out + (size_t)(m0 + r)*N + n0 + c8*8) = v4;
      }
    }
  }
}

// ---------------- attention v3: flash/online, swapped QK^T, LDS-staged K & V^T ----------
DEVI void stage64(const u16* __restrict__ src, int stride, u16* lds, int w, int lane){
  #pragma unroll
  for (int j = 0; j < 2; j++){
    int p  = j*256 + w*64 + lane;        // piece 0..511 (16B each)
    int r  = p >> 3;                     // row 0..63
    int c8 = (p & 7) ^ (r & 7);          // inverse-swizzled source chunk
    gload16(src + (size_t)r*stride + c8*8, lds + (size_t)p*8);
  }
}

__global__ __launch_bounds__(256, 4)
void k_attn3(const u16* __restrict__ qp, const u16* __restrict__ kp,
             const u16* __restrict__ vt, const u32* __restrict__ mb,
             u16* __restrict__ ctx){
  __shared__ __align__(16) u16 Ks[8192];   // 2 x [64][64]
  __shared__ __align__(16) u16 Vs[8192];   // 2 x [64 d][64 kv]
  const int tid = threadIdx.x, wv = tid >> 6, lane = tid & 63;
  const int cr = lane & 15, cg = lane >> 4;
  const int cg4 = cg * 4;
  const int r7 = cr & 7;

  const int dd = blockIdx.x + (blockIdx.y << 3);
  const int logical = (dd & 7) * 768 + (dd >> 3);
  const int bh = logical >> 3;
  const int qblk = logical & 7;
  const int b = bh / 12, hh = bh % 12;
  const int qw = qblk * 64 + wv * 16;
  const int qrow = qw + cr;
  const size_t base = (size_t)bh * 512 * 64;
  const u16* vtb = vt + (size_t)bh * 64 * 512;

  const int slot0 = ((cg    ) ^ r7) << 3;
  const int slot1 = ((4 + cg) ^ r7) << 3;

  bf16x8 qB[2];
  #pragma unroll
  for (int ks = 0; ks < 2; ks++)
    qB[ks] = *(const bf16x8*)&qp[base + (size_t)qrow * 64 + ks*32 + cg*8];

  u32 mw[16];
  {
    const u32* mrow = mb + ((size_t)b * 512 + qrow) * 16;
    #pragma unroll
    for (int i = 0; i < 4; i++){
      uint4 v4 = *(const uint4*)&mrow[i*4];
      mw[i*4+0] = v4.x; mw[i*4+1] = v4.y; mw[i*4+2] = v4.z; mw[i*4+3] = v4.w;
    }
  }

  stage64(kp + base, 64, Ks, wv, lane);
  stage64(vtb,      512, Vs, wv, lane);
  asm volatile("s_waitcnt vmcnt(0)" ::: "memory");
  __builtin_amdgcn_sched_barrier(0);
  BAR();

  float m = -3e38f, vs = 0.f;
  f32x4 oacc[4] = {};

  for (int s = 0; s < 8; ++s){
    const int buf = (s & 1) << 12;
    const int nbf = ((s + 1) & 1) << 12;

    if (s + 1 < 8){
      stage64(kp + base + (size_t)(s+1)*4096, 64, Ks + nbf, wv, lane);
      stage64(vtb + (size_t)(s+1)*64,        512, Vs + nbf, wv, lane);
    }

    f32x4 pacc[4];
    #pragma unroll
    for (int tt = 0; tt < 4; tt++){
      bf16x8 a0 = *(const bf16x8*)&Ks[buf + (tt*16 + cr)*64 + slot0];
      bf16x8 a1 = *(const bf16x8*)&Ks[buf + (tt*16 + cr)*64 + slot1];
      f32x4 z = {0.f, 0.f, 0.f, 0.f};
      z = MFMA(a0, qB[0], z);
      z = MFMA(a1, qB[1], z);
      pacc[tt] = z;
    }

    const u32 w0 = mw[2*s], w1 = mw[2*s+1];
    f32x4 vmx = {-3e38f, -3e38f, -3e38f, -3e38f};
    #pragma unroll
    for (int tt = 0; tt < 4; tt++){
      u32 nib = (((tt < 2) ? w0 : w1) >> (16*(tt & 1) + cg4)) & 0xFu;
      #pragma unroll
      for (int j = 0; j < 4; j++){
        float v = pacc[tt][j] * 0.125f + (((nib >> j) & 1u) ? 0.f : -10000.f);
        pacc[tt][j] = v;
        vmx[j] = fmaxf(vmx[j], v);
      }
    }
    float tm = fmaxf(fmaxf(vmx[0], vmx[1]), fmaxf(vmx[2], vmx[3]));
    tm = fmaxf(tm, __shfl_xor(tm, 16, 64));
    tm = fmaxf(tm, __shfl_xor(tm, 32, 64));

    float mnew = fmaxf(m, tm);
    float alpha = __expf(m - mnew);
    m = mnew;
    #pragma unroll
    for (int db = 0; db < 4; db++) oacc[db] *= alpha;

    f32x4 vsum = {0.f, 0.f, 0.f, 0.f};
    #pragma unroll
    for (int tt = 0; tt < 4; tt++){
      #pragma unroll
      for (int j = 0; j < 4; j++){
        float e = __expf(pacc[tt][j] - m);
        pacc[tt][j] = e;
        vsum[j] += e;
      }
    }
    vs = vs * alpha + (vsum[0] + vsum[1] + vsum[2] + vsum[3]);

    bf16x8 pa[2];
    #pragma unroll
    for (int c = 0; c < 2; c++)
      #pragma unroll
      for (int e = 0; e < 4; e++){
        pa[c][e]   = (__bf16)pacc[2*c][e];
        pa[c][4+e] = (__bf16)pacc[2*c+1][e];
      }

    #pragma unroll
    for (int c = 0; c < 2; c++){
      const int ch0 = ((4*c     + (cg >> 1)) ^ r7);
      const int ch1 = ((4*c + 2 + (cg >> 1)) ^ r7);
      const int sub = (cg & 1) << 3;
      #pragma unroll
      for (int db = 0; db < 4; db++){
        const char* vrow = (const char*)&Vs[buf + (db*16 + cr)*64];
        bf16x8 vb;
        ((uint2*)&vb)[0] = *(const uint2*)(vrow + (ch0 << 4) + sub);
        ((uint2*)&vb)[1] = *(const uint2*)(vrow + (ch1 << 4) + sub);
        oacc[db] = MFMA(pa[c], vb, oacc[db]);
      }
    }

    if (s + 1 < 8) { asm volatile("s_waitcnt vmcnt(0)" ::: "memory"); }
    __builtin_amdgcn_sched_barrier(0);
    BAR();
  }

  vs += __shfl_xor(vs, 16, 64);
  vs += __shfl_xor(vs, 32, 64);
  #pragma unroll
  for (int j = 0; j < 4; j++){
    float ds = __shfl(vs, cg4 + j, 64);
    float inv = 1.0f / ds;
    #pragma unroll
    for (int db = 0; db < 4; db++)
      ctx[((size_t)b * 512 + qw + cg4 + j) * 768 + hh*64 + 16*db + cr] = f2bf(oacc[db][j] * inv);
  }
}

// ---------------- head: K-split dense+tanh (grid = 12 col-chunks x 64 batches) ---------
__global__ __launch_bounds__(256)
void k_dense(const u16* __restrict__ hb, const float* __restrict__ W,
             const float* __restrict__ bias, float* __restrict__ xt){
  __shared__ float xs[768];
  __shared__ float red[256];
  const int b = blockIdx.y, t = threadIdx.x;
  const u16* hr = hb + (size_t)b * 512 * 768;   // row 0 of batch b
  xs[t] = bf2f(hr[t]); xs[t+256] = bf2f(hr[t+256]); xs[t+512] = bf2f(hr[t+512]);
  __syncthreads();
  const int col = blockIdx.x * 64 + (t & 63);
  const int ks  = t >> 6;                        // 0..3, k-slice of 192
  const float* Wp = W + (size_t)(ks * 192) * 768 + col;
  const float* xp = xs + ks * 192;
  float a = 0.f;
  #pragma unroll 8
  for (int k = 0; k < 192; k++) a += xp[k] * Wp[(size_t)k * 768];
  red[t] = a;
  __syncthreads();
  if (t < 64){
    float y = red[t] + red[t+64] + red[t+128] + red[t+192] + bias[col];
    xt[(size_t)b * 768 + col] = tanhf(y);
  }
}

__global__ void k_logits(const float* __restrict__ xt, const float* __restrict__ ow,
                         const float* __restrict__ ob, float* __restrict__ out){
  __shared__ float sb[4];
  int b = blockIdx.x, t = threadIdx.x;
  const float* x = xt + (size_t)b * 768;
  float s = x[t]*ow[t] + x[t+256]*ow[t+256] + x[t+512]*ow[t+512];
  for (int o = 32; o; o >>= 1) s += __shfl_down(s, o, 64);
  int wv = t >> 6, ln = t & 63;
  if (!ln) sb[wv] = s;
  __syncthreads();
  if (t == 0) out[b] = sb[0] + sb[1] + sb[2] + sb[3] + ob[0];
}

// ---------------- launch ----------------
extern "C" void kernel_launch(void* const* d_in, const int* in_sizes, int n_in,
                              void* d_out, int out_size, void* d_ws, size_t ws_size,
                              hipStream_t stream){
  if (n_in < 23) return;
  if (ws_size < 534000000ull) return;

  const int*   ids  = (const int*)  d_in[0];
  const int*   pos  = (const int*)  d_in[1];
  const void*  amsk =               d_in[2];
  const float* wemb = (const float*)d_in[3];
  const float* pemb = (const float*)d_in[4];
  const float* lng  = (const float*)d_in[5];
  const float* lnb  = (const float*)d_in[6];
  const float* Wqkv = (const float*)d_in[7];
  const float* bqkv = (const float*)d_in[8];
  const float* Wo   = (const float*)d_in[9];
  const float* bo   = (const float*)d_in[10];
  const float* ln1g = (const float*)d_in[11];
  const float* ln1b = (const float*)d_in[12];
  const float* W1   = (const float*)d_in[13];
  const float* b1   = (const float*)d_in[14];
  const float* W2   = (const float*)d_in[15];
  const float* b2   = (const float*)d_in[16];
  const float* ln2g = (const float*)d_in[17];
  const float* ln2b = (const float*)d_in[18];
  const float* dW   = (const float*)d_in[19];
  const float* db   = (const float*)d_in[20];
  const float* oW   = (const float*)d_in[21];
  const float* ob   = (const float*)d_in[22];

  char* ws = (char*)d_ws;
  u16*   hb   = (u16*)  (ws + 100663296);
  u16*   C    = (u16*)  (ws + 150994944);   // bf16 layer-output stream
  u16*   qkvp = (u16*)  (ws + 251658240);   // qp | kp (head-packed)
  u16*   vt   = (u16*)  (ws + 402653184);   // [bh][64][512]
  u16*   act  = (u16*)  (ws + 251658240);   // aliases qkvp+vt (disjoint lifetime)
  u16*   ctx  = (u16*)  (ws + 452984832);
  u32*   mbit = (u32*)  (ws + 503316480);
  u16*   wt   = (u16*)  (ws + 505413632);
  float* xt   = (float*)(ws + 533725184);
  int*   flag = (int*)  (ws + 533921792);

  u16* qp   = qkvp;
  u16* kp   = qkvp + (size_t)25165824;

  u16* WqkvT = wt;                                  // [l][2304][768]
  u16* WoT   = WqkvT + (size_t)2*2304*768;          // [l][768][768]
  u16* W1T   = WoT   + (size_t)2*768*768;           // [l][3072][768]
  u16* W2T   = W1T   + (size_t)2*3072*768;          // [l][768][3072]

  k_maskprobe<<<1, 256, 0, stream>>>((const unsigned char*)amsk, flag);
  k_maskbits<<<8192, 256, 0, stream>>>(amsk, flag, mbit);

  for (int l = 0; l < 2; l++){
    k_transpose<<<dim3(24, 72), 256, 0, stream>>>(Wqkv + (size_t)l*768*2304, WqkvT + (size_t)l*2304*768, 768, 2304);
    k_transpose<<<dim3(24, 24), 256, 0, stream>>>(Wo   + (size_t)l*768*768,  WoT   + (size_t)l*768*768,  768, 768);
    k_transpose<<<dim3(24, 96), 256, 0, stream>>>(W1   + (size_t)l*768*3072, W1T   + (size_t)l*3072*768, 768, 3072);
    k_transpose<<<dim3(96, 24), 256, 0, stream>>>(W2   + (size_t)l*3072*768, W2T   + (size_t)l*768*3072, 3072, 768);
  }

  k_embln<<<32768, 256, 0, stream>>>(ids, pos, mbit, wemb, pemb, lng, lnb, hb);

  for (int l = 0; l < 2; l++){
    k_gemm3<3><<<dim3(9, 256), 512, 0, stream>>>(hb, WqkvT + (size_t)l*2304*768, bqkv + l*2304, (void*)qkvp, (void*)vt, 32768, 2304, 768);
    k_attn3<<<dim3(8, 768), 256, 0, stream>>>(qp, kp, vt, mbit, ctx);
    k_gemm3<0><<<dim3(3, 256), 512, 0, stream>>>(ctx, WoT + (size_t)l*768*768, bo + l*768, (void*)C, nullptr, 32768, 768, 768);
    k_lnres<<<32768, 256, 0, stream>>>(C, ln1g + l*768, ln1b + l*768, hb);
    k_gemm3<2><<<dim3(12, 256), 512, 0, stream>>>(hb, W1T + (size_t)l*3072*768, b1 + l*3072, (void*)act, nullptr, 32768, 3072, 768);
    k_gemm3<0><<<dim3(3, 256), 512, 0, stream>>>(act, W2T + (size_t)l*768*3072, b2 + l*768, (void*)C, nullptr, 32768, 768, 3072);
    k_lnres<<<32768, 256, 0, stream>>>(C, ln2g + l*768, ln2b + l*768, hb);
  }

  k_dense<<<dim3(12, 64), 256, 0, stream>>>(hb, dW, db, xt);
  k_logits<<<64, 256, 0, stream>>>(xt, oW, ob, (float*)d_out);
}